// Round 1
// baseline (1018.103 us; speedup 1.0000x reference)
//
#include <hip/hip_runtime.h>
#include <math.h>

#define BB 8
#define NN 500
#define DDIM 256
#define HH 480
#define WW 640
#define HWSZ (HH*WW)        // 307200
#define BHW (BB*HWSZ)       // 2457600
#define NCAND 8192

// ---------------- helpers ----------------

static __device__ __forceinline__ float wredmaxf(float v) {
  #pragma unroll
  for (int o = 1; o < 64; o <<= 1) v = fmaxf(v, __shfl_xor(v, o, 64));
  return v;
}

// block (256 threads) reduce sum -> valid on thread 0
static __device__ __forceinline__ double blockRedSum256(double v) {
  __shared__ double sp[4];
  __syncthreads();
  #pragma unroll
  for (int o = 32; o > 0; o >>= 1) v += __shfl_down(v, o, 64);
  int lane = threadIdx.x & 63, wid = threadIdx.x >> 6;
  if (lane == 0) sp[wid] = v;
  __syncthreads();
  double r = 0.0;
  if (threadIdx.x == 0) r = sp[0] + sp[1] + sp[2] + sp[3];
  return r;
}

static __device__ __forceinline__ float bilin(const float* __restrict__ img, float px, float py) {
  float x = fminf(fmaxf(px, 0.0f), 639.0f);
  float y = fminf(fmaxf(py, 0.0f), 479.0f);
  float x0 = floorf(x), y0 = floorf(y);
  float x1 = fminf(x0 + 1.0f, 639.0f);
  float y1 = fminf(y0 + 1.0f, 479.0f);
  float wx = x - x0, wy = y - y0;
  int x0i = (int)x0, x1i = (int)x1, y0i = (int)y0, y1i = (int)y1;
  float v00 = img[y0i*WW + x0i], v01 = img[y0i*WW + x1i];
  float v10 = img[y1i*WW + x0i], v11 = img[y1i*WW + x1i];
  return v00*(1.0f-wx)*(1.0f-wy) + v01*wx*(1.0f-wy) + v10*(1.0f-wx)*wy + v11*wx*wy;
}

// world point from pixel (px,py) in image bimg; replicates reference op order
static __device__ void src_compute(float px, float py, const float* __restrict__ dep,
                                   const float* __restrict__ poses, const float* __restrict__ Km,
                                   int bimg, float* Xw, float* dout) {
  float d = bilin(dep, px, py);
  const float* Kb = Km + bimg*9;
  double a00=Kb[0],a01=Kb[1],a02=Kb[2],a10=Kb[3],a11=Kb[4],a12=Kb[5],a20=Kb[6],a21=Kb[7],a22=Kb[8];
  double det = a00*(a11*a22-a12*a21) - a01*(a10*a22-a12*a20) + a02*(a10*a21-a11*a20);
  double id = 1.0/det;
  float i00=(float)((a11*a22-a12*a21)*id), i01=(float)((a02*a21-a01*a22)*id), i02=(float)((a01*a12-a02*a11)*id);
  float i10=(float)((a12*a20-a10*a22)*id), i11=(float)((a00*a22-a02*a20)*id), i12=(float)((a02*a10-a00*a12)*id);
  float i20=(float)((a10*a21-a11*a20)*id), i21=(float)((a01*a20-a00*a21)*id), i22=(float)((a00*a11-a01*a10)*id);
  float c0 = i00*px + i01*py + i02;
  float c1 = i10*px + i11*py + i12;
  float c2 = i20*px + i21*py + i22;
  float X0 = d*c0, X1 = d*c1, X2 = d*c2;
  const float* P = poses + bimg*16;
  Xw[0] = (P[0]*X0 + P[1]*X1 + P[2]*X2)  + P[3];
  Xw[1] = (P[4]*X0 + P[5]*X1 + P[6]*X2)  + P[7];
  Xw[2] = (P[8]*X0 + P[9]*X1 + P[10]*X2) + P[11];
  *dout = d;
}

// project world point into image j; returns normalized coords + invis flag
static __device__ void project_to(const float* __restrict__ poses, const float* __restrict__ Km,
                                  int j, const float* Xw, float dsrc,
                                  float* pnx, float* pny, bool* invis) {
  const float* P = poses + j*16;
  float d0 = Xw[0]-P[3], d1 = Xw[1]-P[7], d2 = Xw[2]-P[11];
  // Xj = R_j^T * diff
  float Xj0 = P[0]*d0 + P[4]*d1 + P[8]*d2;
  float Xj1 = P[1]*d0 + P[5]*d1 + P[9]*d2;
  float Xj2 = P[2]*d0 + P[6]*d1 + P[10]*d2;
  const float* Kb = Km + j*9;
  float u = Kb[0]*Xj0 + Kb[1]*Xj1 + Kb[2]*Xj2;
  float v = Kb[3]*Xj0 + Kb[4]*Xj1 + Kb[5]*Xj2;
  float z = Kb[6]*Xj0 + Kb[7]*Xj1 + Kb[8]*Xj2;
  float zs = (fabsf(z) < 1e-6f) ? 1e-6f : z;
  float pu = u/zs, pv = v/zs;
  float nx = 2.0f*pu/639.0f - 1.0f;
  float ny = 2.0f*pv/479.0f - 1.0f;
  *pnx = nx; *pny = ny;
  *invis = (z <= 1e-6f) || (fabsf(nx) > 1.0f) || (fabsf(ny) > 1.0f) || (dsrc <= 0.0f);
}

// ---------------- kernels ----------------

__global__ void k_gray(const float* __restrict__ imgs, float* __restrict__ gray) {
  int idx = blockIdx.x*256 + threadIdx.x;
  int b = idx / HWSZ, p = idx % HWSZ;
  const float* ib = imgs + (size_t)b*3*HWSZ;
  gray[idx] = 0.299f*ib[p] + 0.587f*ib[HWSZ+p] + 0.114f*ib[2*HWSZ+p];
}

__global__ void k_sobel(const float* __restrict__ gray, float* __restrict__ gx, float* __restrict__ gy) {
  int idx = blockIdx.x*256 + threadIdx.x;
  int b = idx / HWSZ, p = idx % HWSZ;
  int y = p / WW, x = p % WW;
  const float* g = gray + (size_t)b*HWSZ;
  const float kx[3][3] = {{-0.125f,0.f,0.125f},{-0.25f,0.f,0.25f},{-0.125f,0.f,0.125f}};
  float sx = 0.f, sy = 0.f;
  #pragma unroll
  for (int i = 0; i < 3; i++)
    #pragma unroll
    for (int j = 0; j < 3; j++) {
      int yy = y+i-1, xx = x+j-1;
      float v = (yy>=0 && yy<HH && xx>=0 && xx<WW) ? g[yy*WW+xx] : 0.f;
      sx += kx[i][j]*v;
      sy += kx[j][i]*v;
    }
  gx[idx] = sx; gy[idx] = sy;
}

__global__ void k_wprep(float* __restrict__ gw) {
  int t = threadIdx.x;
  if (t < 49) {
    double g[7];
    for (int q = 0; q < 7; q++) { double r = (double)(q-3); g[q] = exp(-(r*r)/2.0); }
    double s = 0.0;
    for (int q = 0; q < 7; q++) s += g[q];
    int i = t/7, j = t%7;
    gw[t] = (float)((g[i]/s)*(g[j]/s));
  }
}

__global__ void k_gftt(const float* __restrict__ gx, const float* __restrict__ gy,
                       const float* __restrict__ gw, float* __restrict__ resp) {
  __shared__ float w[49];
  if (threadIdx.x < 49) w[threadIdx.x] = gw[threadIdx.x];
  __syncthreads();
  int idx = blockIdx.x*256 + threadIdx.x;
  int b = idx / HWSZ, p = idx % HWSZ;
  int y = p / WW, x = p % WW;
  const float* gxb = gx + (size_t)b*HWSZ;
  const float* gyb = gy + (size_t)b*HWSZ;
  float sxx = 0.f, syy = 0.f, sxy = 0.f;
  for (int i = 0; i < 7; i++) {
    int yy = y+i-3;
    if (yy < 0 || yy >= HH) continue;
    for (int j = 0; j < 7; j++) {
      int xx = x+j-3;
      if (xx < 0 || xx >= WW) continue;
      float a = gxb[yy*WW+xx], c = gyb[yy*WW+xx];
      float ww = w[i*7+j];
      sxx += ww*(a*a); syy += ww*(c*c); sxy += ww*(a*c);
    }
  }
  float tr = sxx + syy;
  float det = sxx*syy - sxy*sxy;
  float disc = fmaxf(tr*tr - 4.0f*det, 0.f);
  resp[idx] = 0.5f*(tr - sqrtf(disc));
}

__global__ void k_nms(const float* __restrict__ resp, float* __restrict__ c) {
  int idx = blockIdx.x*256 + threadIdx.x;
  int b = idx / HWSZ, p = idx % HWSZ;
  int y = p / WW, x = p % WW;
  const float* r = resp + (size_t)b*HWSZ;
  float v = r[p];
  float mp = -INFINITY;
  for (int dy = -2; dy <= 2; dy++) {
    int yy = y+dy; if (yy < 0 || yy >= HH) continue;
    for (int dx = -2; dx <= 2; dx++) {
      int xx = x+dx; if (xx < 0 || xx >= WW) continue;
      mp = fmaxf(mp, r[yy*WW+xx]);
    }
  }
  c[idx] = (v == mp) ? v : 0.f;
}

__global__ void k_cand(const float* __restrict__ c, float* __restrict__ cv,
                       int* __restrict__ ci, int* __restrict__ cnt) {
  int blk = blockIdx.x;
  int b = blk / 4800, r = blk % 4800;
  int by = r / 80, bx = r % 80;
  int t = threadIdx.x;
  int y = by*8 + (t >> 3), x = bx*8 + (t & 7);
  float v = c[(size_t)b*HWSZ + y*WW + x];
  float bm = wredmaxf(v);
  if (v > 0.f && v == bm) {
    int pos = atomicAdd(&cnt[b], 1);
    if (pos < NCAND) { cv[b*NCAND+pos] = v; ci[b*NCAND+pos] = y*WW + x; }
  }
}

__global__ __launch_bounds__(1024) void k_topk(const float* __restrict__ cv, const int* __restrict__ ci,
                                               const int* __restrict__ cnt,
                                               float* __restrict__ topv, int* __restrict__ topi) {
  extern __shared__ float smem[];
  float* sv = smem;
  int* si = (int*)(smem + NCAND);
  int b = blockIdx.x;
  int n = cnt[b]; if (n > NCAND) n = NCAND;
  for (int e = threadIdx.x; e < NCAND; e += 1024) {
    if (e < n) { sv[e] = cv[b*NCAND+e]; si[e] = ci[b*NCAND+e]; }
    else       { sv[e] = -1.0f;          si[e] = 0x7fffffff; }
  }
  for (int k = 2; k <= NCAND; k <<= 1)
    for (int j = k >> 1; j > 0; j >>= 1) {
      __syncthreads();
      for (int i = threadIdx.x; i < NCAND; i += 1024) {
        int p = i ^ j;
        if (p > i) {
          float v1 = sv[i], v2 = sv[p]; int a1 = si[i], a2 = si[p];
          bool fb = (v1 > v2) || (v1 == v2 && a1 < a2);   // i-element ranks first (desc, idx-asc)
          bool desc = ((i & k) == 0);
          if (desc != fb) { sv[i]=v2; sv[p]=v1; si[i]=a2; si[p]=a1; }
        }
      }
    }
  __syncthreads();
  for (int e = threadIdx.x; e < NN; e += 1024) { topv[b*NN+e] = sv[e]; topi[b*NN+e] = si[e]; }
}

__global__ void k_csrc(const float* __restrict__ topv, const int* __restrict__ topi,
                       const float* __restrict__ depths, const float* __restrict__ poses,
                       const float* __restrict__ Km, float* __restrict__ cXw, float* __restrict__ cd) {
  int t = blockIdx.x*256 + threadIdx.x;
  if (t >= BB*NN) return;
  int i = t / NN;
  if (topv[t] <= 0.f) { cd[t] = 0.f; return; }
  int idx = topi[t];
  float xs = (float)(idx % WW), ys = (float)(idx / WW);
  // normalize_pix then denormalize round-trip (replicates reference fp)
  float cx = 2.0f*xs/639.0f - 1.0f;
  float cy = 2.0f*ys/479.0f - 1.0f;
  float px = (cx + 1.0f)*0.5f*639.0f;
  float py = (cy + 1.0f)*0.5f*479.0f;
  float Xw[3], d;
  src_compute(px, py, depths + (size_t)i*HWSZ, poses, Km, i, Xw, &d);
  cXw[t*3] = Xw[0]; cXw[t*3+1] = Xw[1]; cXw[t*3+2] = Xw[2]; cd[t] = d;
}

__global__ void k_scatter(const float* __restrict__ topv, const float* __restrict__ cXw,
                          const float* __restrict__ cd, const float* __restrict__ poses,
                          const float* __restrict__ Km, unsigned int* __restrict__ target) {
  int t = blockIdx.x*256 + threadIdx.x;   // < BB*BB*NN
  int n = t % NN; int ij = t / NN; int j = ij % BB; int i = ij / BB;
  int sn = i*NN + n;
  float val = topv[sn];
  if (val <= 0.f) return;
  float Xw[3] = {cXw[sn*3], cXw[sn*3+1], cXw[sn*3+2]};
  float d = cd[sn];
  float nx, ny; bool inv;
  project_to(poses, Km, j, Xw, d, &nx, &ny, &inv);
  if (inv) { nx = -2.0f; ny = -2.0f; }
  float fx = rintf((nx + 1.0f)*0.5f*639.0f);
  float fy = rintf((ny + 1.0f)*0.5f*479.0f);
  int wq = (int)fx, hq = (int)fy;
  if (wq < 0) return;                      // reference: valid = wq >= 0
  int hc = min(max(hq, 0), HH-1), wc = min(max(wq, 0), WW-1);
  atomicMax(&target[(size_t)j*HWSZ + hc*WW + wc], __float_as_uint(val));
}

__global__ void k_bce(const float* __restrict__ target, const float* __restrict__ pnness,
                      double* __restrict__ acc) {
  int idx = blockIdx.x*256 + threadIdx.x;
  int b = idx / HWSZ, p = idx % HWSZ;
  int y = p / WW, x = p % WW;
  const float* tb = target + (size_t)b*HWSZ;
  float v = tb[p];
  float mp = -INFINITY;
  for (int dy = -2; dy <= 2; dy++) {
    int yy = y+dy; if (yy < 0 || yy >= HH) continue;
    for (int dx = -2; dx <= 2; dx++) {
      int xx = x+dx; if (xx < 0 || xx >= WW) continue;
      mp = fmaxf(mp, tb[yy*WW+xx]);
    }
  }
  bool t = (v > 0.f) && (v == mp);
  float pv = pnness[idx];
  float term = t ? (-fmaxf(logf(pv), -100.0f)) : (-fmaxf(logf(1.0f - pv), -100.0f));
  double s = blockRedSum256((double)term);
  if (threadIdx.x == 0) atomicAdd(&acc[1], s);
}

__global__ void k_dn(const float* __restrict__ desc, float* __restrict__ dn) {
  int row = blockIdx.x;            // BB*NN rows
  int d = threadIdx.x;             // DDIM threads
  float v = desc[(size_t)row*DDIM + d];
  __shared__ float sp[4];
  __shared__ float den_s;
  float s = v*v;
  #pragma unroll
  for (int o = 32; o > 0; o >>= 1) s += __shfl_down(s, o, 64);
  int lane = threadIdx.x & 63, wid = threadIdx.x >> 6;
  if (lane == 0) sp[wid] = s;
  __syncthreads();
  if (threadIdx.x == 0) den_s = fmaxf(sqrtf(sp[0]+sp[1]+sp[2]+sp[3]), 1e-8f);
  __syncthreads();
  dn[(size_t)row*DDIM + d] = v / den_s;
}

__global__ void k_msrc(const float* __restrict__ points, const float* __restrict__ depths,
                       const float* __restrict__ poses, const float* __restrict__ Km,
                       float* __restrict__ mXw, float* __restrict__ md, float* __restrict__ psrc) {
  int t = blockIdx.x*256 + threadIdx.x;
  if (t >= BB*NN) return;
  int i = t / NN;
  float p0 = points[t*2], p1 = points[t*2+1];
  float px = (p0 + 1.0f)*0.5f*639.0f;
  float py = (p1 + 1.0f)*0.5f*479.0f;
  float Xw[3], d;
  src_compute(px, py, depths + (size_t)i*HWSZ, poses, Km, i, Xw, &d);
  mXw[t*3] = Xw[0]; mXw[t*3+1] = Xw[1]; mXw[t*3+2] = Xw[2];
  md[t] = d; psrc[t*2] = px; psrc[t*2+1] = py;
}

__global__ void k_pdst(const float* __restrict__ mXw, const float* __restrict__ md,
                       const float* __restrict__ poses, const float* __restrict__ Km,
                       float* __restrict__ pdst, int* __restrict__ minv) {
  int t = blockIdx.x*256 + threadIdx.x;   // (a*8+b)*500+m
  int m = t % NN; int ab = t / NN; int b = ab % BB; int a = ab / BB;
  int sn = a*NN + m;
  float Xw[3] = {mXw[sn*3], mXw[sn*3+1], mXw[sn*3+2]};
  float d = md[sn];
  float nx, ny; bool inv;
  project_to(poses, Km, b, Xw, d, &nx, &ny, &inv);
  pdst[t*2]   = (nx + 1.0f)*0.5f*639.0f;   // raw (un-masked) projections, like reference match path
  pdst[t*2+1] = (ny + 1.0f)*0.5f*479.0f;
  minv[t] = inv ? 1 : 0;
}

__global__ void k_match(const float* __restrict__ psrc, const float* __restrict__ pdst,
                        const int* __restrict__ minv, const float* __restrict__ dn,
                        double* __restrict__ acc) {
  __shared__ float spd[2*NN], ssrc[2*NN];
  __shared__ int sinv[NN];
  int ab = blockIdx.x; int b = ab % BB; int a = ab / BB;
  for (int e = threadIdx.x; e < NN; e += 256) {
    spd[e*2]   = pdst[(ab*NN+e)*2];
    spd[e*2+1] = pdst[(ab*NN+e)*2+1];
    sinv[e]    = minv[ab*NN+e];
    ssrc[e*2]   = psrc[(b*NN+e)*2];
    ssrc[e*2+1] = psrc[(b*NN+e)*2+1];
  }
  __syncthreads();
  double lsum = 0.0, lcnt = 0.0;
  for (int idx = threadIdx.x; idx < NN*NN; idx += 256) {
    int nn = idx / NN, mm = idx % NN;
    if (nn >= mm) continue;          // n < m
    if (sinv[nn]) continue;          // reference quirk: invis indexed by n
    float dx = ssrc[nn*2]   - spd[mm*2];
    float dy = ssrc[nn*2+1] - spd[mm*2+1];
    if (dx*dx + dy*dy <= 1.0f) {
      const float* da = dn + ((size_t)a*NN + mm)*DDIM;
      const float* db = dn + ((size_t)b*NN + nn)*DDIM;
      float dot = 0.f;
      for (int q = 0; q < DDIM; q++) dot += db[q]*da[q];
      lsum += (double)(1.0f - dot);
      lcnt += 1.0;
    }
  }
  double s = blockRedSum256(lsum);
  if (threadIdx.x == 0 && s != 0.0) atomicAdd(&acc[2], s);
  double c2 = blockRedSum256(lcnt);
  if (threadIdx.x == 0 && c2 != 0.0) atomicAdd(&acc[3], c2);
}

__global__ void k_dist(const float* __restrict__ dn, double* __restrict__ acc) {
  __shared__ float sA[25*DDIM];
  int b = blockIdx.x / 20, tile = blockIdx.x % 20;
  int n0 = tile*25;
  for (int e = threadIdx.x; e < 25*DDIM; e += 256)
    sA[e] = dn[((size_t)b*NN + n0 + e/DDIM)*DDIM + (e % DDIM)];
  __syncthreads();
  float accr[25];
  double lsum = 0.0;
  for (int mbase = 0; mbase < NN; mbase += 256) {
    int m = mbase + threadIdx.x;
    if (m < NN) {
      #pragma unroll
      for (int r = 0; r < 25; r++) accr[r] = 0.f;
      const float* dm = dn + ((size_t)b*NN + m)*DDIM;
      for (int q = 0; q < DDIM; q++) {
        float x = dm[q];
        #pragma unroll
        for (int r = 0; r < 25; r++) accr[r] += x*sA[r*DDIM + q];
      }
      #pragma unroll
      for (int r = 0; r < 25; r++) lsum += (double)fmaxf(accr[r], 0.f);
    }
  }
  double s = blockRedSum256(lsum);
  if (threadIdx.x == 0) atomicAdd(&acc[0], s);
}

__global__ void k_final(const double* __restrict__ acc, float* __restrict__ out) {
  float dist  = (float)(acc[0] / (double)(BB*NN*NN));
  float corn  = (float)(acc[1] / (double)BHW);
  float cnt   = fmaxf((float)acc[3], 1.0f);
  float match = (float)acc[2] / cnt;
  out[0] = 1.0f*dist + 1.0f*corn + 1.0f*match;
}

// ---------------- host ----------------

extern "C" void kernel_launch(void* const* d_in, const int* in_sizes, int n_in,
                              void* d_out, int out_size, void* d_ws, size_t ws_size,
                              hipStream_t stream) {
  (void)in_sizes; (void)n_in; (void)out_size; (void)ws_size;
  const float* desc      = (const float*)d_in[0];
  const float* points    = (const float*)d_in[1];
  const float* pointness = (const float*)d_in[2];
  const float* depths    = (const float*)d_in[3];
  const float* poses     = (const float*)d_in[4];
  const float* Kmat      = (const float*)d_in[5];
  const float* imgs      = (const float*)d_in[6];
  float* out = (float*)d_out;
  float* ws = (float*)d_ws;

  // workspace layout (~35 MB)
  float* bufA = ws;                          // gray -> resp
  float* bufB = ws + (size_t)BHW;            // gx -> nms'd c
  float* bufC = ws + 2*(size_t)BHW;          // gy -> target (scatter)
  float* cand_val = ws + 3*(size_t)BHW;      // B*8192
  int*   cand_idx = (int*)(cand_val + BB*NCAND);
  float* topv = (float*)(cand_idx + BB*NCAND);
  int*   topi = (int*)(topv + BB*NN);
  float* cXw  = (float*)(topi + BB*NN);
  float* cd   = cXw + BB*NN*3;
  float* mXw  = cd + BB*NN;
  float* md   = mXw + BB*NN*3;
  float* psrc = md + BB*NN;
  float* pdst = psrc + BB*NN*2;
  int*   minv = (int*)(pdst + BB*BB*NN*2);
  float* dn   = (float*)(minv + BB*BB*NN);
  int*   ccnt = (int*)(dn + (size_t)BB*NN*DDIM);
  double* acc = (double*)(ccnt + 8);         // [0]=dist [1]=bce [2]=match_sum [3]=match_cnt
  float* gw   = (float*)(acc + 4);           // 49 gaussian weights

  // zero counters + accumulators (every call: determinism)
  hipMemsetAsync(ccnt, 0, 8*sizeof(int) + 4*sizeof(double), stream);

  k_gray <<<BHW/256, 256, 0, stream>>>(imgs, bufA);
  k_sobel<<<BHW/256, 256, 0, stream>>>(bufA, bufB, bufC);
  k_wprep<<<1, 64, 0, stream>>>(gw);
  k_gftt <<<BHW/256, 256, 0, stream>>>(bufB, bufC, gw, bufA);
  // bufC (gy) now free -> becomes target; zero it
  hipMemsetAsync(bufC, 0, (size_t)BHW*sizeof(float), stream);
  k_nms  <<<BHW/256, 256, 0, stream>>>(bufA, bufB);
  k_cand <<<BB*4800, 64, 0, stream>>>(bufB, cand_val, cand_idx, ccnt);
  k_topk <<<BB, 1024, NCAND*8, stream>>>(cand_val, cand_idx, ccnt, topv, topi);
  k_csrc <<<(BB*NN + 255)/256, 256, 0, stream>>>(topv, topi, depths, poses, Kmat, cXw, cd);
  k_scatter<<<(BB*BB*NN)/256, 256, 0, stream>>>(topv, cXw, cd, poses, Kmat, (unsigned int*)bufC);
  k_bce  <<<BHW/256, 256, 0, stream>>>(bufC, pointness, acc);
  k_dn   <<<BB*NN, DDIM, 0, stream>>>(desc, dn);
  k_msrc <<<(BB*NN + 255)/256, 256, 0, stream>>>(points, depths, poses, Kmat, mXw, md, psrc);
  k_pdst <<<(BB*BB*NN)/256, 256, 0, stream>>>(mXw, md, poses, Kmat, pdst, minv);
  k_match<<<BB*BB, 256, 0, stream>>>(psrc, pdst, minv, dn, acc);
  k_dist <<<BB*20, 256, 0, stream>>>(dn, acc);
  k_final<<<1, 1, 0, stream>>>(acc, out);
}

// Round 2
// 549.449 us; speedup vs baseline: 1.8530x; 1.8530x over previous
//
#include <hip/hip_runtime.h>
#include <math.h>

#define BB 8
#define NN 500
#define DDIM 256
#define HH 480
#define WW 640
#define HWSZ (HH*WW)        // 307200
#define BHW (BB*HWSZ)       // 2457600
#define NCAND 8192
#define NBLK 4800           // 8x8 blocks per image

// ---------------- helpers ----------------

static __device__ __forceinline__ float wredmaxf(float v) {
  #pragma unroll
  for (int o = 1; o < 64; o <<= 1) v = fmaxf(v, __shfl_xor(v, o, 64));
  return v;
}

// block (256 threads) reduce sum -> valid on thread 0
static __device__ __forceinline__ double blockRedSum256(double v) {
  __shared__ double sp[4];
  __syncthreads();
  #pragma unroll
  for (int o = 32; o > 0; o >>= 1) v += __shfl_down(v, o, 64);
  int lane = threadIdx.x & 63, wid = threadIdx.x >> 6;
  if (lane == 0) sp[wid] = v;
  __syncthreads();
  double r = 0.0;
  if (threadIdx.x == 0) r = sp[0] + sp[1] + sp[2] + sp[3];
  return r;
}

static __device__ __forceinline__ float bilin(const float* __restrict__ img, float px, float py) {
  float x = fminf(fmaxf(px, 0.0f), 639.0f);
  float y = fminf(fmaxf(py, 0.0f), 479.0f);
  float x0 = floorf(x), y0 = floorf(y);
  float x1 = fminf(x0 + 1.0f, 639.0f);
  float y1 = fminf(y0 + 1.0f, 479.0f);
  float wx = x - x0, wy = y - y0;
  int x0i = (int)x0, x1i = (int)x1, y0i = (int)y0, y1i = (int)y1;
  float v00 = img[y0i*WW + x0i], v01 = img[y0i*WW + x1i];
  float v10 = img[y1i*WW + x0i], v11 = img[y1i*WW + x1i];
  return v00*(1.0f-wx)*(1.0f-wy) + v01*wx*(1.0f-wy) + v10*(1.0f-wx)*wy + v11*wx*wy;
}

// world point from pixel (px,py) in image bimg; replicates reference op order
static __device__ void src_compute(float px, float py, const float* __restrict__ dep,
                                   const float* __restrict__ poses, const float* __restrict__ Km,
                                   int bimg, float* Xw, float* dout) {
  float d = bilin(dep, px, py);
  const float* Kb = Km + bimg*9;
  double a00=Kb[0],a01=Kb[1],a02=Kb[2],a10=Kb[3],a11=Kb[4],a12=Kb[5],a20=Kb[6],a21=Kb[7],a22=Kb[8];
  double det = a00*(a11*a22-a12*a21) - a01*(a10*a22-a12*a20) + a02*(a10*a21-a11*a20);
  double id = 1.0/det;
  float i00=(float)((a11*a22-a12*a21)*id), i01=(float)((a02*a21-a01*a22)*id), i02=(float)((a01*a12-a02*a11)*id);
  float i10=(float)((a12*a20-a10*a22)*id), i11=(float)((a00*a22-a02*a20)*id), i12=(float)((a02*a10-a00*a12)*id);
  float i20=(float)((a10*a21-a11*a20)*id), i21=(float)((a01*a20-a00*a21)*id), i22=(float)((a00*a11-a01*a10)*id);
  float c0 = i00*px + i01*py + i02;
  float c1 = i10*px + i11*py + i12;
  float c2 = i20*px + i21*py + i22;
  float X0 = d*c0, X1 = d*c1, X2 = d*c2;
  const float* P = poses + bimg*16;
  Xw[0] = (P[0]*X0 + P[1]*X1 + P[2]*X2)  + P[3];
  Xw[1] = (P[4]*X0 + P[5]*X1 + P[6]*X2)  + P[7];
  Xw[2] = (P[8]*X0 + P[9]*X1 + P[10]*X2) + P[11];
  *dout = d;
}

// project world point into image j; returns normalized coords + invis flag
static __device__ void project_to(const float* __restrict__ poses, const float* __restrict__ Km,
                                  int j, const float* Xw, float dsrc,
                                  float* pnx, float* pny, bool* invis) {
  const float* P = poses + j*16;
  float d0 = Xw[0]-P[3], d1 = Xw[1]-P[7], d2 = Xw[2]-P[11];
  float Xj0 = P[0]*d0 + P[4]*d1 + P[8]*d2;
  float Xj1 = P[1]*d0 + P[5]*d1 + P[9]*d2;
  float Xj2 = P[2]*d0 + P[6]*d1 + P[10]*d2;
  const float* Kb = Km + j*9;
  float u = Kb[0]*Xj0 + Kb[1]*Xj1 + Kb[2]*Xj2;
  float v = Kb[3]*Xj0 + Kb[4]*Xj1 + Kb[5]*Xj2;
  float z = Kb[6]*Xj0 + Kb[7]*Xj1 + Kb[8]*Xj2;
  float zs = (fabsf(z) < 1e-6f) ? 1e-6f : z;
  float pu = u/zs, pv = v/zs;
  float nx = 2.0f*pu/639.0f - 1.0f;
  float ny = 2.0f*pv/479.0f - 1.0f;
  *pnx = nx; *pny = ny;
  *invis = (z <= 1e-6f) || (fabsf(nx) > 1.0f) || (fabsf(ny) > 1.0f) || (dsrc <= 0.0f);
}

// ---------------- kernels ----------------

__global__ void k_gray(const float* __restrict__ imgs, float* __restrict__ gray) {
  int idx = blockIdx.x*256 + threadIdx.x;
  int b = idx / HWSZ, p = idx % HWSZ;
  const float* ib = imgs + (size_t)b*3*HWSZ;
  gray[idx] = 0.299f*ib[p] + 0.587f*ib[HWSZ+p] + 0.114f*ib[2*HWSZ+p];
}

__global__ void k_sobel(const float* __restrict__ gray, float* __restrict__ gx, float* __restrict__ gy) {
  int idx = blockIdx.x*256 + threadIdx.x;
  int b = idx / HWSZ, p = idx % HWSZ;
  int y = p / WW, x = p % WW;
  const float* g = gray + (size_t)b*HWSZ;
  const float kx[3][3] = {{-0.125f,0.f,0.125f},{-0.25f,0.f,0.25f},{-0.125f,0.f,0.125f}};
  float sx = 0.f, sy = 0.f;
  #pragma unroll
  for (int i = 0; i < 3; i++)
    #pragma unroll
    for (int j = 0; j < 3; j++) {
      int yy = y+i-1, xx = x+j-1;
      float v = (yy>=0 && yy<HH && xx>=0 && xx<WW) ? g[yy*WW+xx] : 0.f;
      sx += kx[i][j]*v;
      sy += kx[j][i]*v;
    }
  gx[idx] = sx; gy[idx] = sy;
}

__global__ void k_wprep(float* __restrict__ gw) {
  int t = threadIdx.x;
  if (t < 49) {
    double g[7];
    for (int q = 0; q < 7; q++) { double r = (double)(q-3); g[q] = exp(-(r*r)/2.0); }
    double s = 0.0;
    for (int q = 0; q < 7; q++) s += g[q];
    int i = t/7, j = t%7;
    gw[t] = (float)((g[i]/s)*(g[j]/s));
  }
}

// LDS-tiled 7x7 GFTT: 32x8 threads per block, halo 3 -> 38x14 tiles of gx,gy
__global__ void k_gftt(const float* __restrict__ gx, const float* __restrict__ gy,
                       const float* __restrict__ gw, float* __restrict__ resp) {
  __shared__ float w[49];
  __shared__ float sgx[14][38];
  __shared__ float sgy[14][38];
  if (threadIdx.x < 49) w[threadIdx.x] = gw[threadIdx.x];
  int bx = blockIdx.x*32, by = blockIdx.y*8, b = blockIdx.z;
  const float* gxb = gx + (size_t)b*HWSZ;
  const float* gyb = gy + (size_t)b*HWSZ;
  for (int e = threadIdx.x; e < 38*14; e += 256) {
    int lx = e % 38, ly = e / 38;
    int gxi = bx - 3 + lx, gyi = by - 3 + ly;
    bool in = (gxi>=0 && gxi<WW && gyi>=0 && gyi<HH);
    sgx[ly][lx] = in ? gxb[gyi*WW+gxi] : 0.f;   // conv zero-pad
    sgy[ly][lx] = in ? gyb[gyi*WW+gxi] : 0.f;
  }
  __syncthreads();
  int tx = threadIdx.x & 31, ty = threadIdx.x >> 5;
  float sxx = 0.f, syy = 0.f, sxy = 0.f;
  #pragma unroll
  for (int i = 0; i < 7; i++) {
    #pragma unroll
    for (int j = 0; j < 7; j++) {
      float a = sgx[ty+i][tx+j], c = sgy[ty+i][tx+j];
      float ww = w[i*7+j];
      sxx += ww*(a*a); syy += ww*(c*c); sxy += ww*(a*c);
    }
  }
  float tr = sxx + syy;
  float det = sxx*syy - sxy*sxy;
  float disc = fmaxf(tr*tr - 4.0f*det, 0.f);
  resp[(size_t)b*HWSZ + (by+ty)*WW + (bx+tx)] = 0.5f*(tr - sqrtf(disc));
}

// LDS-tiled 5x5 NMS: 32x8 threads, halo 2 -> 36x12 tile
__global__ void k_nms(const float* __restrict__ resp, float* __restrict__ c) {
  __shared__ float s[12][36];
  int bx = blockIdx.x*32, by = blockIdx.y*8, b = blockIdx.z;
  const float* r = resp + (size_t)b*HWSZ;
  for (int e = threadIdx.x; e < 36*12; e += 256) {
    int lx = e % 36, ly = e / 36;
    int gxi = bx - 2 + lx, gyi = by - 2 + ly;
    s[ly][lx] = (gxi>=0 && gxi<WW && gyi>=0 && gyi<HH) ? r[gyi*WW+gxi] : -INFINITY;
  }
  __syncthreads();
  int tx = threadIdx.x & 31, ty = threadIdx.x >> 5;
  float v = s[ty+2][tx+2];
  float mp = -INFINITY;
  #pragma unroll
  for (int dy = 0; dy < 5; dy++)
    #pragma unroll
    for (int dx = 0; dx < 5; dx++)
      mp = fmaxf(mp, s[ty+dy][tx+dx]);
  c[(size_t)b*HWSZ + (by+ty)*WW + (bx+tx)] = (v == mp) ? v : 0.f;
}

// atomic-free candidate extraction: one deterministic slot per 8x8 block;
// tie winners (rare) spill to overflow region via padded per-image counters.
__global__ void k_cand(const float* __restrict__ c, float* __restrict__ cv,
                       int* __restrict__ ci, int* __restrict__ ovf) {
  int blk = blockIdx.x;
  int b = blk / NBLK, r = blk % NBLK;
  int by = r / 80, bx = r % 80;
  int t = threadIdx.x;
  int y = by*8 + (t >> 3), x = bx*8 + (t & 7);
  float v = c[(size_t)b*HWSZ + y*WW + x];
  float bm = wredmaxf(v);
  bool win = (v > 0.f) && (v == bm);
  unsigned long long mask = __ballot(win);
  if (win) {
    int lane = t & 63;
    int rank = __popcll(mask & ((1ull << lane) - 1ull));
    int slot;
    if (rank == 0) slot = r;
    else slot = NBLK + atomicAdd(&ovf[b*64], 1);   // ties: ~never on random data
    if (slot < NCAND) { cv[b*NCAND+slot] = v; ci[b*NCAND+slot] = y*WW + x; }
  }
}

__global__ __launch_bounds__(1024) void k_topk(const float* __restrict__ cv, const int* __restrict__ ci,
                                               float* __restrict__ topv, int* __restrict__ topi) {
  extern __shared__ float smem[];
  float* sv = smem;
  int* si = (int*)(smem + NCAND);
  int b = blockIdx.x;
  for (int e = threadIdx.x; e < NCAND; e += 1024) {
    sv[e] = cv[b*NCAND+e];          // empty slots are (0.f, 0) from memset: rank below positives
    si[e] = ci[b*NCAND+e];
  }
  for (int k = 2; k <= NCAND; k <<= 1)
    for (int j = k >> 1; j > 0; j >>= 1) {
      __syncthreads();
      for (int i = threadIdx.x; i < NCAND; i += 1024) {
        int p = i ^ j;
        if (p > i) {
          float v1 = sv[i], v2 = sv[p]; int a1 = si[i], a2 = si[p];
          bool fb = (v1 > v2) || (v1 == v2 && a1 < a2);   // (desc, idx asc) = top_k order
          bool desc = ((i & k) == 0);
          if (desc != fb) { sv[i]=v2; sv[p]=v1; si[i]=a2; si[p]=a1; }
        }
      }
    }
  __syncthreads();
  for (int e = threadIdx.x; e < NN; e += 1024) { topv[b*NN+e] = sv[e]; topi[b*NN+e] = si[e]; }
}

__global__ void k_csrc(const float* __restrict__ topv, const int* __restrict__ topi,
                       const float* __restrict__ depths, const float* __restrict__ poses,
                       const float* __restrict__ Km, float* __restrict__ cXw, float* __restrict__ cd) {
  int t = blockIdx.x*256 + threadIdx.x;
  if (t >= BB*NN) return;
  int i = t / NN;
  if (topv[t] <= 0.f) { cd[t] = 0.f; return; }
  int idx = topi[t];
  float xs = (float)(idx % WW), ys = (float)(idx / WW);
  float cx = 2.0f*xs/639.0f - 1.0f;
  float cy = 2.0f*ys/479.0f - 1.0f;
  float px = (cx + 1.0f)*0.5f*639.0f;
  float py = (cy + 1.0f)*0.5f*479.0f;
  float Xw[3], d;
  src_compute(px, py, depths + (size_t)i*HWSZ, poses, Km, i, Xw, &d);
  cXw[t*3] = Xw[0]; cXw[t*3+1] = Xw[1]; cXw[t*3+2] = Xw[2]; cd[t] = d;
}

__global__ void k_scatter(const float* __restrict__ topv, const float* __restrict__ cXw,
                          const float* __restrict__ cd, const float* __restrict__ poses,
                          const float* __restrict__ Km, unsigned int* __restrict__ target) {
  int t = blockIdx.x*256 + threadIdx.x;   // < BB*BB*NN
  int n = t % NN; int ij = t / NN; int j = ij % BB; int i = ij / BB;
  int sn = i*NN + n;
  float val = topv[sn];
  if (val <= 0.f) return;
  float Xw[3] = {cXw[sn*3], cXw[sn*3+1], cXw[sn*3+2]};
  float d = cd[sn];
  float nx, ny; bool inv;
  project_to(poses, Km, j, Xw, d, &nx, &ny, &inv);
  if (inv) { nx = -2.0f; ny = -2.0f; }
  float fx = rintf((nx + 1.0f)*0.5f*639.0f);
  float fy = rintf((ny + 1.0f)*0.5f*479.0f);
  int wq = (int)fx, hq = (int)fy;
  if (wq < 0) return;
  int hc = min(max(hq, 0), HH-1), wc = min(max(wq, 0), WW-1);
  atomicMax(&target[(size_t)j*HWSZ + hc*WW + wc], __float_as_uint(val));
}

// LDS-tiled 5x5 maxpool + BCE
__global__ void k_bce(const float* __restrict__ target, const float* __restrict__ pnness,
                      double* __restrict__ acc) {
  __shared__ float s[12][36];
  int bx = blockIdx.x*32, by = blockIdx.y*8, b = blockIdx.z;
  const float* tb = target + (size_t)b*HWSZ;
  for (int e = threadIdx.x; e < 36*12; e += 256) {
    int lx = e % 36, ly = e / 36;
    int gxi = bx - 2 + lx, gyi = by - 2 + ly;
    s[ly][lx] = (gxi>=0 && gxi<WW && gyi>=0 && gyi<HH) ? tb[gyi*WW+gxi] : -INFINITY;
  }
  __syncthreads();
  int tx = threadIdx.x & 31, ty = threadIdx.x >> 5;
  float v = s[ty+2][tx+2];
  float mp = -INFINITY;
  #pragma unroll
  for (int dy = 0; dy < 5; dy++)
    #pragma unroll
    for (int dx = 0; dx < 5; dx++)
      mp = fmaxf(mp, s[ty+dy][tx+dx]);
  bool t = (v > 0.f) && (v == mp);
  float pv = pnness[(size_t)b*HWSZ + (by+ty)*WW + (bx+tx)];
  float term = t ? (-fmaxf(logf(pv), -100.0f)) : (-fmaxf(logf(1.0f - pv), -100.0f));
  double sum = blockRedSum256((double)term);
  if (threadIdx.x == 0) atomicAdd(&acc[1], sum);
}

__global__ void k_dn(const float* __restrict__ desc, float* __restrict__ dn) {
  int row = blockIdx.x;            // BB*NN rows
  int d = threadIdx.x;             // DDIM threads
  float v = desc[(size_t)row*DDIM + d];
  __shared__ float sp[4];
  __shared__ float den_s;
  float s = v*v;
  #pragma unroll
  for (int o = 32; o > 0; o >>= 1) s += __shfl_down(s, o, 64);
  int lane = threadIdx.x & 63, wid = threadIdx.x >> 6;
  if (lane == 0) sp[wid] = s;
  __syncthreads();
  if (threadIdx.x == 0) den_s = fmaxf(sqrtf(sp[0]+sp[1]+sp[2]+sp[3]), 1e-8f);
  __syncthreads();
  dn[(size_t)row*DDIM + d] = v / den_s;
}

__global__ void k_msrc(const float* __restrict__ points, const float* __restrict__ depths,
                       const float* __restrict__ poses, const float* __restrict__ Km,
                       float* __restrict__ mXw, float* __restrict__ md, float* __restrict__ psrc) {
  int t = blockIdx.x*256 + threadIdx.x;
  if (t >= BB*NN) return;
  int i = t / NN;
  float p0 = points[t*2], p1 = points[t*2+1];
  float px = (p0 + 1.0f)*0.5f*639.0f;
  float py = (p1 + 1.0f)*0.5f*479.0f;
  float Xw[3], d;
  src_compute(px, py, depths + (size_t)i*HWSZ, poses, Km, i, Xw, &d);
  mXw[t*3] = Xw[0]; mXw[t*3+1] = Xw[1]; mXw[t*3+2] = Xw[2];
  md[t] = d; psrc[t*2] = px; psrc[t*2+1] = py;
}

__global__ void k_pdst(const float* __restrict__ mXw, const float* __restrict__ md,
                       const float* __restrict__ poses, const float* __restrict__ Km,
                       float* __restrict__ pdst, int* __restrict__ minv) {
  int t = blockIdx.x*256 + threadIdx.x;   // (a*8+b)*500+m
  int m = t % NN; int ab = t / NN; int b = ab % BB; int a = ab / BB;
  int sn = a*NN + m;
  float Xw[3] = {mXw[sn*3], mXw[sn*3+1], mXw[sn*3+2]};
  float d = md[sn];
  float nx, ny; bool inv;
  project_to(poses, Km, b, Xw, d, &nx, &ny, &inv);
  pdst[t*2]   = (nx + 1.0f)*0.5f*639.0f;   // raw projections, like reference match path
  pdst[t*2+1] = (ny + 1.0f)*0.5f*479.0f;
  minv[t] = inv ? 1 : 0;
}

__global__ void k_match(const float* __restrict__ psrc, const float* __restrict__ pdst,
                        const int* __restrict__ minv, const float* __restrict__ dn,
                        double* __restrict__ acc) {
  __shared__ float spd[2*NN], ssrc[2*NN];
  __shared__ int sinv[NN];
  int ab = blockIdx.x; int b = ab % BB; int a = ab / BB;
  for (int e = threadIdx.x; e < NN; e += 256) {
    spd[e*2]   = pdst[(ab*NN+e)*2];
    spd[e*2+1] = pdst[(ab*NN+e)*2+1];
    sinv[e]    = minv[ab*NN+e];
    ssrc[e*2]   = psrc[(b*NN+e)*2];
    ssrc[e*2+1] = psrc[(b*NN+e)*2+1];
  }
  __syncthreads();
  double lsum = 0.0, lcnt = 0.0;
  for (int idx = threadIdx.x; idx < NN*NN; idx += 256) {
    int nn = idx / NN, mm = idx % NN;
    if (nn >= mm) continue;          // n < m
    if (sinv[nn]) continue;          // reference quirk: invis indexed by n
    float dx = ssrc[nn*2]   - spd[mm*2];
    float dy = ssrc[nn*2+1] - spd[mm*2+1];
    if (dx*dx + dy*dy <= 1.0f) {
      const float* da = dn + ((size_t)a*NN + mm)*DDIM;
      const float* db = dn + ((size_t)b*NN + nn)*DDIM;
      float dot = 0.f;
      for (int q = 0; q < DDIM; q++) dot += db[q]*da[q];
      lsum += (double)(1.0f - dot);
      lcnt += 1.0;
    }
  }
  double s = blockRedSum256(lsum);
  if (threadIdx.x == 0 && s != 0.0) atomicAdd(&acc[2], s);
  double c2 = blockRedSum256(lcnt);
  if (threadIdx.x == 0 && c2 != 0.0) atomicAdd(&acc[3], c2);
}

__global__ void k_dist(const float* __restrict__ dn, double* __restrict__ acc) {
  __shared__ float sA[25*DDIM];
  int b = blockIdx.x / 20, tile = blockIdx.x % 20;
  int n0 = tile*25;
  for (int e = threadIdx.x; e < 25*DDIM; e += 256)
    sA[e] = dn[((size_t)b*NN + n0 + e/DDIM)*DDIM + (e % DDIM)];
  __syncthreads();
  float accr[25];
  double lsum = 0.0;
  for (int mbase = 0; mbase < NN; mbase += 256) {
    int m = mbase + threadIdx.x;
    if (m < NN) {
      #pragma unroll
      for (int r = 0; r < 25; r++) accr[r] = 0.f;
      const float* dm = dn + ((size_t)b*NN + m)*DDIM;
      for (int q = 0; q < DDIM; q++) {
        float x = dm[q];
        #pragma unroll
        for (int r = 0; r < 25; r++) accr[r] += x*sA[r*DDIM + q];
      }
      #pragma unroll
      for (int r = 0; r < 25; r++) lsum += (double)fmaxf(accr[r], 0.f);
    }
  }
  double s = blockRedSum256(lsum);
  if (threadIdx.x == 0) atomicAdd(&acc[0], s);
}

__global__ void k_final(const double* __restrict__ acc, float* __restrict__ out) {
  float dist  = (float)(acc[0] / (double)(BB*NN*NN));
  float corn  = (float)(acc[1] / (double)BHW);
  float cnt   = fmaxf((float)acc[3], 1.0f);
  float match = (float)acc[2] / cnt;
  out[0] = 1.0f*dist + 1.0f*corn + 1.0f*match;
}

// ---------------- host ----------------

extern "C" void kernel_launch(void* const* d_in, const int* in_sizes, int n_in,
                              void* d_out, int out_size, void* d_ws, size_t ws_size,
                              hipStream_t stream) {
  (void)in_sizes; (void)n_in; (void)out_size; (void)ws_size;
  const float* desc      = (const float*)d_in[0];
  const float* points    = (const float*)d_in[1];
  const float* pointness = (const float*)d_in[2];
  const float* depths    = (const float*)d_in[3];
  const float* poses     = (const float*)d_in[4];
  const float* Kmat      = (const float*)d_in[5];
  const float* imgs      = (const float*)d_in[6];
  float* out = (float*)d_out;
  float* ws = (float*)d_ws;

  // workspace layout (~35 MB)
  float* bufA = ws;                          // gray -> resp
  float* bufB = ws + (size_t)BHW;            // gx -> nms'd c
  float* bufC = ws + 2*(size_t)BHW;          // gy -> target (scatter)
  float* cand_val = ws + 3*(size_t)BHW;      // B*8192
  int*   cand_idx = (int*)(cand_val + BB*NCAND);
  float* topv = (float*)(cand_idx + BB*NCAND);
  int*   topi = (int*)(topv + BB*NN);
  float* cXw  = (float*)(topi + BB*NN);
  float* cd   = cXw + BB*NN*3;
  float* mXw  = cd + BB*NN;
  float* md   = mXw + BB*NN*3;
  float* psrc = md + BB*NN;
  float* pdst = psrc + BB*NN*2;
  int*   minv = (int*)(pdst + BB*BB*NN*2);
  float* dn   = (float*)(minv + BB*BB*NN);
  int*   ovf  = (int*)(dn + (size_t)BB*NN*DDIM);   // 8 images x stride-64 counters
  double* acc = (double*)(ovf + BB*64);      // [0]=dist [1]=bce [2]=match_sum [3]=match_cnt
  float* gw   = (float*)(acc + 4);           // 49 gaussian weights

  // zero candidate slots + counters + accumulators (every call: determinism)
  hipMemsetAsync(cand_val, 0, (size_t)BB*NCAND*8, stream);
  hipMemsetAsync(ovf, 0, BB*64*sizeof(int) + 4*sizeof(double), stream);

  dim3 tgrid(WW/32, HH/8, BB);

  k_gray <<<BHW/256, 256, 0, stream>>>(imgs, bufA);
  k_sobel<<<BHW/256, 256, 0, stream>>>(bufA, bufB, bufC);
  k_wprep<<<1, 64, 0, stream>>>(gw);
  k_gftt <<<tgrid, 256, 0, stream>>>(bufB, bufC, gw, bufA);
  // bufC (gy) now free -> becomes target; zero it
  hipMemsetAsync(bufC, 0, (size_t)BHW*sizeof(float), stream);
  k_nms  <<<tgrid, 256, 0, stream>>>(bufA, bufB);
  k_cand <<<BB*NBLK, 64, 0, stream>>>(bufB, cand_val, cand_idx, ovf);
  k_topk <<<BB, 1024, NCAND*8, stream>>>(cand_val, cand_idx, topv, topi);
  k_csrc <<<(BB*NN + 255)/256, 256, 0, stream>>>(topv, topi, depths, poses, Kmat, cXw, cd);
  k_scatter<<<(BB*BB*NN)/256, 256, 0, stream>>>(topv, cXw, cd, poses, Kmat, (unsigned int*)bufC);
  k_bce  <<<tgrid, 256, 0, stream>>>(bufC, pointness, acc);
  k_dn   <<<BB*NN, DDIM, 0, stream>>>(desc, dn);
  k_msrc <<<(BB*NN + 255)/256, 256, 0, stream>>>(points, depths, poses, Kmat, mXw, md, psrc);
  k_pdst <<<(BB*BB*NN)/256, 256, 0, stream>>>(mXw, md, poses, Kmat, pdst, minv);
  k_match<<<BB*BB, 256, 0, stream>>>(psrc, pdst, minv, dn, acc);
  k_dist <<<BB*20, 256, 0, stream>>>(dn, acc);
  k_final<<<1, 1, 0, stream>>>(acc, out);
}

// Round 3
// 493.142 us; speedup vs baseline: 2.0645x; 1.1142x over previous
//
#include <hip/hip_runtime.h>
#include <math.h>

#define BB 8
#define NN 500
#define DDIM 256
#define HH 480
#define WW 640
#define HWSZ (HH*WW)        // 307200
#define BHW (BB*HWSZ)       // 2457600
#define NBLK 4800           // 8x8 blocks per image
#define NOVF 3392           // overflow candidate slots per image (NBLK+NOVF = 8192)
#define NTOT 8192

// ---------------- helpers ----------------

static __device__ __forceinline__ float wredmaxf(float v) {
  #pragma unroll
  for (int o = 1; o < 64; o <<= 1) v = fmaxf(v, __shfl_xor(v, o, 64));
  return v;
}

static __device__ __forceinline__ double blockRedSum256(double v) {
  __shared__ double sp[4];
  __syncthreads();
  #pragma unroll
  for (int o = 32; o > 0; o >>= 1) v += __shfl_down(v, o, 64);
  int lane = threadIdx.x & 63, wid = threadIdx.x >> 6;
  if (lane == 0) sp[wid] = v;
  __syncthreads();
  double r = 0.0;
  if (threadIdx.x == 0) r = sp[0] + sp[1] + sp[2] + sp[3];
  return r;
}

static __device__ __forceinline__ float bilin(const float* __restrict__ img, float px, float py) {
  float x = fminf(fmaxf(px, 0.0f), 639.0f);
  float y = fminf(fmaxf(py, 0.0f), 479.0f);
  float x0 = floorf(x), y0 = floorf(y);
  float x1 = fminf(x0 + 1.0f, 639.0f);
  float y1 = fminf(y0 + 1.0f, 479.0f);
  float wx = x - x0, wy = y - y0;
  int x0i = (int)x0, x1i = (int)x1, y0i = (int)y0, y1i = (int)y1;
  float v00 = img[y0i*WW + x0i], v01 = img[y0i*WW + x1i];
  float v10 = img[y1i*WW + x0i], v11 = img[y1i*WW + x1i];
  return v00*(1.0f-wx)*(1.0f-wy) + v01*wx*(1.0f-wy) + v10*(1.0f-wx)*wy + v11*wx*wy;
}

// world point from pixel (px,py) in image bimg; replicates reference op order
static __device__ void src_compute(float px, float py, const float* __restrict__ dep,
                                   const float* __restrict__ poses, const float* __restrict__ Km,
                                   int bimg, float* Xw, float* dout) {
  float d = bilin(dep, px, py);
  const float* Kb = Km + bimg*9;
  double a00=Kb[0],a01=Kb[1],a02=Kb[2],a10=Kb[3],a11=Kb[4],a12=Kb[5],a20=Kb[6],a21=Kb[7],a22=Kb[8];
  double det = a00*(a11*a22-a12*a21) - a01*(a10*a22-a12*a20) + a02*(a10*a21-a11*a20);
  double id = 1.0/det;
  float i00=(float)((a11*a22-a12*a21)*id), i01=(float)((a02*a21-a01*a22)*id), i02=(float)((a01*a12-a02*a11)*id);
  float i10=(float)((a12*a20-a10*a22)*id), i11=(float)((a00*a22-a02*a20)*id), i12=(float)((a02*a10-a00*a12)*id);
  float i20=(float)((a10*a21-a11*a20)*id), i21=(float)((a01*a20-a00*a21)*id), i22=(float)((a00*a11-a01*a10)*id);
  float c0 = i00*px + i01*py + i02;
  float c1 = i10*px + i11*py + i12;
  float c2 = i20*px + i21*py + i22;
  float X0 = d*c0, X1 = d*c1, X2 = d*c2;
  const float* P = poses + bimg*16;
  Xw[0] = (P[0]*X0 + P[1]*X1 + P[2]*X2)  + P[3];
  Xw[1] = (P[4]*X0 + P[5]*X1 + P[6]*X2)  + P[7];
  Xw[2] = (P[8]*X0 + P[9]*X1 + P[10]*X2) + P[11];
  *dout = d;
}

static __device__ void project_to(const float* __restrict__ poses, const float* __restrict__ Km,
                                  int j, const float* Xw, float dsrc,
                                  float* pnx, float* pny, bool* invis) {
  const float* P = poses + j*16;
  float d0 = Xw[0]-P[3], d1 = Xw[1]-P[7], d2 = Xw[2]-P[11];
  float Xj0 = P[0]*d0 + P[4]*d1 + P[8]*d2;
  float Xj1 = P[1]*d0 + P[5]*d1 + P[9]*d2;
  float Xj2 = P[2]*d0 + P[6]*d1 + P[10]*d2;
  const float* Kb = Km + j*9;
  float u = Kb[0]*Xj0 + Kb[1]*Xj1 + Kb[2]*Xj2;
  float v = Kb[3]*Xj0 + Kb[4]*Xj1 + Kb[5]*Xj2;
  float z = Kb[6]*Xj0 + Kb[7]*Xj1 + Kb[8]*Xj2;
  float zs = (fabsf(z) < 1e-6f) ? 1e-6f : z;
  float pu = u/zs, pv = v/zs;
  float nx = 2.0f*pu/639.0f - 1.0f;
  float ny = 2.0f*pv/479.0f - 1.0f;
  *pnx = nx; *pny = ny;
  *invis = (z <= 1e-6f) || (fabsf(nx) > 1.0f) || (fabsf(ny) > 1.0f) || (dsrc <= 0.0f);
}

// ---------------- kernels ----------------

// fused gray -> sobel -> 7x7 GFTT. 32x8 out tile, gray halo 4 (40x16),
// sobel halo 3 (38x14). Sobel outputs at out-of-image positions forced to 0
// (they are zero-padding for the gauss conv in the reference).
__global__ void k_gfused(const float* __restrict__ imgs, float* __restrict__ resp) {
  __shared__ float sgray[16][40];
  __shared__ float sgx[14][38];
  __shared__ float sgy[14][38];
  __shared__ float w[49];
  int bx = blockIdx.x*32, by = blockIdx.y*8, b = blockIdx.z;
  if (threadIdx.x < 49) {
    double g[7];
    for (int q = 0; q < 7; q++) { double r = (double)(q-3); g[q] = exp(-(r*r)/2.0); }
    double s = 0.0;
    for (int q = 0; q < 7; q++) s += g[q];
    int i = threadIdx.x/7, j = threadIdx.x%7;
    w[threadIdx.x] = (float)((g[i]/s)*(g[j]/s));
  }
  const float* ib = imgs + (size_t)b*3*HWSZ;
  for (int e = threadIdx.x; e < 40*16; e += 256) {
    int lx = e % 40, ly = e / 40;
    int gxi = bx - 4 + lx, gyi = by - 4 + ly;
    float v = 0.f;
    if (gxi>=0 && gxi<WW && gyi>=0 && gyi<HH) {
      int p = gyi*WW + gxi;
      v = 0.299f*ib[p] + 0.587f*ib[HWSZ+p] + 0.114f*ib[2*HWSZ+p];
    }
    sgray[ly][lx] = v;
  }
  __syncthreads();
  const float kx[3][3] = {{-0.125f,0.f,0.125f},{-0.25f,0.f,0.25f},{-0.125f,0.f,0.125f}};
  for (int e = threadIdx.x; e < 38*14; e += 256) {
    int lx = e % 38, ly = e / 38;
    int X = bx - 3 + lx, Y = by - 3 + ly;
    float sx = 0.f, sy = 0.f;
    #pragma unroll
    for (int i = 0; i < 3; i++)
      #pragma unroll
      for (int j = 0; j < 3; j++) {
        float v = sgray[ly+i][lx+j];
        sx += kx[i][j]*v;
        sy += kx[j][i]*v;
      }
    bool in = (X>=0 && X<WW && Y>=0 && Y<HH);
    sgx[ly][lx] = in ? sx : 0.f;
    sgy[ly][lx] = in ? sy : 0.f;
  }
  __syncthreads();
  int tx = threadIdx.x & 31, ty = threadIdx.x >> 5;
  float sxx = 0.f, syy = 0.f, sxy = 0.f;
  #pragma unroll
  for (int i = 0; i < 7; i++) {
    #pragma unroll
    for (int j = 0; j < 7; j++) {
      float a = sgx[ty+i][tx+j], c = sgy[ty+i][tx+j];
      float ww = w[i*7+j];
      sxx += ww*(a*a); syy += ww*(c*c); sxy += ww*(a*c);
    }
  }
  float tr = sxx + syy;
  float det = sxx*syy - sxy*sxy;
  float disc = fmaxf(tr*tr - 4.0f*det, 0.f);
  resp[(size_t)b*HWSZ + (by+ty)*WW + (bx+tx)] = 0.5f*(tr - sqrtf(disc));
}

// fused 5x5 NMS + per-8x8-block candidate extraction (+ zero the scatter target)
__global__ void k_nmscand(const float* __restrict__ resp, float* __restrict__ cv,
                          int* __restrict__ ci, float* __restrict__ cvo,
                          int* __restrict__ cio, int* __restrict__ ovf,
                          float* __restrict__ target) {
  __shared__ float s[12][36];
  __shared__ float c32[8][32];
  int bx = blockIdx.x*32, by = blockIdx.y*8, b = blockIdx.z;
  const float* r = resp + (size_t)b*HWSZ;
  for (int e = threadIdx.x; e < 36*12; e += 256) {
    int lx = e % 36, ly = e / 36;
    int gxi = bx - 2 + lx, gyi = by - 2 + ly;
    s[ly][lx] = (gxi>=0 && gxi<WW && gyi>=0 && gyi<HH) ? r[gyi*WW+gxi] : -INFINITY;
  }
  __syncthreads();
  int tx = threadIdx.x & 31, ty = threadIdx.x >> 5;
  float v = s[ty+2][tx+2];
  float mp = -INFINITY;
  #pragma unroll
  for (int dy = 0; dy < 5; dy++)
    #pragma unroll
    for (int dx = 0; dx < 5; dx++)
      mp = fmaxf(mp, s[ty+dy][tx+dx]);
  c32[ty][tx] = (v == mp) ? v : 0.f;
  target[(size_t)b*HWSZ + (by+ty)*WW + (bx+tx)] = 0.f;   // zero scatter target
  __syncthreads();
  // wave w (0..3) reduces 8x8 block w of this tile
  int wv = threadIdx.x >> 6, lane = threadIdx.x & 63;
  int ltx = wv*8 + (lane & 7), lty = lane >> 3;
  float cval = c32[lty][ltx];
  float bm = wredmaxf(cval);
  bool win = (cval > 0.f) && (cval == bm);
  unsigned long long mask = __ballot(win);
  int rblk = blockIdx.y*80 + blockIdx.x*4 + wv;          // global 8x8-block index
  int gidx = (by + lty)*WW + (bx + ltx);
  if (mask == 0ull) {
    if (lane == 0) { cv[b*NBLK+rblk] = 0.f; ci[b*NBLK+rblk] = 0; }
  } else if (win) {
    int rank = __popcll(mask & ((1ull << lane) - 1ull));
    if (rank == 0) { cv[b*NBLK+rblk] = cval; ci[b*NBLK+rblk] = gidx; }
    else {
      int pos = atomicAdd(&ovf[b*64], 1);
      if (pos < NOVF) { cvo[b*NOVF+pos] = cval; cio[b*NOVF+pos] = gidx; }
    }
  }
}

// top-500 selection via MSB-first radix select on 64-bit keys
// key = (float_bits << 32) | ~idx  -> top-k order == (value desc, idx asc).
// Keys are distinct except all-identical empty (0,0) slots; >T/==T split
// makes the selection exact regardless.
__global__ __launch_bounds__(1024) void k_topsel(const float* __restrict__ cv, const int* __restrict__ ci,
                                                 const float* __restrict__ cvo, const int* __restrict__ cio,
                                                 float* __restrict__ topv, int* __restrict__ topi) {
  __shared__ unsigned int hist[256];
  __shared__ unsigned long long prefix_s;
  __shared__ int kk_s, cgt_s, ceq_s;
  int b = blockIdx.x;
  unsigned long long kreg[8];
  #pragma unroll
  for (int q = 0; q < 8; q++) {
    int e = threadIdx.x + q*1024;
    float v; unsigned int idx;
    if (e < NBLK) { v = cv[b*NBLK+e];      idx = (unsigned int)ci[b*NBLK+e]; }
    else          { v = cvo[b*NOVF+e-NBLK]; idx = (unsigned int)cio[b*NOVF+e-NBLK]; }
    kreg[q] = ((unsigned long long)__float_as_uint(v) << 32) | (0xFFFFFFFFu - idx);
  }
  if (threadIdx.x == 0) { prefix_s = 0ull; kk_s = NN; }
  for (int round = 0; round < 8; round++) {
    int shift = 56 - 8*round;
    if (threadIdx.x < 256) hist[threadIdx.x] = 0u;
    __syncthreads();
    unsigned long long prefix = prefix_s;
    unsigned long long himask = (round == 0) ? 0ull : (~0ull << (shift + 8));
    #pragma unroll
    for (int q = 0; q < 8; q++) {
      if ((kreg[q] & himask) == prefix) {
        unsigned int d = (unsigned int)((kreg[q] >> shift) & 255ull);
        atomicAdd(&hist[d], 1u);
      }
    }
    __syncthreads();
    if (threadIdx.x == 0) {
      int kk = kk_s, acc = 0, chosen = 0;
      for (int d = 255; d >= 0; --d) {
        int h = (int)hist[d];
        if (acc + h >= kk) { chosen = d; kk_s = kk - acc; break; }
        acc += h;
      }
      prefix_s = prefix | ((unsigned long long)chosen << shift);
    }
    __syncthreads();
  }
  unsigned long long T = prefix_s;
  int kk = kk_s;                    // how many ==T to take
  if (threadIdx.x == 0) { cgt_s = 0; ceq_s = 0; }
  __syncthreads();
  #pragma unroll
  for (int q = 0; q < 8; q++) {
    unsigned long long key = kreg[q];
    int slot = -1;
    if (key > T) slot = atomicAdd(&cgt_s, 1);
    else if (key == T) {
      int p = atomicAdd(&ceq_s, 1);
      if (p < kk) slot = (NN-1) - p;
    }
    if (slot >= 0) {
      topv[b*NN+slot] = __uint_as_float((unsigned int)(key >> 32));
      topi[b*NN+slot] = (int)(0xFFFFFFFFu - (unsigned int)(key & 0xFFFFFFFFull));
    }
  }
}

// fused source-point compute + 8-way projection scatter
__global__ void k_scatfuse(const float* __restrict__ topv, const int* __restrict__ topi,
                           const float* __restrict__ depths, const float* __restrict__ poses,
                           const float* __restrict__ Km, unsigned int* __restrict__ target) {
  int t = blockIdx.x*256 + threadIdx.x;
  if (t >= BB*NN) return;
  int i = t / NN;
  float val = topv[t];
  if (val <= 0.f) return;
  int idx = topi[t];
  float xs = (float)(idx % WW), ys = (float)(idx / WW);
  float cx = 2.0f*xs/639.0f - 1.0f;
  float cy = 2.0f*ys/479.0f - 1.0f;
  float px = (cx + 1.0f)*0.5f*639.0f;
  float py = (cy + 1.0f)*0.5f*479.0f;
  float Xw[3], d;
  src_compute(px, py, depths + (size_t)i*HWSZ, poses, Km, i, Xw, &d);
  for (int j = 0; j < BB; j++) {
    float nx, ny; bool inv;
    project_to(poses, Km, j, Xw, d, &nx, &ny, &inv);
    if (inv) { nx = -2.0f; ny = -2.0f; }
    float fx = rintf((nx + 1.0f)*0.5f*639.0f);
    float fy = rintf((ny + 1.0f)*0.5f*479.0f);
    int wq = (int)fx, hq = (int)fy;
    if (wq < 0) continue;
    int hc = min(max(hq, 0), HH-1), wc = min(max(wq, 0), WW-1);
    atomicMax(&target[(size_t)j*HWSZ + hc*WW + wc], __float_as_uint(val));
  }
}

// LDS-tiled 5x5 maxpool + BCE
__global__ void k_bce(const float* __restrict__ target, const float* __restrict__ pnness,
                      double* __restrict__ acc) {
  __shared__ float s[12][36];
  int bx = blockIdx.x*32, by = blockIdx.y*8, b = blockIdx.z;
  const float* tb = target + (size_t)b*HWSZ;
  for (int e = threadIdx.x; e < 36*12; e += 256) {
    int lx = e % 36, ly = e / 36;
    int gxi = bx - 2 + lx, gyi = by - 2 + ly;
    s[ly][lx] = (gxi>=0 && gxi<WW && gyi>=0 && gyi<HH) ? tb[gyi*WW+gxi] : -INFINITY;
  }
  __syncthreads();
  int tx = threadIdx.x & 31, ty = threadIdx.x >> 5;
  float v = s[ty+2][tx+2];
  float mp = -INFINITY;
  #pragma unroll
  for (int dy = 0; dy < 5; dy++)
    #pragma unroll
    for (int dx = 0; dx < 5; dx++)
      mp = fmaxf(mp, s[ty+dy][tx+dx]);
  bool t = (v > 0.f) && (v == mp);
  float pv = pnness[(size_t)b*HWSZ + (by+ty)*WW + (bx+tx)];
  float term = t ? (-fmaxf(logf(pv), -100.0f)) : (-fmaxf(logf(1.0f - pv), -100.0f));
  double sum = blockRedSum256((double)term);
  if (threadIdx.x == 0) atomicAdd(&acc[1], sum);
}

__global__ void k_dn(const float* __restrict__ desc, float* __restrict__ dn) {
  int row = blockIdx.x;
  int d = threadIdx.x;
  float v = desc[(size_t)row*DDIM + d];
  __shared__ float sp[4];
  __shared__ float den_s;
  float s = v*v;
  #pragma unroll
  for (int o = 32; o > 0; o >>= 1) s += __shfl_down(s, o, 64);
  int lane = threadIdx.x & 63, wid = threadIdx.x >> 6;
  if (lane == 0) sp[wid] = s;
  __syncthreads();
  if (threadIdx.x == 0) den_s = fmaxf(sqrtf(sp[0]+sp[1]+sp[2]+sp[3]), 1e-8f);
  __syncthreads();
  dn[(size_t)row*DDIM + d] = v / den_s;
}

// fused match source compute + 8-way projection
__global__ void k_msrcdst(const float* __restrict__ points, const float* __restrict__ depths,
                          const float* __restrict__ poses, const float* __restrict__ Km,
                          float* __restrict__ psrc, float* __restrict__ pdst, int* __restrict__ minv) {
  int t = blockIdx.x*256 + threadIdx.x;
  if (t >= BB*NN) return;
  int a = t / NN, m = t % NN;
  float p0 = points[t*2], p1 = points[t*2+1];
  float px = (p0 + 1.0f)*0.5f*639.0f;
  float py = (p1 + 1.0f)*0.5f*479.0f;
  float Xw[3], d;
  src_compute(px, py, depths + (size_t)a*HWSZ, poses, Km, a, Xw, &d);
  psrc[t*2] = px; psrc[t*2+1] = py;
  for (int b = 0; b < BB; b++) {
    float nx, ny; bool inv;
    project_to(poses, Km, b, Xw, d, &nx, &ny, &inv);
    int o = (a*BB + b)*NN + m;
    pdst[o*2]   = (nx + 1.0f)*0.5f*639.0f;   // raw projections, like reference match path
    pdst[o*2+1] = (ny + 1.0f)*0.5f*479.0f;
    minv[o] = inv ? 1 : 0;
  }
}

__global__ void k_match(const float* __restrict__ psrc, const float* __restrict__ pdst,
                        const int* __restrict__ minv, const float* __restrict__ dn,
                        double* __restrict__ acc) {
  __shared__ float spd[2*NN], ssrc[2*NN];
  __shared__ int sinv[NN];
  int ab = blockIdx.x; int b = ab % BB; int a = ab / BB;
  for (int e = threadIdx.x; e < NN; e += 256) {
    spd[e*2]   = pdst[(ab*NN+e)*2];
    spd[e*2+1] = pdst[(ab*NN+e)*2+1];
    sinv[e]    = minv[ab*NN+e];
    ssrc[e*2]   = psrc[(b*NN+e)*2];
    ssrc[e*2+1] = psrc[(b*NN+e)*2+1];
  }
  __syncthreads();
  double lsum = 0.0, lcnt = 0.0;
  for (int idx = threadIdx.x; idx < NN*NN; idx += 256) {
    int nn = idx / NN, mm = idx % NN;
    if (nn >= mm) continue;          // n < m
    if (sinv[nn]) continue;          // reference quirk: invis indexed by n
    float dx = ssrc[nn*2]   - spd[mm*2];
    float dy = ssrc[nn*2+1] - spd[mm*2+1];
    if (dx*dx + dy*dy <= 1.0f) {
      const float* da = dn + ((size_t)a*NN + mm)*DDIM;
      const float* db = dn + ((size_t)b*NN + nn)*DDIM;
      float dot = 0.f;
      for (int q = 0; q < DDIM; q++) dot += db[q]*da[q];
      lsum += (double)(1.0f - dot);
      lcnt += 1.0;
    }
  }
  double s = blockRedSum256(lsum);
  if (threadIdx.x == 0 && s != 0.0) atomicAdd(&acc[2], s);
  double c2 = blockRedSum256(lcnt);
  if (threadIdx.x == 0 && c2 != 0.0) atomicAdd(&acc[3], c2);
}

__global__ void k_dist(const float* __restrict__ dn, double* __restrict__ acc) {
  __shared__ float sA[25*DDIM];
  int b = blockIdx.x / 20, tile = blockIdx.x % 20;
  int n0 = tile*25;
  for (int e = threadIdx.x; e < 25*DDIM; e += 256)
    sA[e] = dn[((size_t)b*NN + n0 + e/DDIM)*DDIM + (e % DDIM)];
  __syncthreads();
  float accr[25];
  double lsum = 0.0;
  for (int mbase = 0; mbase < NN; mbase += 256) {
    int m = mbase + threadIdx.x;
    if (m < NN) {
      #pragma unroll
      for (int r = 0; r < 25; r++) accr[r] = 0.f;
      const float* dm = dn + ((size_t)b*NN + m)*DDIM;
      for (int q = 0; q < DDIM; q++) {
        float x = dm[q];
        #pragma unroll
        for (int r = 0; r < 25; r++) accr[r] += x*sA[r*DDIM + q];
      }
      #pragma unroll
      for (int r = 0; r < 25; r++) lsum += (double)fmaxf(accr[r], 0.f);
    }
  }
  double s = blockRedSum256(lsum);
  if (threadIdx.x == 0) atomicAdd(&acc[0], s);
}

__global__ void k_final(const double* __restrict__ acc, float* __restrict__ out) {
  float dist  = (float)(acc[0] / (double)(BB*NN*NN));
  float corn  = (float)(acc[1] / (double)BHW);
  float cnt   = fmaxf((float)acc[3], 1.0f);
  float match = (float)acc[2] / cnt;
  out[0] = 1.0f*dist + 1.0f*corn + 1.0f*match;
}

// ---------------- host ----------------

extern "C" void kernel_launch(void* const* d_in, const int* in_sizes, int n_in,
                              void* d_out, int out_size, void* d_ws, size_t ws_size,
                              hipStream_t stream) {
  (void)in_sizes; (void)n_in; (void)out_size; (void)ws_size;
  const float* desc      = (const float*)d_in[0];
  const float* points    = (const float*)d_in[1];
  const float* pointness = (const float*)d_in[2];
  const float* depths    = (const float*)d_in[3];
  const float* poses     = (const float*)d_in[4];
  const float* Kmat      = (const float*)d_in[5];
  const float* imgs      = (const float*)d_in[6];
  float* out = (float*)d_out;
  float* ws = (float*)d_ws;

  // workspace layout (~25 MB)
  float* bufA = ws;                          // resp
  float* bufC = ws + (size_t)BHW;            // scatter target
  float* cv_main = ws + 2*(size_t)BHW;       // 8 x 4800
  int*   ci_main = (int*)(cv_main + BB*NBLK);
  // --- contiguous zeroed region start ---
  float* cv_ovf  = (float*)(ci_main + BB*NBLK);   // 8 x 3392
  int*   ci_ovf  = (int*)(cv_ovf + BB*NOVF);
  int*   ovf     = (int*)(ci_ovf + BB*NOVF);      // 8 x stride-64 counters
  double* acc    = (double*)(ovf + BB*64);        // [0]=dist [1]=bce [2]=match_sum [3]=match_cnt
  // --- contiguous zeroed region end ---
  float* topv = (float*)(acc + 4);
  int*   topi = (int*)(topv + BB*NN);
  float* psrc = (float*)(topi + BB*NN);
  float* pdst = psrc + BB*NN*2;
  int*   minv = (int*)(pdst + BB*BB*NN*2);
  float* dn   = (float*)(minv + BB*BB*NN);        // 8*500*256 floats

  size_t zbytes = (size_t)BB*NOVF*8 + (size_t)BB*64*4 + 4*sizeof(double);
  hipMemsetAsync(cv_ovf, 0, zbytes, stream);

  dim3 tgrid(WW/32, HH/8, BB);

  k_gfused <<<tgrid, 256, 0, stream>>>(imgs, bufA);
  k_nmscand<<<tgrid, 256, 0, stream>>>(bufA, cv_main, ci_main, cv_ovf, ci_ovf, ovf, bufC);
  k_topsel <<<BB, 1024, 0, stream>>>(cv_main, ci_main, cv_ovf, ci_ovf, topv, topi);
  k_scatfuse<<<(BB*NN + 255)/256, 256, 0, stream>>>(topv, topi, depths, poses, Kmat, (unsigned int*)bufC);
  k_bce   <<<tgrid, 256, 0, stream>>>(bufC, pointness, acc);
  k_dn    <<<BB*NN, DDIM, 0, stream>>>(desc, dn);
  k_msrcdst<<<(BB*NN + 255)/256, 256, 0, stream>>>(points, depths, poses, Kmat, psrc, pdst, minv);
  k_match <<<BB*BB, 256, 0, stream>>>(psrc, pdst, minv, dn, acc);
  k_dist  <<<BB*20, 256, 0, stream>>>(dn, acc);
  k_final <<<1, 1, 0, stream>>>(acc, out);
}

// Round 4
// 273.904 us; speedup vs baseline: 3.7170x; 1.8004x over previous
//
#include <hip/hip_runtime.h>
#include <math.h>

#define BB 8
#define NN 500
#define DDIM 256
#define HH 480
#define WW 640
#define HWSZ (HH*WW)        // 307200
#define BHW (BB*HWSZ)       // 2457600
#define NBLK 4800           // 8x8 blocks per image
#define NOVF 3392           // overflow candidate slots per image (NBLK+NOVF = 8192)
#define MSPLIT 8
#define MCH 63              // ceil(500/8)

// ---------------- helpers ----------------

static __device__ __forceinline__ float wredmaxf(float v) {
  #pragma unroll
  for (int o = 1; o < 64; o <<= 1) v = fmaxf(v, __shfl_xor(v, o, 64));
  return v;
}

static __device__ __forceinline__ double blockRedSum256(double v) {
  __shared__ double sp[4];
  __syncthreads();
  #pragma unroll
  for (int o = 32; o > 0; o >>= 1) v += __shfl_down(v, o, 64);
  int lane = threadIdx.x & 63, wid = threadIdx.x >> 6;
  if (lane == 0) sp[wid] = v;
  __syncthreads();
  double r = 0.0;
  if (threadIdx.x == 0) r = sp[0] + sp[1] + sp[2] + sp[3];
  return r;
}

static __device__ __forceinline__ float bilin(const float* __restrict__ img, float px, float py) {
  float x = fminf(fmaxf(px, 0.0f), 639.0f);
  float y = fminf(fmaxf(py, 0.0f), 479.0f);
  float x0 = floorf(x), y0 = floorf(y);
  float x1 = fminf(x0 + 1.0f, 639.0f);
  float y1 = fminf(y0 + 1.0f, 479.0f);
  float wx = x - x0, wy = y - y0;
  int x0i = (int)x0, x1i = (int)x1, y0i = (int)y0, y1i = (int)y1;
  float v00 = img[y0i*WW + x0i], v01 = img[y0i*WW + x1i];
  float v10 = img[y1i*WW + x0i], v11 = img[y1i*WW + x1i];
  return v00*(1.0f-wx)*(1.0f-wy) + v01*wx*(1.0f-wy) + v10*(1.0f-wx)*wy + v11*wx*wy;
}

// world point from pixel (px,py) in image bimg; replicates reference op order
static __device__ void src_compute(float px, float py, const float* __restrict__ dep,
                                   const float* __restrict__ poses, const float* __restrict__ Km,
                                   int bimg, float* Xw, float* dout) {
  float d = bilin(dep, px, py);
  const float* Kb = Km + bimg*9;
  double a00=Kb[0],a01=Kb[1],a02=Kb[2],a10=Kb[3],a11=Kb[4],a12=Kb[5],a20=Kb[6],a21=Kb[7],a22=Kb[8];
  double det = a00*(a11*a22-a12*a21) - a01*(a10*a22-a12*a20) + a02*(a10*a21-a11*a20);
  double id = 1.0/det;
  float i00=(float)((a11*a22-a12*a21)*id), i01=(float)((a02*a21-a01*a22)*id), i02=(float)((a01*a12-a02*a11)*id);
  float i10=(float)((a12*a20-a10*a22)*id), i11=(float)((a00*a22-a02*a20)*id), i12=(float)((a02*a10-a00*a12)*id);
  float i20=(float)((a10*a21-a11*a20)*id), i21=(float)((a01*a20-a00*a21)*id), i22=(float)((a00*a11-a01*a10)*id);
  float c0 = i00*px + i01*py + i02;
  float c1 = i10*px + i11*py + i12;
  float c2 = i20*px + i21*py + i22;
  float X0 = d*c0, X1 = d*c1, X2 = d*c2;
  const float* P = poses + bimg*16;
  Xw[0] = (P[0]*X0 + P[1]*X1 + P[2]*X2)  + P[3];
  Xw[1] = (P[4]*X0 + P[5]*X1 + P[6]*X2)  + P[7];
  Xw[2] = (P[8]*X0 + P[9]*X1 + P[10]*X2) + P[11];
  *dout = d;
}

static __device__ void project_to(const float* __restrict__ poses, const float* __restrict__ Km,
                                  int j, const float* Xw, float dsrc,
                                  float* pnx, float* pny, bool* invis) {
  const float* P = poses + j*16;
  float d0 = Xw[0]-P[3], d1 = Xw[1]-P[7], d2 = Xw[2]-P[11];
  float Xj0 = P[0]*d0 + P[4]*d1 + P[8]*d2;
  float Xj1 = P[1]*d0 + P[5]*d1 + P[9]*d2;
  float Xj2 = P[2]*d0 + P[6]*d1 + P[10]*d2;
  const float* Kb = Km + j*9;
  float u = Kb[0]*Xj0 + Kb[1]*Xj1 + Kb[2]*Xj2;
  float v = Kb[3]*Xj0 + Kb[4]*Xj1 + Kb[5]*Xj2;
  float z = Kb[6]*Xj0 + Kb[7]*Xj1 + Kb[8]*Xj2;
  float zs = (fabsf(z) < 1e-6f) ? 1e-6f : z;
  float pu = u/zs, pv = v/zs;
  float nx = 2.0f*pu/639.0f - 1.0f;
  float ny = 2.0f*pv/479.0f - 1.0f;
  *pnx = nx; *pny = ny;
  *invis = (z <= 1e-6f) || (fabsf(nx) > 1.0f) || (fabsf(ny) > 1.0f) || (dsrc <= 0.0f);
}

// ---------------- kernels ----------------

// fused gray -> sobel -> 7x7 GFTT. 32x8 out tile, gray halo 4 (40x16),
// sobel halo 3 (38x14). Sobel outputs at out-of-image positions forced to 0.
__global__ void k_gfused(const float* __restrict__ imgs, float* __restrict__ resp) {
  __shared__ float sgray[16][40];
  __shared__ float sgx[14][38];
  __shared__ float sgy[14][38];
  __shared__ float w[49];
  int bx = blockIdx.x*32, by = blockIdx.y*8, b = blockIdx.z;
  if (threadIdx.x < 49) {
    double g[7];
    for (int q = 0; q < 7; q++) { double r = (double)(q-3); g[q] = exp(-(r*r)/2.0); }
    double s = 0.0;
    for (int q = 0; q < 7; q++) s += g[q];
    int i = threadIdx.x/7, j = threadIdx.x%7;
    w[threadIdx.x] = (float)((g[i]/s)*(g[j]/s));
  }
  const float* ib = imgs + (size_t)b*3*HWSZ;
  for (int e = threadIdx.x; e < 40*16; e += 256) {
    int lx = e % 40, ly = e / 40;
    int gxi = bx - 4 + lx, gyi = by - 4 + ly;
    float v = 0.f;
    if (gxi>=0 && gxi<WW && gyi>=0 && gyi<HH) {
      int p = gyi*WW + gxi;
      v = 0.299f*ib[p] + 0.587f*ib[HWSZ+p] + 0.114f*ib[2*HWSZ+p];
    }
    sgray[ly][lx] = v;
  }
  __syncthreads();
  const float kx[3][3] = {{-0.125f,0.f,0.125f},{-0.25f,0.f,0.25f},{-0.125f,0.f,0.125f}};
  for (int e = threadIdx.x; e < 38*14; e += 256) {
    int lx = e % 38, ly = e / 38;
    int X = bx - 3 + lx, Y = by - 3 + ly;
    float sx = 0.f, sy = 0.f;
    #pragma unroll
    for (int i = 0; i < 3; i++)
      #pragma unroll
      for (int j = 0; j < 3; j++) {
        float v = sgray[ly+i][lx+j];
        sx += kx[i][j]*v;
        sy += kx[j][i]*v;
      }
    bool in = (X>=0 && X<WW && Y>=0 && Y<HH);
    sgx[ly][lx] = in ? sx : 0.f;
    sgy[ly][lx] = in ? sy : 0.f;
  }
  __syncthreads();
  int tx = threadIdx.x & 31, ty = threadIdx.x >> 5;
  float sxx = 0.f, syy = 0.f, sxy = 0.f;
  #pragma unroll
  for (int i = 0; i < 7; i++) {
    #pragma unroll
    for (int j = 0; j < 7; j++) {
      float a = sgx[ty+i][tx+j], c = sgy[ty+i][tx+j];
      float ww = w[i*7+j];
      sxx += ww*(a*a); syy += ww*(c*c); sxy += ww*(a*c);
    }
  }
  float tr = sxx + syy;
  float det = sxx*syy - sxy*sxy;
  float disc = fmaxf(tr*tr - 4.0f*det, 0.f);
  resp[(size_t)b*HWSZ + (by+ty)*WW + (bx+tx)] = 0.5f*(tr - sqrtf(disc));
}

// fused 5x5 NMS + per-8x8-block candidate extraction (+ zero the scatter target)
__global__ void k_nmscand(const float* __restrict__ resp, float* __restrict__ cv,
                          int* __restrict__ ci, float* __restrict__ cvo,
                          int* __restrict__ cio, int* __restrict__ ovf,
                          float* __restrict__ target) {
  __shared__ float s[12][36];
  __shared__ float c32[8][32];
  int bx = blockIdx.x*32, by = blockIdx.y*8, b = blockIdx.z;
  const float* r = resp + (size_t)b*HWSZ;
  for (int e = threadIdx.x; e < 36*12; e += 256) {
    int lx = e % 36, ly = e / 36;
    int gxi = bx - 2 + lx, gyi = by - 2 + ly;
    s[ly][lx] = (gxi>=0 && gxi<WW && gyi>=0 && gyi<HH) ? r[gyi*WW+gxi] : -INFINITY;
  }
  __syncthreads();
  int tx = threadIdx.x & 31, ty = threadIdx.x >> 5;
  float v = s[ty+2][tx+2];
  float mp = -INFINITY;
  #pragma unroll
  for (int dy = 0; dy < 5; dy++)
    #pragma unroll
    for (int dx = 0; dx < 5; dx++)
      mp = fmaxf(mp, s[ty+dy][tx+dx]);
  c32[ty][tx] = (v == mp) ? v : 0.f;
  target[(size_t)b*HWSZ + (by+ty)*WW + (bx+tx)] = 0.f;   // zero scatter target
  __syncthreads();
  int wv = threadIdx.x >> 6, lane = threadIdx.x & 63;
  int ltx = wv*8 + (lane & 7), lty = lane >> 3;
  float cval = c32[lty][ltx];
  float bm = wredmaxf(cval);
  bool win = (cval > 0.f) && (cval == bm);
  unsigned long long mask = __ballot(win);
  int rblk = blockIdx.y*80 + blockIdx.x*4 + wv;          // global 8x8-block index
  int gidx = (by + lty)*WW + (bx + ltx);
  if (mask == 0ull) {
    if (lane == 0) { cv[b*NBLK+rblk] = 0.f; ci[b*NBLK+rblk] = 0; }
  } else if (win) {
    int rank = __popcll(mask & ((1ull << lane) - 1ull));
    if (rank == 0) { cv[b*NBLK+rblk] = cval; ci[b*NBLK+rblk] = gidx; }
    else {
      int pos = atomicAdd(&ovf[b*64], 1);
      if (pos < NOVF) { cvo[b*NOVF+pos] = cval; cio[b*NOVF+pos] = gidx; }
    }
  }
}

// top-500 selection via MSB-first radix select on 64-bit keys
// key = (float_bits << 32) | ~idx  -> top-k order == (value desc, idx asc).
__global__ __launch_bounds__(1024) void k_topsel(const float* __restrict__ cv, const int* __restrict__ ci,
                                                 const float* __restrict__ cvo, const int* __restrict__ cio,
                                                 float* __restrict__ topv, int* __restrict__ topi) {
  __shared__ unsigned int hist[256];
  __shared__ unsigned int ss[257];
  __shared__ unsigned long long prefix_s;
  __shared__ int kk_s, cgt_s, ceq_s;
  int b = blockIdx.x;
  unsigned long long kreg[8];
  #pragma unroll
  for (int q = 0; q < 8; q++) {
    int e = threadIdx.x + q*1024;
    float v; unsigned int idx;
    if (e < NBLK) { v = cv[b*NBLK+e];       idx = (unsigned int)ci[b*NBLK+e]; }
    else          { v = cvo[b*NOVF+e-NBLK]; idx = (unsigned int)cio[b*NOVF+e-NBLK]; }
    kreg[q] = ((unsigned long long)__float_as_uint(v) << 32) | (0xFFFFFFFFu - idx);
  }
  if (threadIdx.x == 0) { prefix_s = 0ull; kk_s = NN; ss[256] = 0u; }
  __syncthreads();
  for (int round = 0; round < 8; round++) {
    int shift = 56 - 8*round;
    if (threadIdx.x < 256) hist[threadIdx.x] = 0u;
    __syncthreads();
    unsigned long long prefix = prefix_s;
    int kk = kk_s;
    unsigned long long himask = (round == 0) ? 0ull : (~0ull << (shift + 8));
    #pragma unroll
    for (int q = 0; q < 8; q++) {
      if ((kreg[q] & himask) == prefix) {
        unsigned int d = (unsigned int)((kreg[q] >> shift) & 255ull);
        atomicAdd(&hist[d], 1u);
      }
    }
    __syncthreads();
    // parallel suffix-sum of hist -> ss
    if (threadIdx.x < 256) ss[threadIdx.x] = hist[threadIdx.x];
    __syncthreads();
    for (int off = 1; off < 256; off <<= 1) {
      unsigned int nv = 0u;
      if (threadIdx.x < 256)
        nv = ss[threadIdx.x] + ((threadIdx.x + off < 256) ? ss[threadIdx.x + off] : 0u);
      __syncthreads();
      if (threadIdx.x < 256) ss[threadIdx.x] = nv;
      __syncthreads();
    }
    if (threadIdx.x < 256) {
      int S = (int)ss[threadIdx.x];
      int Sn = (int)ss[threadIdx.x + 1];   // ss[256]=0
      if (S >= kk && Sn < kk) {            // exactly one thread: largest digit with S>=kk
        prefix_s = prefix | ((unsigned long long)threadIdx.x << shift);
        kk_s = kk - Sn;
      }
    }
    __syncthreads();
  }
  unsigned long long T = prefix_s;
  int kk = kk_s;
  if (threadIdx.x == 0) { cgt_s = 0; ceq_s = 0; }
  __syncthreads();
  #pragma unroll
  for (int q = 0; q < 8; q++) {
    unsigned long long key = kreg[q];
    int slot = -1;
    if (key > T) slot = atomicAdd(&cgt_s, 1);
    else if (key == T) {
      int p = atomicAdd(&ceq_s, 1);
      if (p < kk) slot = (NN-1) - p;
    }
    if (slot >= 0) {
      topv[b*NN+slot] = __uint_as_float((unsigned int)(key >> 32));
      topi[b*NN+slot] = (int)(0xFFFFFFFFu - (unsigned int)(key & 0xFFFFFFFFull));
    }
  }
}

// fused source-point compute + 8-way projection scatter
__global__ void k_scatfuse(const float* __restrict__ topv, const int* __restrict__ topi,
                           const float* __restrict__ depths, const float* __restrict__ poses,
                           const float* __restrict__ Km, unsigned int* __restrict__ target) {
  int t = blockIdx.x*256 + threadIdx.x;
  if (t >= BB*NN) return;
  int i = t / NN;
  float val = topv[t];
  if (val <= 0.f) return;
  int idx = topi[t];
  float xs = (float)(idx % WW), ys = (float)(idx / WW);
  float cx = 2.0f*xs/639.0f - 1.0f;
  float cy = 2.0f*ys/479.0f - 1.0f;
  float px = (cx + 1.0f)*0.5f*639.0f;
  float py = (cy + 1.0f)*0.5f*479.0f;
  float Xw[3], d;
  src_compute(px, py, depths + (size_t)i*HWSZ, poses, Km, i, Xw, &d);
  for (int j = 0; j < BB; j++) {
    float nx, ny; bool inv;
    project_to(poses, Km, j, Xw, d, &nx, &ny, &inv);
    if (inv) { nx = -2.0f; ny = -2.0f; }
    float fx = rintf((nx + 1.0f)*0.5f*639.0f);
    float fy = rintf((ny + 1.0f)*0.5f*479.0f);
    int wq = (int)fx, hq = (int)fy;
    if (wq < 0) continue;
    int hc = min(max(hq, 0), HH-1), wc = min(max(wq, 0), WW-1);
    atomicMax(&target[(size_t)j*HWSZ + hc*WW + wc], __float_as_uint(val));
  }
}

// LDS-tiled 5x5 maxpool + BCE
__global__ void k_bce(const float* __restrict__ target, const float* __restrict__ pnness,
                      double* __restrict__ acc) {
  __shared__ float s[12][36];
  int bx = blockIdx.x*32, by = blockIdx.y*8, b = blockIdx.z;
  const float* tb = target + (size_t)b*HWSZ;
  for (int e = threadIdx.x; e < 36*12; e += 256) {
    int lx = e % 36, ly = e / 36;
    int gxi = bx - 2 + lx, gyi = by - 2 + ly;
    s[ly][lx] = (gxi>=0 && gxi<WW && gyi>=0 && gyi<HH) ? tb[gyi*WW+gxi] : -INFINITY;
  }
  __syncthreads();
  int tx = threadIdx.x & 31, ty = threadIdx.x >> 5;
  float v = s[ty+2][tx+2];
  float mp = -INFINITY;
  #pragma unroll
  for (int dy = 0; dy < 5; dy++)
    #pragma unroll
    for (int dx = 0; dx < 5; dx++)
      mp = fmaxf(mp, s[ty+dy][tx+dx]);
  bool t = (v > 0.f) && (v == mp);
  float pv = pnness[(size_t)b*HWSZ + (by+ty)*WW + (bx+tx)];
  float term = t ? (-fmaxf(logf(pv), -100.0f)) : (-fmaxf(logf(1.0f - pv), -100.0f));
  double sum = blockRedSum256((double)term);
  if (threadIdx.x == 0) atomicAdd(&acc[1], sum);
}

__global__ void k_dn(const float* __restrict__ desc, float* __restrict__ dn) {
  int row = blockIdx.x;
  int d = threadIdx.x;
  float v = desc[(size_t)row*DDIM + d];
  __shared__ float sp[4];
  __shared__ float den_s;
  float s = v*v;
  #pragma unroll
  for (int o = 32; o > 0; o >>= 1) s += __shfl_down(s, o, 64);
  int lane = threadIdx.x & 63, wid = threadIdx.x >> 6;
  if (lane == 0) sp[wid] = s;
  __syncthreads();
  if (threadIdx.x == 0) den_s = fmaxf(sqrtf(sp[0]+sp[1]+sp[2]+sp[3]), 1e-8f);
  __syncthreads();
  dn[(size_t)row*DDIM + d] = v / den_s;
}

// fused match source compute + 8-way projection
__global__ void k_msrcdst(const float* __restrict__ points, const float* __restrict__ depths,
                          const float* __restrict__ poses, const float* __restrict__ Km,
                          float* __restrict__ psrc, float* __restrict__ pdst, int* __restrict__ minv) {
  int t = blockIdx.x*256 + threadIdx.x;
  if (t >= BB*NN) return;
  int a = t / NN, m = t % NN;
  float p0 = points[t*2], p1 = points[t*2+1];
  float px = (p0 + 1.0f)*0.5f*639.0f;
  float py = (p1 + 1.0f)*0.5f*479.0f;
  float Xw[3], d;
  src_compute(px, py, depths + (size_t)a*HWSZ, poses, Km, a, Xw, &d);
  psrc[t*2] = px; psrc[t*2+1] = py;
  for (int b = 0; b < BB; b++) {
    float nx, ny; bool inv;
    project_to(poses, Km, b, Xw, d, &nx, &ny, &inv);
    int o = (a*BB + b)*NN + m;
    pdst[o*2]   = (nx + 1.0f)*0.5f*639.0f;
    pdst[o*2+1] = (ny + 1.0f)*0.5f*479.0f;
    minv[o] = inv ? 1 : 0;
  }
}

// match: grid (BB*BB, MSPLIT); each block scans a 63-row slice of the 500x500 pair space
__global__ void k_match(const float* __restrict__ psrc, const float* __restrict__ pdst,
                        const int* __restrict__ minv, const float* __restrict__ dn,
                        double* __restrict__ acc) {
  __shared__ float spd[2*NN], ssrc[2*NN];
  __shared__ int sinv[NN];
  int ab = blockIdx.x; int b = ab % BB; int a = ab / BB;
  int mm0 = blockIdx.y * MCH;
  int mmN = min(NN, mm0 + MCH);
  for (int e = threadIdx.x; e < NN; e += 256) {
    spd[e*2]   = pdst[(ab*NN+e)*2];
    spd[e*2+1] = pdst[(ab*NN+e)*2+1];
    sinv[e]    = minv[ab*NN+e];
    ssrc[e*2]   = psrc[(b*NN+e)*2];
    ssrc[e*2+1] = psrc[(b*NN+e)*2+1];
  }
  __syncthreads();
  double lsum = 0.0, lcnt = 0.0;
  int npairs = (mmN - mm0) * NN;
  for (int idx = threadIdx.x; idx < npairs; idx += 256) {
    int mm = mm0 + idx / NN;
    int nn = idx % NN;
    if (nn >= mm) continue;          // n < m
    if (sinv[nn]) continue;          // reference quirk: invis indexed by n
    float dx = ssrc[nn*2]   - spd[mm*2];
    float dy = ssrc[nn*2+1] - spd[mm*2+1];
    if (dx*dx + dy*dy <= 1.0f) {
      const float* da = dn + ((size_t)a*NN + mm)*DDIM;
      const float* db = dn + ((size_t)b*NN + nn)*DDIM;
      float dot = 0.f;
      for (int q = 0; q < DDIM; q++) dot += db[q]*da[q];
      lsum += (double)(1.0f - dot);
      lcnt += 1.0;
    }
  }
  double s = blockRedSum256(lsum);
  if (threadIdx.x == 0 && s != 0.0) atomicAdd(&acc[2], s);
  double c2 = blockRedSum256(lcnt);
  if (threadIdx.x == 0 && c2 != 0.0) atomicAdd(&acc[3], c2);
}

// distinction: register-tiled 64x64 f32 GEMM tiles on dn * dn^T (symmetric:
// lower-triangle tiles weighted x2). Output never materialized -> relu-sum only.
__global__ __launch_bounds__(256) void k_dist(const float* __restrict__ dn, double* __restrict__ acc) {
  if (blockIdx.x > blockIdx.y) return;
  __shared__ float As[64][36];
  __shared__ float Bs[64][36];
  int b = blockIdx.z;
  int r0 = blockIdx.y*64, c0 = blockIdx.x*64;
  const float* base = dn + (size_t)b*NN*DDIM;
  float accf[4][4];
  #pragma unroll
  for (int i = 0; i < 4; i++)
    #pragma unroll
    for (int j = 0; j < 4; j++) accf[i][j] = 0.f;
  int tx = threadIdx.x & 15, ty = threadIdx.x >> 4;
  for (int kc = 0; kc < DDIM; kc += 32) {
    __syncthreads();
    #pragma unroll
    for (int l = 0; l < 2; l++) {
      int q = threadIdx.x + l*256;        // 512 float4 slots per matrix
      int row = q >> 3, kq = q & 7;
      int gr = r0 + row;
      float4 va = make_float4(0.f,0.f,0.f,0.f);
      if (gr < NN) va = *(const float4*)&base[(size_t)gr*DDIM + kc + kq*4];
      *(float4*)&As[row][kq*4] = va;
      int gc = c0 + row;
      float4 vb = make_float4(0.f,0.f,0.f,0.f);
      if (gc < NN) vb = *(const float4*)&base[(size_t)gc*DDIM + kc + kq*4];
      *(float4*)&Bs[row][kq*4] = vb;
    }
    __syncthreads();
    #pragma unroll
    for (int kk = 0; kk < 32; kk += 4) {
      float4 a4[4], b4[4];
      #pragma unroll
      for (int i = 0; i < 4; i++) a4[i] = *(const float4*)&As[ty*4+i][kk];
      #pragma unroll
      for (int j = 0; j < 4; j++) b4[j] = *(const float4*)&Bs[tx*4+j][kk];
      #pragma unroll
      for (int i = 0; i < 4; i++)
        #pragma unroll
        for (int j = 0; j < 4; j++)
          accf[i][j] += a4[i].x*b4[j].x + a4[i].y*b4[j].y + a4[i].z*b4[j].z + a4[i].w*b4[j].w;
    }
  }
  double wgt = (blockIdx.x == blockIdx.y) ? 1.0 : 2.0;
  double lsum = 0.0;
  #pragma unroll
  for (int i = 0; i < 4; i++)
    #pragma unroll
    for (int j = 0; j < 4; j++)
      lsum += (double)fmaxf(accf[i][j], 0.f);
  lsum *= wgt;
  double s = blockRedSum256(lsum);
  if (threadIdx.x == 0) atomicAdd(&acc[0], s);
}

__global__ void k_final(const double* __restrict__ acc, float* __restrict__ out) {
  float dist  = (float)(acc[0] / (double)(BB*NN*NN));
  float corn  = (float)(acc[1] / (double)BHW);
  float cnt   = fmaxf((float)acc[3], 1.0f);
  float match = (float)acc[2] / cnt;
  out[0] = 1.0f*dist + 1.0f*corn + 1.0f*match;
}

// ---------------- host ----------------

extern "C" void kernel_launch(void* const* d_in, const int* in_sizes, int n_in,
                              void* d_out, int out_size, void* d_ws, size_t ws_size,
                              hipStream_t stream) {
  (void)in_sizes; (void)n_in; (void)out_size; (void)ws_size;
  const float* desc      = (const float*)d_in[0];
  const float* points    = (const float*)d_in[1];
  const float* pointness = (const float*)d_in[2];
  const float* depths    = (const float*)d_in[3];
  const float* poses     = (const float*)d_in[4];
  const float* Kmat      = (const float*)d_in[5];
  const float* imgs      = (const float*)d_in[6];
  float* out = (float*)d_out;
  float* ws = (float*)d_ws;

  float* bufA = ws;                          // resp
  float* bufC = ws + (size_t)BHW;            // scatter target
  float* cv_main = ws + 2*(size_t)BHW;       // 8 x 4800
  int*   ci_main = (int*)(cv_main + BB*NBLK);
  // --- contiguous zeroed region start ---
  float* cv_ovf  = (float*)(ci_main + BB*NBLK);   // 8 x 3392
  int*   ci_ovf  = (int*)(cv_ovf + BB*NOVF);
  int*   ovf     = (int*)(ci_ovf + BB*NOVF);      // 8 x stride-64 counters
  double* acc    = (double*)(ovf + BB*64);        // [0]=dist [1]=bce [2]=match_sum [3]=match_cnt
  // --- contiguous zeroed region end ---
  float* topv = (float*)(acc + 4);
  int*   topi = (int*)(topv + BB*NN);
  float* psrc = (float*)(topi + BB*NN);
  float* pdst = psrc + BB*NN*2;
  int*   minv = (int*)(pdst + BB*BB*NN*2);
  float* dn   = (float*)(minv + BB*BB*NN);        // 8*500*256 floats

  size_t zbytes = (size_t)BB*NOVF*8 + (size_t)BB*64*4 + 4*sizeof(double);
  hipMemsetAsync(cv_ovf, 0, zbytes, stream);

  dim3 tgrid(WW/32, HH/8, BB);

  k_gfused <<<tgrid, 256, 0, stream>>>(imgs, bufA);
  k_nmscand<<<tgrid, 256, 0, stream>>>(bufA, cv_main, ci_main, cv_ovf, ci_ovf, ovf, bufC);
  k_topsel <<<BB, 1024, 0, stream>>>(cv_main, ci_main, cv_ovf, ci_ovf, topv, topi);
  k_scatfuse<<<(BB*NN + 255)/256, 256, 0, stream>>>(topv, topi, depths, poses, Kmat, (unsigned int*)bufC);
  k_bce   <<<tgrid, 256, 0, stream>>>(bufC, pointness, acc);
  k_dn    <<<BB*NN, DDIM, 0, stream>>>(desc, dn);
  k_msrcdst<<<(BB*NN + 255)/256, 256, 0, stream>>>(points, depths, poses, Kmat, psrc, pdst, minv);
  k_match <<<dim3(BB*BB, MSPLIT), 256, 0, stream>>>(psrc, pdst, minv, dn, acc);
  k_dist  <<<dim3(8, 8, BB), 256, 0, stream>>>(dn, acc);
  k_final <<<1, 1, 0, stream>>>(acc, out);
}

// Round 5
// 175.985 us; speedup vs baseline: 5.7852x; 1.5564x over previous
//
#include <hip/hip_runtime.h>
#include <math.h>

#define BB 8
#define NN 500
#define DDIM 256
#define HH 480
#define WW 640
#define HWSZ (HH*WW)        // 307200
#define BHW (BB*HWSZ)       // 2457600
#define NBLK 4800           // 8x8 blocks per image
#define NOVF 3392           // overflow candidate slots per image
#define MSPLIT 8
#define MCH 63              // ceil(500/8)
#define NLIST (BB*NN*BB)    // 32000 deterministic list slots
#define NBCE 1024           // bce streaming blocks
#define NCORR 125           // ceil(32000/256)

// partial-sum slot map (doubles at ws start)
#define PD_DIST  0          // 512
#define PD_MS    512        // 512
#define PD_MC    1024       // 512
#define PD_BCE   1536       // 1024
#define PD_CORR  2560       // 125
#define PD_TOTAL 2688

// ---------------- helpers ----------------

static __device__ __forceinline__ float wredmaxf(float v) {
  #pragma unroll
  for (int o = 1; o < 64; o <<= 1) v = fmaxf(v, __shfl_xor(v, o, 64));
  return v;
}

static __device__ __forceinline__ double blockRedSum256(double v) {
  __shared__ double sp[4];
  __syncthreads();
  #pragma unroll
  for (int o = 32; o > 0; o >>= 1) v += __shfl_down(v, o, 64);
  int lane = threadIdx.x & 63, wid = threadIdx.x >> 6;
  if (lane == 0) sp[wid] = v;
  __syncthreads();
  double r = 0.0;
  if (threadIdx.x == 0) r = sp[0] + sp[1] + sp[2] + sp[3];
  return r;
}

static __device__ __forceinline__ float bilin(const float* __restrict__ img, float px, float py) {
  float x = fminf(fmaxf(px, 0.0f), 639.0f);
  float y = fminf(fmaxf(py, 0.0f), 479.0f);
  float x0 = floorf(x), y0 = floorf(y);
  float x1 = fminf(x0 + 1.0f, 639.0f);
  float y1 = fminf(y0 + 1.0f, 479.0f);
  float wx = x - x0, wy = y - y0;
  int x0i = (int)x0, x1i = (int)x1, y0i = (int)y0, y1i = (int)y1;
  float v00 = img[y0i*WW + x0i], v01 = img[y0i*WW + x1i];
  float v10 = img[y1i*WW + x0i], v11 = img[y1i*WW + x1i];
  return v00*(1.0f-wx)*(1.0f-wy) + v01*wx*(1.0f-wy) + v10*(1.0f-wx)*wy + v11*wx*wy;
}

// world point from pixel (px,py) in image bimg; replicates reference op order
static __device__ void src_compute(float px, float py, const float* __restrict__ dep,
                                   const float* __restrict__ poses, const float* __restrict__ Km,
                                   int bimg, float* Xw, float* dout) {
  float d = bilin(dep, px, py);
  const float* Kb = Km + bimg*9;
  double a00=Kb[0],a01=Kb[1],a02=Kb[2],a10=Kb[3],a11=Kb[4],a12=Kb[5],a20=Kb[6],a21=Kb[7],a22=Kb[8];
  double det = a00*(a11*a22-a12*a21) - a01*(a10*a22-a12*a20) + a02*(a10*a21-a11*a20);
  double id = 1.0/det;
  float i00=(float)((a11*a22-a12*a21)*id), i01=(float)((a02*a21-a01*a22)*id), i02=(float)((a01*a12-a02*a11)*id);
  float i10=(float)((a12*a20-a10*a22)*id), i11=(float)((a00*a22-a02*a20)*id), i12=(float)((a02*a10-a00*a12)*id);
  float i20=(float)((a10*a21-a11*a20)*id), i21=(float)((a01*a20-a00*a21)*id), i22=(float)((a00*a11-a01*a10)*id);
  float c0 = i00*px + i01*py + i02;
  float c1 = i10*px + i11*py + i12;
  float c2 = i20*px + i21*py + i22;
  float X0 = d*c0, X1 = d*c1, X2 = d*c2;
  const float* P = poses + bimg*16;
  Xw[0] = (P[0]*X0 + P[1]*X1 + P[2]*X2)  + P[3];
  Xw[1] = (P[4]*X0 + P[5]*X1 + P[6]*X2)  + P[7];
  Xw[2] = (P[8]*X0 + P[9]*X1 + P[10]*X2) + P[11];
  *dout = d;
}

static __device__ void project_to(const float* __restrict__ poses, const float* __restrict__ Km,
                                  int j, const float* Xw, float dsrc,
                                  float* pnx, float* pny, bool* invis) {
  const float* P = poses + j*16;
  float d0 = Xw[0]-P[3], d1 = Xw[1]-P[7], d2 = Xw[2]-P[11];
  float Xj0 = P[0]*d0 + P[4]*d1 + P[8]*d2;
  float Xj1 = P[1]*d0 + P[5]*d1 + P[9]*d2;
  float Xj2 = P[2]*d0 + P[6]*d1 + P[10]*d2;
  const float* Kb = Km + j*9;
  float u = Kb[0]*Xj0 + Kb[1]*Xj1 + Kb[2]*Xj2;
  float v = Kb[3]*Xj0 + Kb[4]*Xj1 + Kb[5]*Xj2;
  float z = Kb[6]*Xj0 + Kb[7]*Xj1 + Kb[8]*Xj2;
  float zs = (fabsf(z) < 1e-6f) ? 1e-6f : z;
  float pu = u/zs, pv = v/zs;
  float nx = 2.0f*pu/639.0f - 1.0f;
  float ny = 2.0f*pv/479.0f - 1.0f;
  *pnx = nx; *pny = ny;
  *invis = (z <= 1e-6f) || (fabsf(nx) > 1.0f) || (fabsf(ny) > 1.0f) || (dsrc <= 0.0f);
}

// ---------------- kernels ----------------

// fused gray -> sobel -> 7x7 GFTT. 32x8 out tile, gray halo 4 (40x16),
// sobel halo 3 (38x14). Sobel outputs at out-of-image positions forced to 0.
__global__ void k_gfused(const float* __restrict__ imgs, float* __restrict__ resp) {
  __shared__ float sgray[16][40];
  __shared__ float sgx[14][38];
  __shared__ float sgy[14][38];
  __shared__ float w[49];
  int bx = blockIdx.x*32, by = blockIdx.y*8, b = blockIdx.z;
  if (threadIdx.x < 49) {
    double g[7];
    for (int q = 0; q < 7; q++) { double r = (double)(q-3); g[q] = exp(-(r*r)/2.0); }
    double s = 0.0;
    for (int q = 0; q < 7; q++) s += g[q];
    int i = threadIdx.x/7, j = threadIdx.x%7;
    w[threadIdx.x] = (float)((g[i]/s)*(g[j]/s));
  }
  const float* ib = imgs + (size_t)b*3*HWSZ;
  for (int e = threadIdx.x; e < 40*16; e += 256) {
    int lx = e % 40, ly = e / 40;
    int gxi = bx - 4 + lx, gyi = by - 4 + ly;
    float v = 0.f;
    if (gxi>=0 && gxi<WW && gyi>=0 && gyi<HH) {
      int p = gyi*WW + gxi;
      v = 0.299f*ib[p] + 0.587f*ib[HWSZ+p] + 0.114f*ib[2*HWSZ+p];
    }
    sgray[ly][lx] = v;
  }
  __syncthreads();
  const float kx[3][3] = {{-0.125f,0.f,0.125f},{-0.25f,0.f,0.25f},{-0.125f,0.f,0.125f}};
  for (int e = threadIdx.x; e < 38*14; e += 256) {
    int lx = e % 38, ly = e / 38;
    int X = bx - 3 + lx, Y = by - 3 + ly;
    float sx = 0.f, sy = 0.f;
    #pragma unroll
    for (int i = 0; i < 3; i++)
      #pragma unroll
      for (int j = 0; j < 3; j++) {
        float v = sgray[ly+i][lx+j];
        sx += kx[i][j]*v;
        sy += kx[j][i]*v;
      }
    bool in = (X>=0 && X<WW && Y>=0 && Y<HH);
    sgx[ly][lx] = in ? sx : 0.f;
    sgy[ly][lx] = in ? sy : 0.f;
  }
  __syncthreads();
  int tx = threadIdx.x & 31, ty = threadIdx.x >> 5;
  float sxx = 0.f, syy = 0.f, sxy = 0.f;
  #pragma unroll
  for (int i = 0; i < 7; i++) {
    #pragma unroll
    for (int j = 0; j < 7; j++) {
      float a = sgx[ty+i][tx+j], c = sgy[ty+i][tx+j];
      float ww = w[i*7+j];
      sxx += ww*(a*a); syy += ww*(c*c); sxy += ww*(a*c);
    }
  }
  float tr = sxx + syy;
  float det = sxx*syy - sxy*sxy;
  float disc = fmaxf(tr*tr - 4.0f*det, 0.f);
  resp[(size_t)b*HWSZ + (by+ty)*WW + (bx+tx)] = 0.5f*(tr - sqrtf(disc));
}

// fused 5x5 NMS + per-8x8-block candidate extraction (+ zero the scatter target)
__global__ void k_nmscand(const float* __restrict__ resp, float* __restrict__ cv,
                          int* __restrict__ ci, float* __restrict__ cvo,
                          int* __restrict__ cio, int* __restrict__ ovf,
                          float* __restrict__ target) {
  __shared__ float s[12][36];
  __shared__ float c32[8][32];
  int bx = blockIdx.x*32, by = blockIdx.y*8, b = blockIdx.z;
  const float* r = resp + (size_t)b*HWSZ;
  for (int e = threadIdx.x; e < 36*12; e += 256) {
    int lx = e % 36, ly = e / 36;
    int gxi = bx - 2 + lx, gyi = by - 2 + ly;
    s[ly][lx] = (gxi>=0 && gxi<WW && gyi>=0 && gyi<HH) ? r[gyi*WW+gxi] : -INFINITY;
  }
  __syncthreads();
  int tx = threadIdx.x & 31, ty = threadIdx.x >> 5;
  float v = s[ty+2][tx+2];
  float mp = -INFINITY;
  #pragma unroll
  for (int dy = 0; dy < 5; dy++)
    #pragma unroll
    for (int dx = 0; dx < 5; dx++)
      mp = fmaxf(mp, s[ty+dy][tx+dx]);
  c32[ty][tx] = (v == mp) ? v : 0.f;
  target[(size_t)b*HWSZ + (by+ty)*WW + (bx+tx)] = 0.f;   // zero scatter target
  __syncthreads();
  int wv = threadIdx.x >> 6, lane = threadIdx.x & 63;
  int ltx = wv*8 + (lane & 7), lty = lane >> 3;
  float cval = c32[lty][ltx];
  float bm = wredmaxf(cval);
  bool win = (cval > 0.f) && (cval == bm);
  unsigned long long mask = __ballot(win);
  int rblk = blockIdx.y*80 + blockIdx.x*4 + wv;          // global 8x8-block index
  int gidx = (by + lty)*WW + (bx + ltx);
  if (mask == 0ull) {
    if (lane == 0) { cv[b*NBLK+rblk] = 0.f; ci[b*NBLK+rblk] = 0; }
  } else if (win) {
    int rank = __popcll(mask & ((1ull << lane) - 1ull));
    if (rank == 0) { cv[b*NBLK+rblk] = cval; ci[b*NBLK+rblk] = gidx; }
    else {
      int pos = atomicAdd(&ovf[b*64], 1);
      if (pos < NOVF) { cvo[b*NOVF+pos] = cval; cio[b*NOVF+pos] = gidx; }
    }
  }
}

// top-500 selection via MSB-first radix select on 64-bit keys
// key = (float_bits << 32) | ~idx  -> top-k order == (value desc, idx asc).
__global__ __launch_bounds__(1024) void k_topsel(const float* __restrict__ cv, const int* __restrict__ ci,
                                                 const float* __restrict__ cvo, const int* __restrict__ cio,
                                                 float* __restrict__ topv, int* __restrict__ topi) {
  __shared__ unsigned int hist[256];
  __shared__ unsigned int ss[257];
  __shared__ unsigned long long prefix_s;
  __shared__ int kk_s, cgt_s, ceq_s;
  int b = blockIdx.x;
  unsigned long long kreg[8];
  #pragma unroll
  for (int q = 0; q < 8; q++) {
    int e = threadIdx.x + q*1024;
    float v; unsigned int idx;
    if (e < NBLK) { v = cv[b*NBLK+e];       idx = (unsigned int)ci[b*NBLK+e]; }
    else          { v = cvo[b*NOVF+e-NBLK]; idx = (unsigned int)cio[b*NOVF+e-NBLK]; }
    kreg[q] = ((unsigned long long)__float_as_uint(v) << 32) | (0xFFFFFFFFu - idx);
  }
  if (threadIdx.x == 0) { prefix_s = 0ull; kk_s = NN; ss[256] = 0u; }
  __syncthreads();
  for (int round = 0; round < 8; round++) {
    int shift = 56 - 8*round;
    if (threadIdx.x < 256) hist[threadIdx.x] = 0u;
    __syncthreads();
    unsigned long long prefix = prefix_s;
    int kk = kk_s;
    unsigned long long himask = (round == 0) ? 0ull : (~0ull << (shift + 8));
    #pragma unroll
    for (int q = 0; q < 8; q++) {
      if ((kreg[q] & himask) == prefix) {
        unsigned int d = (unsigned int)((kreg[q] >> shift) & 255ull);
        atomicAdd(&hist[d], 1u);
      }
    }
    __syncthreads();
    if (threadIdx.x < 256) ss[threadIdx.x] = hist[threadIdx.x];
    __syncthreads();
    for (int off = 1; off < 256; off <<= 1) {
      unsigned int nv = 0u;
      if (threadIdx.x < 256)
        nv = ss[threadIdx.x] + ((threadIdx.x + off < 256) ? ss[threadIdx.x + off] : 0u);
      __syncthreads();
      if (threadIdx.x < 256) ss[threadIdx.x] = nv;
      __syncthreads();
    }
    if (threadIdx.x < 256) {
      int S = (int)ss[threadIdx.x];
      int Sn = (int)ss[threadIdx.x + 1];
      if (S >= kk && Sn < kk) {
        prefix_s = prefix | ((unsigned long long)threadIdx.x << shift);
        kk_s = kk - Sn;
      }
    }
    __syncthreads();
  }
  unsigned long long T = prefix_s;
  int kk = kk_s;
  if (threadIdx.x == 0) { cgt_s = 0; ceq_s = 0; }
  __syncthreads();
  #pragma unroll
  for (int q = 0; q < 8; q++) {
    unsigned long long key = kreg[q];
    int slot = -1;
    if (key > T) slot = atomicAdd(&cgt_s, 1);
    else if (key == T) {
      int p = atomicAdd(&ceq_s, 1);
      if (p < kk) slot = (NN-1) - p;
    }
    if (slot >= 0) {
      topv[b*NN+slot] = __uint_as_float((unsigned int)(key >> 32));
      topi[b*NN+slot] = (int)(0xFFFFFFFFu - (unsigned int)(key & 0xFFFFFFFFull));
    }
  }
}

// fused source-point compute + 8-way projection scatter.
// First writer of each target pixel (atomicMax old==0) records the pixel at a
// DETERMINISTIC slot t*BB+j in the -1-initialized list (exactly once per pixel).
__global__ void k_scatfuse(const float* __restrict__ topv, const int* __restrict__ topi,
                           const float* __restrict__ depths, const float* __restrict__ poses,
                           const float* __restrict__ Km, unsigned int* __restrict__ target,
                           int* __restrict__ list) {
  int t = blockIdx.x*256 + threadIdx.x;
  if (t >= BB*NN) return;
  int i = t / NN;
  float val = topv[t];
  if (val <= 0.f) return;
  int idx = topi[t];
  float xs = (float)(idx % WW), ys = (float)(idx / WW);
  float cx = 2.0f*xs/639.0f - 1.0f;
  float cy = 2.0f*ys/479.0f - 1.0f;
  float px = (cx + 1.0f)*0.5f*639.0f;
  float py = (cy + 1.0f)*0.5f*479.0f;
  float Xw[3], d;
  src_compute(px, py, depths + (size_t)i*HWSZ, poses, Km, i, Xw, &d);
  for (int j = 0; j < BB; j++) {
    float nx, ny; bool inv;
    project_to(poses, Km, j, Xw, d, &nx, &ny, &inv);
    if (inv) { nx = -2.0f; ny = -2.0f; }
    float fx = rintf((nx + 1.0f)*0.5f*639.0f);
    float fy = rintf((ny + 1.0f)*0.5f*479.0f);
    int wq = (int)fx, hq = (int)fy;
    if (wq < 0) continue;
    int hc = min(max(hq, 0), HH-1), wc = min(max(wq, 0), WW-1);
    int p = j*HWSZ + hc*WW + wc;
    unsigned int old = atomicMax(&target[p], __float_as_uint(val));
    if (old == 0u) list[t*BB + j] = p;   // first writer -> exactly once per pixel
  }
}

// streaming BCE over all pixels assuming t=false: sum of -max(log(1-p),-100)
__global__ void k_bce_stream(const float* __restrict__ pn, double* __restrict__ pd) {
  int idx = blockIdx.x*256 + threadIdx.x;
  double l = 0.0;
  for (int q = idx; q < BHW/4; q += NBCE*256) {
    float4 v = ((const float4*)pn)[q];
    l -= (double)fmaxf(logf(1.f - v.x), -100.f);
    l -= (double)fmaxf(logf(1.f - v.y), -100.f);
    l -= (double)fmaxf(logf(1.f - v.z), -100.f);
    l -= (double)fmaxf(logf(1.f - v.w), -100.f);
  }
  double s = blockRedSum256(l);
  if (threadIdx.x == 0) pd[PD_BCE + blockIdx.x] = s;
}

// correction at scattered pixels: t can only be true where target>0 (v>0 required),
// i.e. exactly the listed pixels. Evaluate 5x5 max there; if t, swap the BCE term.
__global__ void k_bcecorr(const int* __restrict__ list, const float* __restrict__ target,
                          const float* __restrict__ pn, double* __restrict__ pd) {
  int idx = blockIdx.x*256 + threadIdx.x;
  double l = 0.0;
  if (idx < NLIST) {
    int p = list[idx];
    if (p >= 0) {
      int j = p / HWSZ, pix = p % HWSZ;
      int y = pix / WW, x = pix % WW;
      const float* tb = target + (size_t)j*HWSZ;
      float v = tb[pix];
      float mp = -INFINITY;
      for (int dy = -2; dy <= 2; dy++) {
        int yy = y + dy; if (yy < 0 || yy >= HH) continue;
        for (int dx = -2; dx <= 2; dx++) {
          int xx = x + dx; if (xx < 0 || xx >= WW) continue;
          mp = fmaxf(mp, tb[yy*WW+xx]);
        }
      }
      if (v > 0.f && v == mp) {
        float pv = pn[p];
        l = (double)(-fmaxf(logf(pv), -100.f)) + (double)fmaxf(logf(1.f - pv), -100.f);
      }
    }
  }
  double s = blockRedSum256(l);
  if (threadIdx.x == 0) pd[PD_CORR + blockIdx.x] = s;
}

__global__ void k_dn(const float* __restrict__ desc, float* __restrict__ dn) {
  int row = blockIdx.x;
  int d = threadIdx.x;
  float v = desc[(size_t)row*DDIM + d];
  __shared__ float sp[4];
  __shared__ float den_s;
  float s = v*v;
  #pragma unroll
  for (int o = 32; o > 0; o >>= 1) s += __shfl_down(s, o, 64);
  int lane = threadIdx.x & 63, wid = threadIdx.x >> 6;
  if (lane == 0) sp[wid] = s;
  __syncthreads();
  if (threadIdx.x == 0) den_s = fmaxf(sqrtf(sp[0]+sp[1]+sp[2]+sp[3]), 1e-8f);
  __syncthreads();
  dn[(size_t)row*DDIM + d] = v / den_s;
}

// fused match source compute + 8-way projection
__global__ void k_msrcdst(const float* __restrict__ points, const float* __restrict__ depths,
                          const float* __restrict__ poses, const float* __restrict__ Km,
                          float* __restrict__ psrc, float* __restrict__ pdst, int* __restrict__ minv) {
  int t = blockIdx.x*256 + threadIdx.x;
  if (t >= BB*NN) return;
  int a = t / NN, m = t % NN;
  float p0 = points[t*2], p1 = points[t*2+1];
  float px = (p0 + 1.0f)*0.5f*639.0f;
  float py = (p1 + 1.0f)*0.5f*479.0f;
  float Xw[3], d;
  src_compute(px, py, depths + (size_t)a*HWSZ, poses, Km, a, Xw, &d);
  psrc[t*2] = px; psrc[t*2+1] = py;
  for (int b = 0; b < BB; b++) {
    float nx, ny; bool inv;
    project_to(poses, Km, b, Xw, d, &nx, &ny, &inv);
    int o = (a*BB + b)*NN + m;
    pdst[o*2]   = (nx + 1.0f)*0.5f*639.0f;
    pdst[o*2+1] = (ny + 1.0f)*0.5f*479.0f;
    minv[o] = inv ? 1 : 0;
  }
}

// match: grid (BB*BB, MSPLIT); partial sums, no global atomics
__global__ void k_match(const float* __restrict__ psrc, const float* __restrict__ pdst,
                        const int* __restrict__ minv, const float* __restrict__ dn,
                        double* __restrict__ pd) {
  __shared__ float spd[2*NN], ssrc[2*NN];
  __shared__ int sinv[NN];
  int ab = blockIdx.x; int b = ab % BB; int a = ab / BB;
  int mm0 = blockIdx.y * MCH;
  int mmN = min(NN, mm0 + MCH);
  for (int e = threadIdx.x; e < NN; e += 256) {
    spd[e*2]   = pdst[(ab*NN+e)*2];
    spd[e*2+1] = pdst[(ab*NN+e)*2+1];
    sinv[e]    = minv[ab*NN+e];
    ssrc[e*2]   = psrc[(b*NN+e)*2];
    ssrc[e*2+1] = psrc[(b*NN+e)*2+1];
  }
  __syncthreads();
  double lsum = 0.0, lcnt = 0.0;
  int npairs = (mmN - mm0) * NN;
  for (int idx = threadIdx.x; idx < npairs; idx += 256) {
    int mm = mm0 + idx / NN;
    int nn = idx % NN;
    if (nn >= mm) continue;          // n < m
    if (sinv[nn]) continue;          // reference quirk: invis indexed by n
    float dx = ssrc[nn*2]   - spd[mm*2];
    float dy = ssrc[nn*2+1] - spd[mm*2+1];
    if (dx*dx + dy*dy <= 1.0f) {
      const float* da = dn + ((size_t)a*NN + mm)*DDIM;
      const float* db = dn + ((size_t)b*NN + nn)*DDIM;
      float dot = 0.f;
      for (int q = 0; q < DDIM; q++) dot += db[q]*da[q];
      lsum += (double)(1.0f - dot);
      lcnt += 1.0;
    }
  }
  int slot = blockIdx.y*64 + blockIdx.x;
  double s = blockRedSum256(lsum);
  if (threadIdx.x == 0) pd[PD_MS + slot] = s;
  double c2 = blockRedSum256(lcnt);
  if (threadIdx.x == 0) pd[PD_MC + slot] = c2;
}

// distinction: register-tiled 64x64 f32 GEMM tiles on dn * dn^T (symmetric:
// lower-triangle tiles x2). Partial sums, no global atomics.
__global__ __launch_bounds__(256) void k_dist(const float* __restrict__ dn, double* __restrict__ pd) {
  int slot = blockIdx.z*64 + blockIdx.y*8 + blockIdx.x;
  if (blockIdx.x > blockIdx.y) { if (threadIdx.x == 0) pd[PD_DIST + slot] = 0.0; return; }
  __shared__ float As[64][36];
  __shared__ float Bs[64][36];
  int b = blockIdx.z;
  int r0 = blockIdx.y*64, c0 = blockIdx.x*64;
  const float* base = dn + (size_t)b*NN*DDIM;
  float accf[4][4];
  #pragma unroll
  for (int i = 0; i < 4; i++)
    #pragma unroll
    for (int j = 0; j < 4; j++) accf[i][j] = 0.f;
  int tx = threadIdx.x & 15, ty = threadIdx.x >> 4;
  for (int kc = 0; kc < DDIM; kc += 32) {
    __syncthreads();
    #pragma unroll
    for (int l = 0; l < 2; l++) {
      int q = threadIdx.x + l*256;
      int row = q >> 3, kq = q & 7;
      int gr = r0 + row;
      float4 va = make_float4(0.f,0.f,0.f,0.f);
      if (gr < NN) va = *(const float4*)&base[(size_t)gr*DDIM + kc + kq*4];
      *(float4*)&As[row][kq*4] = va;
      int gc = c0 + row;
      float4 vb = make_float4(0.f,0.f,0.f,0.f);
      if (gc < NN) vb = *(const float4*)&base[(size_t)gc*DDIM + kc + kq*4];
      *(float4*)&Bs[row][kq*4] = vb;
    }
    __syncthreads();
    #pragma unroll
    for (int kk = 0; kk < 32; kk += 4) {
      float4 a4[4], b4[4];
      #pragma unroll
      for (int i = 0; i < 4; i++) a4[i] = *(const float4*)&As[ty*4+i][kk];
      #pragma unroll
      for (int j = 0; j < 4; j++) b4[j] = *(const float4*)&Bs[tx*4+j][kk];
      #pragma unroll
      for (int i = 0; i < 4; i++)
        #pragma unroll
        for (int j = 0; j < 4; j++)
          accf[i][j] += a4[i].x*b4[j].x + a4[i].y*b4[j].y + a4[i].z*b4[j].z + a4[i].w*b4[j].w;
    }
  }
  double wgt = (blockIdx.x == blockIdx.y) ? 1.0 : 2.0;
  double lsum = 0.0;
  #pragma unroll
  for (int i = 0; i < 4; i++)
    #pragma unroll
    for (int j = 0; j < 4; j++)
      lsum += (double)fmaxf(accf[i][j], 0.f);
  lsum *= wgt;
  double s = blockRedSum256(lsum);
  if (threadIdx.x == 0) pd[PD_DIST + slot] = s;
}

__global__ void k_final(const double* __restrict__ pd, float* __restrict__ out) {
  int tid = threadIdx.x;
  double l;
  l = 0.0; for (int i = tid; i < 512;  i += 256) l += pd[PD_DIST + i];
  double dist = blockRedSum256(l);
  l = 0.0; for (int i = tid; i < 512;  i += 256) l += pd[PD_MS + i];
  double ms = blockRedSum256(l);
  l = 0.0; for (int i = tid; i < 512;  i += 256) l += pd[PD_MC + i];
  double mc = blockRedSum256(l);
  l = 0.0; for (int i = tid; i < NBCE; i += 256) l += pd[PD_BCE + i];
  double bce = blockRedSum256(l);
  l = 0.0; for (int i = tid; i < NCORR; i += 256) l += pd[PD_CORR + i];
  double corr = blockRedSum256(l);
  if (tid == 0) {
    float distf = (float)(dist / (double)(BB*NN*NN));
    float cornf = (float)((bce + corr) / (double)BHW);
    float cntf  = fmaxf((float)mc, 1.0f);
    float matchf = (float)ms / cntf;
    out[0] = distf + cornf + matchf;
  }
}

// ---------------- host ----------------

extern "C" void kernel_launch(void* const* d_in, const int* in_sizes, int n_in,
                              void* d_out, int out_size, void* d_ws, size_t ws_size,
                              hipStream_t stream) {
  (void)in_sizes; (void)n_in; (void)out_size; (void)ws_size;
  const float* desc      = (const float*)d_in[0];
  const float* points    = (const float*)d_in[1];
  const float* pointness = (const float*)d_in[2];
  const float* depths    = (const float*)d_in[3];
  const float* poses     = (const float*)d_in[4];
  const float* Kmat      = (const float*)d_in[5];
  const float* imgs      = (const float*)d_in[6];
  float* out = (float*)d_out;

  double* pd = (double*)d_ws;                      // partial sums first (8B aligned)
  float* f = (float*)(pd + PD_TOTAL);
  float* bufA = f;                                 // resp
  float* bufC = bufA + (size_t)BHW;                // scatter target
  float* cv_main = bufC + (size_t)BHW;             // 8 x 4800
  int*   ci_main = (int*)(cv_main + BB*NBLK);
  // --- zero region start ---
  float* cv_ovf  = (float*)(ci_main + BB*NBLK);    // 8 x 3392
  int*   ci_ovf  = (int*)(cv_ovf + BB*NOVF);
  int*   ovf     = (int*)(ci_ovf + BB*NOVF);       // 8 x stride-64 counters
  // --- zero region end ---
  float* topv = (float*)(ovf + BB*64);
  int*   topi = (int*)(topv + BB*NN);
  float* psrc = (float*)(topi + BB*NN);
  float* pdst = psrc + BB*NN*2;
  int*   minv = (int*)(pdst + BB*BB*NN*2);
  float* dn   = (float*)(minv + BB*BB*NN);         // 8*500*256 floats
  int*   list = (int*)(dn + (size_t)BB*NN*DDIM);   // 32000 ints

  size_t zbytes = (size_t)BB*NOVF*8 + (size_t)BB*64*4;
  hipMemsetAsync(cv_ovf, 0, zbytes, stream);
  hipMemsetAsync(list, 0xFF, (size_t)NLIST*4, stream);   // -1 sentinel

  dim3 tgrid(WW/32, HH/8, BB);

  k_gfused <<<tgrid, 256, 0, stream>>>(imgs, bufA);
  k_nmscand<<<tgrid, 256, 0, stream>>>(bufA, cv_main, ci_main, cv_ovf, ci_ovf, ovf, bufC);
  k_topsel <<<BB, 1024, 0, stream>>>(cv_main, ci_main, cv_ovf, ci_ovf, topv, topi);
  k_scatfuse<<<(BB*NN + 255)/256, 256, 0, stream>>>(topv, topi, depths, poses, Kmat,
                                                    (unsigned int*)bufC, list);
  k_bce_stream<<<NBCE, 256, 0, stream>>>(pointness, pd);
  k_bcecorr<<<NCORR, 256, 0, stream>>>(list, bufC, pointness, pd);
  k_dn    <<<BB*NN, DDIM, 0, stream>>>(desc, dn);
  k_msrcdst<<<(BB*NN + 255)/256, 256, 0, stream>>>(points, depths, poses, Kmat, psrc, pdst, minv);
  k_match <<<dim3(BB*BB, MSPLIT), 256, 0, stream>>>(psrc, pdst, minv, dn, pd);
  k_dist  <<<dim3(8, 8, BB), 256, 0, stream>>>(dn, pd);
  k_final <<<1, 256, 0, stream>>>(pd, out);
}

// Round 6
// 165.789 us; speedup vs baseline: 6.1410x; 1.0615x over previous
//
#include <hip/hip_runtime.h>
#include <math.h>

#define BB 8
#define NN 500
#define DDIM 256
#define HH 480
#define WW 640
#define HWSZ (HH*WW)        // 307200
#define BHW (BB*HWSZ)       // 2457600
#define NBLK 4800           // 8x8 blocks per image
#define NOVF 3392           // overflow candidate slots per image
#define MSPLIT 8
#define MCH 63              // ceil(500/8)
#define NLIST (BB*NN*BB)    // 32000 deterministic list slots
#define NBCE 1024           // bce streaming blocks
#define NCORR 125           // ceil(32000/256)

// partial-sum slot map (doubles at ws start)
#define PD_DIST  0          // 512
#define PD_MS    512        // 512
#define PD_MC    1024       // 512
#define PD_BCE   1536       // 1024
#define PD_CORR  2560       // 125
#define PD_TOTAL 2688

// ---------------- helpers ----------------

static __device__ __forceinline__ float wredmaxf(float v) {
  #pragma unroll
  for (int o = 1; o < 64; o <<= 1) v = fmaxf(v, __shfl_xor(v, o, 64));
  return v;
}

static __device__ __forceinline__ double blockRedSum256(double v) {
  __shared__ double sp[4];
  __syncthreads();
  #pragma unroll
  for (int o = 32; o > 0; o >>= 1) v += __shfl_down(v, o, 64);
  int lane = threadIdx.x & 63, wid = threadIdx.x >> 6;
  if (lane == 0) sp[wid] = v;
  __syncthreads();
  double r = 0.0;
  if (threadIdx.x == 0) r = sp[0] + sp[1] + sp[2] + sp[3];
  return r;
}

static __device__ __forceinline__ float bilin(const float* __restrict__ img, float px, float py) {
  float x = fminf(fmaxf(px, 0.0f), 639.0f);
  float y = fminf(fmaxf(py, 0.0f), 479.0f);
  float x0 = floorf(x), y0 = floorf(y);
  float x1 = fminf(x0 + 1.0f, 639.0f);
  float y1 = fminf(y0 + 1.0f, 479.0f);
  float wx = x - x0, wy = y - y0;
  int x0i = (int)x0, x1i = (int)x1, y0i = (int)y0, y1i = (int)y1;
  float v00 = img[y0i*WW + x0i], v01 = img[y0i*WW + x1i];
  float v10 = img[y1i*WW + x0i], v11 = img[y1i*WW + x1i];
  return v00*(1.0f-wx)*(1.0f-wy) + v01*wx*(1.0f-wy) + v10*(1.0f-wx)*wy + v11*wx*wy;
}

// world point from pixel (px,py) in image bimg; replicates reference op order
static __device__ void src_compute(float px, float py, const float* __restrict__ dep,
                                   const float* __restrict__ poses, const float* __restrict__ Km,
                                   int bimg, float* Xw, float* dout) {
  float d = bilin(dep, px, py);
  const float* Kb = Km + bimg*9;
  double a00=Kb[0],a01=Kb[1],a02=Kb[2],a10=Kb[3],a11=Kb[4],a12=Kb[5],a20=Kb[6],a21=Kb[7],a22=Kb[8];
  double det = a00*(a11*a22-a12*a21) - a01*(a10*a22-a12*a20) + a02*(a10*a21-a11*a20);
  double id = 1.0/det;
  float i00=(float)((a11*a22-a12*a21)*id), i01=(float)((a02*a21-a01*a22)*id), i02=(float)((a01*a12-a02*a11)*id);
  float i10=(float)((a12*a20-a10*a22)*id), i11=(float)((a00*a22-a02*a20)*id), i12=(float)((a02*a10-a00*a12)*id);
  float i20=(float)((a10*a21-a11*a20)*id), i21=(float)((a01*a20-a00*a21)*id), i22=(float)((a00*a11-a01*a10)*id);
  float c0 = i00*px + i01*py + i02;
  float c1 = i10*px + i11*py + i12;
  float c2 = i20*px + i21*py + i22;
  float X0 = d*c0, X1 = d*c1, X2 = d*c2;
  const float* P = poses + bimg*16;
  Xw[0] = (P[0]*X0 + P[1]*X1 + P[2]*X2)  + P[3];
  Xw[1] = (P[4]*X0 + P[5]*X1 + P[6]*X2)  + P[7];
  Xw[2] = (P[8]*X0 + P[9]*X1 + P[10]*X2) + P[11];
  *dout = d;
}

static __device__ void project_to(const float* __restrict__ poses, const float* __restrict__ Km,
                                  int j, const float* Xw, float dsrc,
                                  float* pnx, float* pny, bool* invis) {
  const float* P = poses + j*16;
  float d0 = Xw[0]-P[3], d1 = Xw[1]-P[7], d2 = Xw[2]-P[11];
  float Xj0 = P[0]*d0 + P[4]*d1 + P[8]*d2;
  float Xj1 = P[1]*d0 + P[5]*d1 + P[9]*d2;
  float Xj2 = P[2]*d0 + P[6]*d1 + P[10]*d2;
  const float* Kb = Km + j*9;
  float u = Kb[0]*Xj0 + Kb[1]*Xj1 + Kb[2]*Xj2;
  float v = Kb[3]*Xj0 + Kb[4]*Xj1 + Kb[5]*Xj2;
  float z = Kb[6]*Xj0 + Kb[7]*Xj1 + Kb[8]*Xj2;
  float zs = (fabsf(z) < 1e-6f) ? 1e-6f : z;
  float pu = u/zs, pv = v/zs;
  float nx = 2.0f*pu/639.0f - 1.0f;
  float ny = 2.0f*pv/479.0f - 1.0f;
  *pnx = nx; *pny = ny;
  *invis = (z <= 1e-6f) || (fabsf(nx) > 1.0f) || (fabsf(ny) > 1.0f) || (dsrc <= 0.0f);
}

// ---------------- kernels ----------------

// fused gray -> sobel -> GFTT with SEPARABLE gaussian (w[i][j] = G[i]*G[j]).
// 32x32 output tile; gray halo 4 (40x40); sobel halo 3 (38x38);
// H-pass 38x32; V-pass register-blocked 4 rows/thread.
__global__ __launch_bounds__(256) void k_gfused(const float* __restrict__ imgs, float* __restrict__ resp) {
  __shared__ float smem[6536];
  __shared__ float Gw[7];
  float* sgxy = smem;              // [38][38][2] interleaved gx,gy  (2888 floats)
  float* gray = smem + 2888;       // [40][41]                      (1640 floats, dead after sobel)
  float* hxx  = smem + 2888;       // [38][32] aliases gray
  float* hyy  = hxx + 1216;
  float* hxy  = hyy + 1216;
  int bx = blockIdx.x*32, by = blockIdx.y*32, b = blockIdx.z;
  int tid = threadIdx.x;
  if (tid < 7) {
    double g[7]; double s = 0.0;
    for (int q = 0; q < 7; q++) { double r = (double)(q-3); g[q] = exp(-(r*r)/2.0); s += g[q]; }
    Gw[tid] = (float)(g[tid]/s);
  }
  const float* ib = imgs + (size_t)b*3*HWSZ;
  for (int e = tid; e < 40*40; e += 256) {
    int ly = e/40, lx = e%40;
    int X = bx - 4 + lx, Y = by - 4 + ly;
    float v = 0.f;
    if (X>=0 && X<WW && Y>=0 && Y<HH) {
      int p = Y*WW + X;
      v = 0.299f*ib[p] + 0.587f*ib[HWSZ+p] + 0.114f*ib[2*HWSZ+p];
    }
    gray[ly*41+lx] = v;
  }
  __syncthreads();
  const float kxw[3][3] = {{-0.125f,0.f,0.125f},{-0.25f,0.f,0.25f},{-0.125f,0.f,0.125f}};
  for (int e = tid; e < 38*38; e += 256) {
    int rr = e/38, c = e%38;
    int X = bx - 3 + c, Y = by - 3 + rr;
    float sx = 0.f, sy = 0.f;
    #pragma unroll
    for (int i = 0; i < 3; i++)
      #pragma unroll
      for (int j = 0; j < 3; j++) {
        float v = gray[(rr+i)*41 + (c+j)];
        sx += kxw[i][j]*v;
        sy += kxw[j][i]*v;
      }
    bool in = (X>=0 && X<WW && Y>=0 && Y<HH);
    sgxy[e*2]   = in ? sx : 0.f;    // conv zero-pad semantics
    sgxy[e*2+1] = in ? sy : 0.f;
  }
  __syncthreads();
  // H-pass (overwrites gray region; gray is dead)
  for (int e = tid; e < 38*32; e += 256) {
    int rr = e >> 5, co = e & 31;
    int base = (rr*38 + co)*2;
    float axx = 0.f, ayy = 0.f, axy = 0.f;
    #pragma unroll
    for (int j = 0; j < 7; j++) {
      float a = sgxy[base + j*2];
      float c = sgxy[base + j*2 + 1];
      float Gj = Gw[j];
      axx += Gj*(a*a); ayy += Gj*(c*c); axy += Gj*(a*c);
    }
    hxx[e] = axx; hyy[e] = ayy; hxy[e] = axy;
  }
  __syncthreads();
  // V-pass: thread (tx, ty) -> col tx, rows ty*4 .. ty*4+3
  int tx = tid & 31, ty = tid >> 5;
  int r0 = ty*4;
  float axx[4] = {0,0,0,0}, ayy[4] = {0,0,0,0}, axy[4] = {0,0,0,0};
  #pragma unroll
  for (int rr = 0; rr < 10; rr++) {
    int r = r0 + rr;
    float vxx = hxx[r*32+tx], vyy = hyy[r*32+tx], vxy = hxy[r*32+tx];
    #pragma unroll
    for (int o = 0; o < 4; o++) {
      int i = rr - o;
      if (i >= 0 && i <= 6) {
        float Gi = Gw[i];
        axx[o] += Gi*vxx; ayy[o] += Gi*vyy; axy[o] += Gi*vxy;
      }
    }
  }
  #pragma unroll
  for (int o = 0; o < 4; o++) {
    float tr = axx[o] + ayy[o];
    float det = axx[o]*ayy[o] - axy[o]*axy[o];
    float disc = fmaxf(tr*tr - 4.0f*det, 0.f);
    int y = by + r0 + o;
    resp[(size_t)b*HWSZ + y*WW + (bx+tx)] = 0.5f*(tr - sqrtf(disc));
  }
}

// fused SEPARABLE 5x5 NMS + per-8x8-block candidate extraction (+ zero scatter target)
// 32x32 tile, halo 2 (36x36). max is order-exact -> bit-identical to 2D max.
__global__ __launch_bounds__(256) void k_nmscand(const float* __restrict__ resp, float* __restrict__ cv,
                          int* __restrict__ ci, float* __restrict__ cvo,
                          int* __restrict__ cio, int* __restrict__ ovf,
                          float* __restrict__ target) {
  __shared__ float s[36*37];
  __shared__ float hm[36*32];
  __shared__ float c32[32*32];
  int bx = blockIdx.x*32, by = blockIdx.y*32, b = blockIdx.z;
  int tid = threadIdx.x;
  const float* r = resp + (size_t)b*HWSZ;
  for (int e = tid; e < 36*36; e += 256) {
    int ly = e/36, lx = e%36;
    int X = bx - 2 + lx, Y = by - 2 + ly;
    s[ly*37+lx] = (X>=0 && X<WW && Y>=0 && Y<HH) ? r[Y*WW+X] : -INFINITY;
  }
  __syncthreads();
  for (int e = tid; e < 36*32; e += 256) {
    int rr = e >> 5, co = e & 31;
    int base = rr*37 + co;
    float m = s[base];
    m = fmaxf(m, s[base+1]); m = fmaxf(m, s[base+2]);
    m = fmaxf(m, s[base+3]); m = fmaxf(m, s[base+4]);
    hm[e] = m;
  }
  __syncthreads();
  for (int e = tid; e < 1024; e += 256) {
    int y = e >> 5, x = e & 31;
    float mp = hm[y*32+x];
    mp = fmaxf(mp, hm[(y+1)*32+x]); mp = fmaxf(mp, hm[(y+2)*32+x]);
    mp = fmaxf(mp, hm[(y+3)*32+x]); mp = fmaxf(mp, hm[(y+4)*32+x]);
    float v = s[(y+2)*37 + (x+2)];
    c32[e] = (v == mp) ? v : 0.f;
    target[(size_t)b*HWSZ + (by+y)*WW + (bx+x)] = 0.f;
  }
  __syncthreads();
  // 16 8x8 cand blocks per tile; wave wv handles 4 sequentially
  int wv = tid >> 6, lane = tid & 63;
  int ly8 = lane >> 3, lx8 = lane & 7;
  for (int q = 0; q < 4; q++) {
    int bb = wv*4 + q;
    int oy = (bb >> 2)*8, ox = (bb & 3)*8;
    float cval = c32[(oy+ly8)*32 + ox+lx8];
    float bm = wredmaxf(cval);
    bool win = (cval > 0.f) && (cval == bm);
    unsigned long long mask = __ballot(win);
    int BY = blockIdx.y*4 + (bb >> 2), BX = blockIdx.x*4 + (bb & 3);
    int rblk = BY*80 + BX;
    int gidx = (by+oy+ly8)*WW + (bx+ox+lx8);
    if (mask == 0ull) {
      if (lane == 0) { cv[b*NBLK+rblk] = 0.f; ci[b*NBLK+rblk] = 0; }
    } else if (win) {
      int rank = __popcll(mask & ((1ull << lane) - 1ull));
      if (rank == 0) { cv[b*NBLK+rblk] = cval; ci[b*NBLK+rblk] = gidx; }
      else {
        int pos = atomicAdd(&ovf[b*64], 1);
        if (pos < NOVF) { cvo[b*NOVF+pos] = cval; cio[b*NOVF+pos] = gidx; }
      }
    }
  }
}

// top-500 selection via MSB-first radix select on 64-bit keys
// key = (float_bits << 32) | ~idx  -> top-k order == (value desc, idx asc).
__global__ __launch_bounds__(1024) void k_topsel(const float* __restrict__ cv, const int* __restrict__ ci,
                                                 const float* __restrict__ cvo, const int* __restrict__ cio,
                                                 float* __restrict__ topv, int* __restrict__ topi) {
  __shared__ unsigned int hist[256];
  __shared__ unsigned int ss[257];
  __shared__ unsigned long long prefix_s;
  __shared__ int kk_s, cgt_s, ceq_s;
  int b = blockIdx.x;
  unsigned long long kreg[8];
  #pragma unroll
  for (int q = 0; q < 8; q++) {
    int e = threadIdx.x + q*1024;
    float v; unsigned int idx;
    if (e < NBLK) { v = cv[b*NBLK+e];       idx = (unsigned int)ci[b*NBLK+e]; }
    else          { v = cvo[b*NOVF+e-NBLK]; idx = (unsigned int)cio[b*NOVF+e-NBLK]; }
    kreg[q] = ((unsigned long long)__float_as_uint(v) << 32) | (0xFFFFFFFFu - idx);
  }
  if (threadIdx.x == 0) { prefix_s = 0ull; kk_s = NN; ss[256] = 0u; }
  __syncthreads();
  for (int round = 0; round < 8; round++) {
    int shift = 56 - 8*round;
    if (threadIdx.x < 256) hist[threadIdx.x] = 0u;
    __syncthreads();
    unsigned long long prefix = prefix_s;
    int kk = kk_s;
    unsigned long long himask = (round == 0) ? 0ull : (~0ull << (shift + 8));
    #pragma unroll
    for (int q = 0; q < 8; q++) {
      if ((kreg[q] & himask) == prefix) {
        unsigned int d = (unsigned int)((kreg[q] >> shift) & 255ull);
        atomicAdd(&hist[d], 1u);
      }
    }
    __syncthreads();
    if (threadIdx.x < 256) ss[threadIdx.x] = hist[threadIdx.x];
    __syncthreads();
    for (int off = 1; off < 256; off <<= 1) {
      unsigned int nv = 0u;
      if (threadIdx.x < 256)
        nv = ss[threadIdx.x] + ((threadIdx.x + off < 256) ? ss[threadIdx.x + off] : 0u);
      __syncthreads();
      if (threadIdx.x < 256) ss[threadIdx.x] = nv;
      __syncthreads();
    }
    if (threadIdx.x < 256) {
      int S = (int)ss[threadIdx.x];
      int Sn = (int)ss[threadIdx.x + 1];
      if (S >= kk && Sn < kk) {
        prefix_s = prefix | ((unsigned long long)threadIdx.x << shift);
        kk_s = kk - Sn;
      }
    }
    __syncthreads();
  }
  unsigned long long T = prefix_s;
  int kk = kk_s;
  if (threadIdx.x == 0) { cgt_s = 0; ceq_s = 0; }
  __syncthreads();
  #pragma unroll
  for (int q = 0; q < 8; q++) {
    unsigned long long key = kreg[q];
    int slot = -1;
    if (key > T) slot = atomicAdd(&cgt_s, 1);
    else if (key == T) {
      int p = atomicAdd(&ceq_s, 1);
      if (p < kk) slot = (NN-1) - p;
    }
    if (slot >= 0) {
      topv[b*NN+slot] = __uint_as_float((unsigned int)(key >> 32));
      topi[b*NN+slot] = (int)(0xFFFFFFFFu - (unsigned int)(key & 0xFFFFFFFFull));
    }
  }
}

// fused source-point compute + 8-way projection scatter.
// First writer of each target pixel (atomicMax old==0) records the pixel at a
// DETERMINISTIC slot t*BB+j in the -1-initialized list (exactly once per pixel).
__global__ void k_scatfuse(const float* __restrict__ topv, const int* __restrict__ topi,
                           const float* __restrict__ depths, const float* __restrict__ poses,
                           const float* __restrict__ Km, unsigned int* __restrict__ target,
                           int* __restrict__ list) {
  int t = blockIdx.x*256 + threadIdx.x;
  if (t >= BB*NN) return;
  int i = t / NN;
  float val = topv[t];
  if (val <= 0.f) return;
  int idx = topi[t];
  float xs = (float)(idx % WW), ys = (float)(idx / WW);
  float cx = 2.0f*xs/639.0f - 1.0f;
  float cy = 2.0f*ys/479.0f - 1.0f;
  float px = (cx + 1.0f)*0.5f*639.0f;
  float py = (cy + 1.0f)*0.5f*479.0f;
  float Xw[3], d;
  src_compute(px, py, depths + (size_t)i*HWSZ, poses, Km, i, Xw, &d);
  for (int j = 0; j < BB; j++) {
    float nx, ny; bool inv;
    project_to(poses, Km, j, Xw, d, &nx, &ny, &inv);
    if (inv) { nx = -2.0f; ny = -2.0f; }
    float fx = rintf((nx + 1.0f)*0.5f*639.0f);
    float fy = rintf((ny + 1.0f)*0.5f*479.0f);
    int wq = (int)fx, hq = (int)fy;
    if (wq < 0) continue;
    int hc = min(max(hq, 0), HH-1), wc = min(max(wq, 0), WW-1);
    int p = j*HWSZ + hc*WW + wc;
    unsigned int old = atomicMax(&target[p], __float_as_uint(val));
    if (old == 0u) list[t*BB + j] = p;   // first writer -> exactly once per pixel
  }
}

// streaming BCE over all pixels assuming t=false: sum of -max(log(1-p),-100)
__global__ void k_bce_stream(const float* __restrict__ pn, double* __restrict__ pd) {
  int idx = blockIdx.x*256 + threadIdx.x;
  double l = 0.0;
  for (int q = idx; q < BHW/4; q += NBCE*256) {
    float4 v = ((const float4*)pn)[q];
    l -= (double)fmaxf(logf(1.f - v.x), -100.f);
    l -= (double)fmaxf(logf(1.f - v.y), -100.f);
    l -= (double)fmaxf(logf(1.f - v.z), -100.f);
    l -= (double)fmaxf(logf(1.f - v.w), -100.f);
  }
  double s = blockRedSum256(l);
  if (threadIdx.x == 0) pd[PD_BCE + blockIdx.x] = s;
}

// correction at scattered pixels: t can only be true where target>0 (v>0 required),
// i.e. exactly the listed pixels. Evaluate 5x5 max there; if t, swap the BCE term.
__global__ void k_bcecorr(const int* __restrict__ list, const float* __restrict__ target,
                          const float* __restrict__ pn, double* __restrict__ pd) {
  int idx = blockIdx.x*256 + threadIdx.x;
  double l = 0.0;
  if (idx < NLIST) {
    int p = list[idx];
    if (p >= 0) {
      int j = p / HWSZ, pix = p % HWSZ;
      int y = pix / WW, x = pix % WW;
      const float* tb = target + (size_t)j*HWSZ;
      float v = tb[pix];
      float mp = -INFINITY;
      for (int dy = -2; dy <= 2; dy++) {
        int yy = y + dy; if (yy < 0 || yy >= HH) continue;
        for (int dx = -2; dx <= 2; dx++) {
          int xx = x + dx; if (xx < 0 || xx >= WW) continue;
          mp = fmaxf(mp, tb[yy*WW+xx]);
        }
      }
      if (v > 0.f && v == mp) {
        float pv = pn[p];
        l = (double)(-fmaxf(logf(pv), -100.f)) + (double)fmaxf(logf(1.f - pv), -100.f);
      }
    }
  }
  double s = blockRedSum256(l);
  if (threadIdx.x == 0) pd[PD_CORR + blockIdx.x] = s;
}

__global__ void k_dn(const float* __restrict__ desc, float* __restrict__ dn) {
  int row = blockIdx.x;
  int d = threadIdx.x;
  float v = desc[(size_t)row*DDIM + d];
  __shared__ float sp[4];
  __shared__ float den_s;
  float s = v*v;
  #pragma unroll
  for (int o = 32; o > 0; o >>= 1) s += __shfl_down(s, o, 64);
  int lane = threadIdx.x & 63, wid = threadIdx.x >> 6;
  if (lane == 0) sp[wid] = s;
  __syncthreads();
  if (threadIdx.x == 0) den_s = fmaxf(sqrtf(sp[0]+sp[1]+sp[2]+sp[3]), 1e-8f);
  __syncthreads();
  dn[(size_t)row*DDIM + d] = v / den_s;
}

// fused match source compute + 8-way projection
__global__ void k_msrcdst(const float* __restrict__ points, const float* __restrict__ depths,
                          const float* __restrict__ poses, const float* __restrict__ Km,
                          float* __restrict__ psrc, float* __restrict__ pdst, int* __restrict__ minv) {
  int t = blockIdx.x*256 + threadIdx.x;
  if (t >= BB*NN) return;
  int a = t / NN, m = t % NN;
  float p0 = points[t*2], p1 = points[t*2+1];
  float px = (p0 + 1.0f)*0.5f*639.0f;
  float py = (p1 + 1.0f)*0.5f*479.0f;
  float Xw[3], d;
  src_compute(px, py, depths + (size_t)a*HWSZ, poses, Km, a, Xw, &d);
  psrc[t*2] = px; psrc[t*2+1] = py;
  for (int b = 0; b < BB; b++) {
    float nx, ny; bool inv;
    project_to(poses, Km, b, Xw, d, &nx, &ny, &inv);
    int o = (a*BB + b)*NN + m;
    pdst[o*2]   = (nx + 1.0f)*0.5f*639.0f;
    pdst[o*2+1] = (ny + 1.0f)*0.5f*479.0f;
    minv[o] = inv ? 1 : 0;
  }
}

// match: grid (BB*BB, MSPLIT); partial sums, no global atomics
__global__ void k_match(const float* __restrict__ psrc, const float* __restrict__ pdst,
                        const int* __restrict__ minv, const float* __restrict__ dn,
                        double* __restrict__ pd) {
  __shared__ float spd[2*NN], ssrc[2*NN];
  __shared__ int sinv[NN];
  int ab = blockIdx.x; int b = ab % BB; int a = ab / BB;
  int mm0 = blockIdx.y * MCH;
  int mmN = min(NN, mm0 + MCH);
  for (int e = threadIdx.x; e < NN; e += 256) {
    spd[e*2]   = pdst[(ab*NN+e)*2];
    spd[e*2+1] = pdst[(ab*NN+e)*2+1];
    sinv[e]    = minv[ab*NN+e];
    ssrc[e*2]   = psrc[(b*NN+e)*2];
    ssrc[e*2+1] = psrc[(b*NN+e)*2+1];
  }
  __syncthreads();
  double lsum = 0.0, lcnt = 0.0;
  int npairs = (mmN - mm0) * NN;
  for (int idx = threadIdx.x; idx < npairs; idx += 256) {
    int mm = mm0 + idx / NN;
    int nn = idx % NN;
    if (nn >= mm) continue;          // n < m
    if (sinv[nn]) continue;          // reference quirk: invis indexed by n
    float dx = ssrc[nn*2]   - spd[mm*2];
    float dy = ssrc[nn*2+1] - spd[mm*2+1];
    if (dx*dx + dy*dy <= 1.0f) {
      const float* da = dn + ((size_t)a*NN + mm)*DDIM;
      const float* db = dn + ((size_t)b*NN + nn)*DDIM;
      float dot = 0.f;
      for (int q = 0; q < DDIM; q++) dot += db[q]*da[q];
      lsum += (double)(1.0f - dot);
      lcnt += 1.0;
    }
  }
  int slot = blockIdx.y*64 + blockIdx.x;
  double s = blockRedSum256(lsum);
  if (threadIdx.x == 0) pd[PD_MS + slot] = s;
  double c2 = blockRedSum256(lcnt);
  if (threadIdx.x == 0) pd[PD_MC + slot] = c2;
}

// distinction: register-tiled 64x64 f32 GEMM tiles on dn * dn^T (symmetric:
// lower-triangle tiles x2). Partial sums, no global atomics.
__global__ __launch_bounds__(256) void k_dist(const float* __restrict__ dn, double* __restrict__ pd) {
  int slot = blockIdx.z*64 + blockIdx.y*8 + blockIdx.x;
  if (blockIdx.x > blockIdx.y) { if (threadIdx.x == 0) pd[PD_DIST + slot] = 0.0; return; }
  __shared__ float As[64][36];
  __shared__ float Bs[64][36];
  int b = blockIdx.z;
  int r0 = blockIdx.y*64, c0 = blockIdx.x*64;
  const float* base = dn + (size_t)b*NN*DDIM;
  float accf[4][4];
  #pragma unroll
  for (int i = 0; i < 4; i++)
    #pragma unroll
    for (int j = 0; j < 4; j++) accf[i][j] = 0.f;
  int tx = threadIdx.x & 15, ty = threadIdx.x >> 4;
  for (int kc = 0; kc < DDIM; kc += 32) {
    __syncthreads();
    #pragma unroll
    for (int l = 0; l < 2; l++) {
      int q = threadIdx.x + l*256;
      int row = q >> 3, kq = q & 7;
      int gr = r0 + row;
      float4 va = make_float4(0.f,0.f,0.f,0.f);
      if (gr < NN) va = *(const float4*)&base[(size_t)gr*DDIM + kc + kq*4];
      *(float4*)&As[row][kq*4] = va;
      int gc = c0 + row;
      float4 vb = make_float4(0.f,0.f,0.f,0.f);
      if (gc < NN) vb = *(const float4*)&base[(size_t)gc*DDIM + kc + kq*4];
      *(float4*)&Bs[row][kq*4] = vb;
    }
    __syncthreads();
    #pragma unroll
    for (int kk = 0; kk < 32; kk += 4) {
      float4 a4[4], b4[4];
      #pragma unroll
      for (int i = 0; i < 4; i++) a4[i] = *(const float4*)&As[ty*4+i][kk];
      #pragma unroll
      for (int j = 0; j < 4; j++) b4[j] = *(const float4*)&Bs[tx*4+j][kk];
      #pragma unroll
      for (int i = 0; i < 4; i++)
        #pragma unroll
        for (int j = 0; j < 4; j++)
          accf[i][j] += a4[i].x*b4[j].x + a4[i].y*b4[j].y + a4[i].z*b4[j].z + a4[i].w*b4[j].w;
    }
  }
  double wgt = (blockIdx.x == blockIdx.y) ? 1.0 : 2.0;
  double lsum = 0.0;
  #pragma unroll
  for (int i = 0; i < 4; i++)
    #pragma unroll
    for (int j = 0; j < 4; j++)
      lsum += (double)fmaxf(accf[i][j], 0.f);
  lsum *= wgt;
  double s = blockRedSum256(lsum);
  if (threadIdx.x == 0) pd[PD_DIST + slot] = s;
}

__global__ void k_final(const double* __restrict__ pd, float* __restrict__ out) {
  int tid = threadIdx.x;
  double l;
  l = 0.0; for (int i = tid; i < 512;  i += 256) l += pd[PD_DIST + i];
  double dist = blockRedSum256(l);
  l = 0.0; for (int i = tid; i < 512;  i += 256) l += pd[PD_MS + i];
  double ms = blockRedSum256(l);
  l = 0.0; for (int i = tid; i < 512;  i += 256) l += pd[PD_MC + i];
  double mc = blockRedSum256(l);
  l = 0.0; for (int i = tid; i < NBCE; i += 256) l += pd[PD_BCE + i];
  double bce = blockRedSum256(l);
  l = 0.0; for (int i = tid; i < NCORR; i += 256) l += pd[PD_CORR + i];
  double corr = blockRedSum256(l);
  if (tid == 0) {
    float distf = (float)(dist / (double)(BB*NN*NN));
    float cornf = (float)((bce + corr) / (double)BHW);
    float cntf  = fmaxf((float)mc, 1.0f);
    float matchf = (float)ms / cntf;
    out[0] = distf + cornf + matchf;
  }
}

// ---------------- host ----------------

extern "C" void kernel_launch(void* const* d_in, const int* in_sizes, int n_in,
                              void* d_out, int out_size, void* d_ws, size_t ws_size,
                              hipStream_t stream) {
  (void)in_sizes; (void)n_in; (void)out_size; (void)ws_size;
  const float* desc      = (const float*)d_in[0];
  const float* points    = (const float*)d_in[1];
  const float* pointness = (const float*)d_in[2];
  const float* depths    = (const float*)d_in[3];
  const float* poses     = (const float*)d_in[4];
  const float* Kmat      = (const float*)d_in[5];
  const float* imgs      = (const float*)d_in[6];
  float* out = (float*)d_out;

  double* pd = (double*)d_ws;                      // partial sums first (8B aligned)
  float* f = (float*)(pd + PD_TOTAL);
  float* bufA = f;                                 // resp
  float* bufC = bufA + (size_t)BHW;                // scatter target
  float* cv_main = bufC + (size_t)BHW;             // 8 x 4800
  int*   ci_main = (int*)(cv_main + BB*NBLK);
  // --- zero region start ---
  float* cv_ovf  = (float*)(ci_main + BB*NBLK);    // 8 x 3392
  int*   ci_ovf  = (int*)(cv_ovf + BB*NOVF);
  int*   ovf     = (int*)(ci_ovf + BB*NOVF);       // 8 x stride-64 counters
  // --- zero region end ---
  float* topv = (float*)(ovf + BB*64);
  int*   topi = (int*)(topv + BB*NN);
  float* psrc = (float*)(topi + BB*NN);
  float* pdst = psrc + BB*NN*2;
  int*   minv = (int*)(pdst + BB*BB*NN*2);
  float* dn   = (float*)(minv + BB*BB*NN);         // 8*500*256 floats
  int*   list = (int*)(dn + (size_t)BB*NN*DDIM);   // 32000 ints

  size_t zbytes = (size_t)BB*NOVF*8 + (size_t)BB*64*4;
  hipMemsetAsync(cv_ovf, 0, zbytes, stream);
  hipMemsetAsync(list, 0xFF, (size_t)NLIST*4, stream);   // -1 sentinel

  dim3 tgrid(WW/32, HH/32, BB);                    // 20 x 15 x 8

  k_gfused <<<tgrid, 256, 0, stream>>>(imgs, bufA);
  k_nmscand<<<tgrid, 256, 0, stream>>>(bufA, cv_main, ci_main, cv_ovf, ci_ovf, ovf, bufC);
  k_topsel <<<BB, 1024, 0, stream>>>(cv_main, ci_main, cv_ovf, ci_ovf, topv, topi);
  k_scatfuse<<<(BB*NN + 255)/256, 256, 0, stream>>>(topv, topi, depths, poses, Kmat,
                                                    (unsigned int*)bufC, list);
  k_bce_stream<<<NBCE, 256, 0, stream>>>(pointness, pd);
  k_bcecorr<<<NCORR, 256, 0, stream>>>(list, bufC, pointness, pd);
  k_dn    <<<BB*NN, DDIM, 0, stream>>>(desc, dn);
  k_msrcdst<<<(BB*NN + 255)/256, 256, 0, stream>>>(points, depths, poses, Kmat, psrc, pdst, minv);
  k_match <<<dim3(BB*BB, MSPLIT), 256, 0, stream>>>(psrc, pdst, minv, dn, pd);
  k_dist  <<<dim3(8, 8, BB), 256, 0, stream>>>(dn, pd);
  k_final <<<1, 256, 0, stream>>>(pd, out);
}

// Round 7
// 158.607 us; speedup vs baseline: 6.4190x; 1.0453x over previous
//
#include <hip/hip_runtime.h>
#include <math.h>

#define BB 8
#define NN 500
#define DDIM 256
#define HH 480
#define WW 640
#define HWSZ (HH*WW)        // 307200
#define BHW (BB*HWSZ)       // 2457600
#define NBLK 4800           // 8x8 blocks per image
#define NOVF 3392           // overflow candidate slots per image
#define MSPLIT 8
#define MCH 63              // ceil(500/8)
#define NLIST (BB*NN*BB)    // 32000 deterministic list slots
#define NBCE 1024           // bce streaming blocks
#define NCORR 125           // ceil(32000/256)

// partial-sum slot map (doubles at ws start)
#define PD_DIST  0          // 512
#define PD_MS    512        // 512
#define PD_MC    1024       // 512
#define PD_BCE   1536       // 1024
#define PD_CORR  2560       // 125
#define PD_TOTAL 2688

// ---------------- helpers ----------------

static __device__ __forceinline__ float wredmaxf(float v) {
  #pragma unroll
  for (int o = 1; o < 64; o <<= 1) v = fmaxf(v, __shfl_xor(v, o, 64));
  return v;
}

static __device__ __forceinline__ double blockRedSum256(double v) {
  __shared__ double sp[4];
  __syncthreads();
  #pragma unroll
  for (int o = 32; o > 0; o >>= 1) v += __shfl_down(v, o, 64);
  int lane = threadIdx.x & 63, wid = threadIdx.x >> 6;
  if (lane == 0) sp[wid] = v;
  __syncthreads();
  double r = 0.0;
  if (threadIdx.x == 0) r = sp[0] + sp[1] + sp[2] + sp[3];
  return r;
}

static __device__ __forceinline__ float bilin(const float* __restrict__ img, float px, float py) {
  float x = fminf(fmaxf(px, 0.0f), 639.0f);
  float y = fminf(fmaxf(py, 0.0f), 479.0f);
  float x0 = floorf(x), y0 = floorf(y);
  float x1 = fminf(x0 + 1.0f, 639.0f);
  float y1 = fminf(y0 + 1.0f, 479.0f);
  float wx = x - x0, wy = y - y0;
  int x0i = (int)x0, x1i = (int)x1, y0i = (int)y0, y1i = (int)y1;
  float v00 = img[y0i*WW + x0i], v01 = img[y0i*WW + x1i];
  float v10 = img[y1i*WW + x0i], v11 = img[y1i*WW + x1i];
  return v00*(1.0f-wx)*(1.0f-wy) + v01*wx*(1.0f-wy) + v10*(1.0f-wx)*wy + v11*wx*wy;
}

// world point from pixel (px,py) in image bimg; replicates reference op order
static __device__ void src_compute(float px, float py, const float* __restrict__ dep,
                                   const float* __restrict__ poses, const float* __restrict__ Km,
                                   int bimg, float* Xw, float* dout) {
  float d = bilin(dep, px, py);
  const float* Kb = Km + bimg*9;
  double a00=Kb[0],a01=Kb[1],a02=Kb[2],a10=Kb[3],a11=Kb[4],a12=Kb[5],a20=Kb[6],a21=Kb[7],a22=Kb[8];
  double det = a00*(a11*a22-a12*a21) - a01*(a10*a22-a12*a20) + a02*(a10*a21-a11*a20);
  double id = 1.0/det;
  float i00=(float)((a11*a22-a12*a21)*id), i01=(float)((a02*a21-a01*a22)*id), i02=(float)((a01*a12-a02*a11)*id);
  float i10=(float)((a12*a20-a10*a22)*id), i11=(float)((a00*a22-a02*a20)*id), i12=(float)((a02*a10-a00*a12)*id);
  float i20=(float)((a10*a21-a11*a20)*id), i21=(float)((a01*a20-a00*a21)*id), i22=(float)((a00*a11-a01*a10)*id);
  float c0 = i00*px + i01*py + i02;
  float c1 = i10*px + i11*py + i12;
  float c2 = i20*px + i21*py + i22;
  float X0 = d*c0, X1 = d*c1, X2 = d*c2;
  const float* P = poses + bimg*16;
  Xw[0] = (P[0]*X0 + P[1]*X1 + P[2]*X2)  + P[3];
  Xw[1] = (P[4]*X0 + P[5]*X1 + P[6]*X2)  + P[7];
  Xw[2] = (P[8]*X0 + P[9]*X1 + P[10]*X2) + P[11];
  *dout = d;
}

static __device__ void project_to(const float* __restrict__ poses, const float* __restrict__ Km,
                                  int j, const float* Xw, float dsrc,
                                  float* pnx, float* pny, bool* invis) {
  const float* P = poses + j*16;
  float d0 = Xw[0]-P[3], d1 = Xw[1]-P[7], d2 = Xw[2]-P[11];
  float Xj0 = P[0]*d0 + P[4]*d1 + P[8]*d2;
  float Xj1 = P[1]*d0 + P[5]*d1 + P[9]*d2;
  float Xj2 = P[2]*d0 + P[6]*d1 + P[10]*d2;
  const float* Kb = Km + j*9;
  float u = Kb[0]*Xj0 + Kb[1]*Xj1 + Kb[2]*Xj2;
  float v = Kb[3]*Xj0 + Kb[4]*Xj1 + Kb[5]*Xj2;
  float z = Kb[6]*Xj0 + Kb[7]*Xj1 + Kb[8]*Xj2;
  float zs = (fabsf(z) < 1e-6f) ? 1e-6f : z;
  float pu = u/zs, pv = v/zs;
  float nx = 2.0f*pu/639.0f - 1.0f;
  float ny = 2.0f*pv/479.0f - 1.0f;
  *pnx = nx; *pny = ny;
  *invis = (z <= 1e-6f) || (fabsf(nx) > 1.0f) || (fabsf(ny) > 1.0f) || (dsrc <= 0.0f);
}

// ---------------- kernels ----------------

// fused gray -> sobel -> GFTT with SEPARABLE gaussian (w[i][j] = G[i]*G[j]).
// 32x32 output tile; gray halo 4; sobel halo 3; H-pass 38x32; V-pass 4 rows/thread.
// Also: blocks (z==0, y==0) re-initialize ovf counters and the -1 list
// (replaces two pathologically slow runtime fill kernels, ~40us each).
__global__ __launch_bounds__(256) void k_gfused(const float* __restrict__ imgs, float* __restrict__ resp,
                                                int* __restrict__ ovf, int* __restrict__ list) {
  __shared__ float smem[6536];
  __shared__ float Gw[7];
  float* sgxy = smem;              // [38][38][2] interleaved gx,gy  (2888 floats)
  float* gray = smem + 2888;       // [40][41]  (dead after sobel)
  float* hxx  = smem + 2888;       // [38][32] aliases gray
  float* hyy  = hxx + 1216;
  float* hxy  = hyy + 1216;
  int bx = blockIdx.x*32, by = blockIdx.y*32, b = blockIdx.z;
  int tid = threadIdx.x;
  if (blockIdx.z == 0 && blockIdx.y == 0) {
    int g = blockIdx.x*256 + tid;                 // 0..5119
    for (int e = g; e < BB*64; e += 20*256) ovf[e] = 0;
    for (int e = g; e < NLIST; e += 20*256) list[e] = -1;
  }
  if (tid < 7) {
    double g[7]; double s = 0.0;
    for (int q = 0; q < 7; q++) { double r = (double)(q-3); g[q] = exp(-(r*r)/2.0); s += g[q]; }
    Gw[tid] = (float)(g[tid]/s);
  }
  const float* ib = imgs + (size_t)b*3*HWSZ;
  for (int e = tid; e < 40*40; e += 256) {
    int ly = e/40, lx = e%40;
    int X = bx - 4 + lx, Y = by - 4 + ly;
    float v = 0.f;
    if (X>=0 && X<WW && Y>=0 && Y<HH) {
      int p = Y*WW + X;
      v = 0.299f*ib[p] + 0.587f*ib[HWSZ+p] + 0.114f*ib[2*HWSZ+p];
    }
    gray[ly*41+lx] = v;
  }
  __syncthreads();
  const float kxw[3][3] = {{-0.125f,0.f,0.125f},{-0.25f,0.f,0.25f},{-0.125f,0.f,0.125f}};
  for (int e = tid; e < 38*38; e += 256) {
    int rr = e/38, c = e%38;
    int X = bx - 3 + c, Y = by - 3 + rr;
    float sx = 0.f, sy = 0.f;
    #pragma unroll
    for (int i = 0; i < 3; i++)
      #pragma unroll
      for (int j = 0; j < 3; j++) {
        float v = gray[(rr+i)*41 + (c+j)];
        sx += kxw[i][j]*v;
        sy += kxw[j][i]*v;
      }
    bool in = (X>=0 && X<WW && Y>=0 && Y<HH);
    sgxy[e*2]   = in ? sx : 0.f;    // conv zero-pad semantics
    sgxy[e*2+1] = in ? sy : 0.f;
  }
  __syncthreads();
  // H-pass (overwrites gray region; gray is dead)
  for (int e = tid; e < 38*32; e += 256) {
    int rr = e >> 5, co = e & 31;
    int base = (rr*38 + co)*2;
    float axx = 0.f, ayy = 0.f, axy = 0.f;
    #pragma unroll
    for (int j = 0; j < 7; j++) {
      float a = sgxy[base + j*2];
      float c = sgxy[base + j*2 + 1];
      float Gj = Gw[j];
      axx += Gj*(a*a); ayy += Gj*(c*c); axy += Gj*(a*c);
    }
    hxx[e] = axx; hyy[e] = ayy; hxy[e] = axy;
  }
  __syncthreads();
  // V-pass: thread (tx, ty) -> col tx, rows ty*4 .. ty*4+3
  int tx = tid & 31, ty = tid >> 5;
  int r0 = ty*4;
  float axx[4] = {0,0,0,0}, ayy[4] = {0,0,0,0}, axy[4] = {0,0,0,0};
  #pragma unroll
  for (int rr = 0; rr < 10; rr++) {
    int r = r0 + rr;
    float vxx = hxx[r*32+tx], vyy = hyy[r*32+tx], vxy = hxy[r*32+tx];
    #pragma unroll
    for (int o = 0; o < 4; o++) {
      int i = rr - o;
      if (i >= 0 && i <= 6) {
        float Gi = Gw[i];
        axx[o] += Gi*vxx; ayy[o] += Gi*vyy; axy[o] += Gi*vxy;
      }
    }
  }
  #pragma unroll
  for (int o = 0; o < 4; o++) {
    float tr = axx[o] + ayy[o];
    float det = axx[o]*ayy[o] - axy[o]*axy[o];
    float disc = fmaxf(tr*tr - 4.0f*det, 0.f);
    int y = by + r0 + o;
    resp[(size_t)b*HWSZ + y*WW + (bx+tx)] = 0.5f*(tr - sqrtf(disc));
  }
}

// fused SEPARABLE 5x5 NMS + per-8x8-block candidate extraction (+ zero scatter target)
__global__ __launch_bounds__(256) void k_nmscand(const float* __restrict__ resp, float* __restrict__ cv,
                          int* __restrict__ ci, float* __restrict__ cvo,
                          int* __restrict__ cio, int* __restrict__ ovf,
                          float* __restrict__ target) {
  __shared__ float s[36*37];
  __shared__ float hm[36*32];
  __shared__ float c32[32*32];
  int bx = blockIdx.x*32, by = blockIdx.y*32, b = blockIdx.z;
  int tid = threadIdx.x;
  const float* r = resp + (size_t)b*HWSZ;
  for (int e = tid; e < 36*36; e += 256) {
    int ly = e/36, lx = e%36;
    int X = bx - 2 + lx, Y = by - 2 + ly;
    s[ly*37+lx] = (X>=0 && X<WW && Y>=0 && Y<HH) ? r[Y*WW+X] : -INFINITY;
  }
  __syncthreads();
  for (int e = tid; e < 36*32; e += 256) {
    int rr = e >> 5, co = e & 31;
    int base = rr*37 + co;
    float m = s[base];
    m = fmaxf(m, s[base+1]); m = fmaxf(m, s[base+2]);
    m = fmaxf(m, s[base+3]); m = fmaxf(m, s[base+4]);
    hm[e] = m;
  }
  __syncthreads();
  for (int e = tid; e < 1024; e += 256) {
    int y = e >> 5, x = e & 31;
    float mp = hm[y*32+x];
    mp = fmaxf(mp, hm[(y+1)*32+x]); mp = fmaxf(mp, hm[(y+2)*32+x]);
    mp = fmaxf(mp, hm[(y+3)*32+x]); mp = fmaxf(mp, hm[(y+4)*32+x]);
    float v = s[(y+2)*37 + (x+2)];
    c32[e] = (v == mp) ? v : 0.f;
    target[(size_t)b*HWSZ + (by+y)*WW + (bx+x)] = 0.f;
  }
  __syncthreads();
  int wv = tid >> 6, lane = tid & 63;
  int ly8 = lane >> 3, lx8 = lane & 7;
  for (int q = 0; q < 4; q++) {
    int bb = wv*4 + q;
    int oy = (bb >> 2)*8, ox = (bb & 3)*8;
    float cval = c32[(oy+ly8)*32 + ox+lx8];
    float bm = wredmaxf(cval);
    bool win = (cval > 0.f) && (cval == bm);
    unsigned long long mask = __ballot(win);
    int BY = blockIdx.y*4 + (bb >> 2), BX = blockIdx.x*4 + (bb & 3);
    int rblk = BY*80 + BX;
    int gidx = (by+oy+ly8)*WW + (bx+ox+lx8);
    if (mask == 0ull) {
      if (lane == 0) { cv[b*NBLK+rblk] = 0.f; ci[b*NBLK+rblk] = 0; }
    } else if (win) {
      int rank = __popcll(mask & ((1ull << lane) - 1ull));
      if (rank == 0) { cv[b*NBLK+rblk] = cval; ci[b*NBLK+rblk] = gidx; }
      else {
        int pos = atomicAdd(&ovf[b*64], 1);
        if (pos < NOVF) { cvo[b*NOVF+pos] = cval; cio[b*NOVF+pos] = gidx; }
      }
    }
  }
}

// top-500 selection via MSB-first radix select on 64-bit keys
// key = (float_bits << 32) | ~idx  -> top-k order == (value desc, idx asc).
// Overflow slots beyond the per-image count are masked to the empty key (stale-safe).
__global__ __launch_bounds__(1024) void k_topsel(const float* __restrict__ cv, const int* __restrict__ ci,
                                                 const float* __restrict__ cvo, const int* __restrict__ cio,
                                                 const int* __restrict__ ovf,
                                                 float* __restrict__ topv, int* __restrict__ topi) {
  __shared__ unsigned int hist[256];
  __shared__ unsigned int ss[257];
  __shared__ unsigned long long prefix_s;
  __shared__ int kk_s, cgt_s, ceq_s;
  int b = blockIdx.x;
  int nval = min(ovf[b*64], NOVF);
  unsigned long long kreg[8];
  #pragma unroll
  for (int q = 0; q < 8; q++) {
    int e = threadIdx.x + q*1024;
    float v = 0.f; unsigned int idx = 0u;
    if (e < NBLK) { v = cv[b*NBLK+e]; idx = (unsigned int)ci[b*NBLK+e]; }
    else if (e - NBLK < nval) { v = cvo[b*NOVF+e-NBLK]; idx = (unsigned int)cio[b*NOVF+e-NBLK]; }
    kreg[q] = ((unsigned long long)__float_as_uint(v) << 32) | (0xFFFFFFFFu - idx);
  }
  if (threadIdx.x == 0) { prefix_s = 0ull; kk_s = NN; ss[256] = 0u; }
  __syncthreads();
  for (int round = 0; round < 8; round++) {
    int shift = 56 - 8*round;
    if (threadIdx.x < 256) hist[threadIdx.x] = 0u;
    __syncthreads();
    unsigned long long prefix = prefix_s;
    int kk = kk_s;
    unsigned long long himask = (round == 0) ? 0ull : (~0ull << (shift + 8));
    #pragma unroll
    for (int q = 0; q < 8; q++) {
      if ((kreg[q] & himask) == prefix) {
        unsigned int d = (unsigned int)((kreg[q] >> shift) & 255ull);
        atomicAdd(&hist[d], 1u);
      }
    }
    __syncthreads();
    if (threadIdx.x < 256) ss[threadIdx.x] = hist[threadIdx.x];
    __syncthreads();
    for (int off = 1; off < 256; off <<= 1) {
      unsigned int nv = 0u;
      if (threadIdx.x < 256)
        nv = ss[threadIdx.x] + ((threadIdx.x + off < 256) ? ss[threadIdx.x + off] : 0u);
      __syncthreads();
      if (threadIdx.x < 256) ss[threadIdx.x] = nv;
      __syncthreads();
    }
    if (threadIdx.x < 256) {
      int S = (int)ss[threadIdx.x];
      int Sn = (int)ss[threadIdx.x + 1];
      if (S >= kk && Sn < kk) {
        prefix_s = prefix | ((unsigned long long)threadIdx.x << shift);
        kk_s = kk - Sn;
      }
    }
    __syncthreads();
  }
  unsigned long long T = prefix_s;
  int kk = kk_s;
  if (threadIdx.x == 0) { cgt_s = 0; ceq_s = 0; }
  __syncthreads();
  #pragma unroll
  for (int q = 0; q < 8; q++) {
    unsigned long long key = kreg[q];
    int slot = -1;
    if (key > T) slot = atomicAdd(&cgt_s, 1);
    else if (key == T) {
      int p = atomicAdd(&ceq_s, 1);
      if (p < kk) slot = (NN-1) - p;
    }
    if (slot >= 0) {
      topv[b*NN+slot] = __uint_as_float((unsigned int)(key >> 32));
      topi[b*NN+slot] = (int)(0xFFFFFFFFu - (unsigned int)(key & 0xFFFFFFFFull));
    }
  }
}

// fused source-point compute + 8-way projection scatter.
// First writer of each target pixel (atomicMax old==0) records the pixel at a
// DETERMINISTIC slot t*BB+j in the -1-initialized list (exactly once per pixel).
__global__ void k_scatfuse(const float* __restrict__ topv, const int* __restrict__ topi,
                           const float* __restrict__ depths, const float* __restrict__ poses,
                           const float* __restrict__ Km, unsigned int* __restrict__ target,
                           int* __restrict__ list) {
  int t = blockIdx.x*256 + threadIdx.x;
  if (t >= BB*NN) return;
  int i = t / NN;
  float val = topv[t];
  if (val <= 0.f) return;
  int idx = topi[t];
  float xs = (float)(idx % WW), ys = (float)(idx / WW);
  float cx = 2.0f*xs/639.0f - 1.0f;
  float cy = 2.0f*ys/479.0f - 1.0f;
  float px = (cx + 1.0f)*0.5f*639.0f;
  float py = (cy + 1.0f)*0.5f*479.0f;
  float Xw[3], d;
  src_compute(px, py, depths + (size_t)i*HWSZ, poses, Km, i, Xw, &d);
  for (int j = 0; j < BB; j++) {
    float nx, ny; bool inv;
    project_to(poses, Km, j, Xw, d, &nx, &ny, &inv);
    if (inv) { nx = -2.0f; ny = -2.0f; }
    float fx = rintf((nx + 1.0f)*0.5f*639.0f);
    float fy = rintf((ny + 1.0f)*0.5f*479.0f);
    int wq = (int)fx, hq = (int)fy;
    if (wq < 0) continue;
    int hc = min(max(hq, 0), HH-1), wc = min(max(wq, 0), WW-1);
    int p = j*HWSZ + hc*WW + wc;
    unsigned int old = atomicMax(&target[p], __float_as_uint(val));
    if (old == 0u) list[t*BB + j] = p;   // first writer -> exactly once per pixel
  }
}

// streaming BCE over all pixels assuming t=false: sum of -max(log(1-p),-100)
__global__ void k_bce_stream(const float* __restrict__ pn, double* __restrict__ pd) {
  int idx = blockIdx.x*256 + threadIdx.x;
  double l = 0.0;
  for (int q = idx; q < BHW/4; q += NBCE*256) {
    float4 v = ((const float4*)pn)[q];
    l -= (double)fmaxf(logf(1.f - v.x), -100.f);
    l -= (double)fmaxf(logf(1.f - v.y), -100.f);
    l -= (double)fmaxf(logf(1.f - v.z), -100.f);
    l -= (double)fmaxf(logf(1.f - v.w), -100.f);
  }
  double s = blockRedSum256(l);
  if (threadIdx.x == 0) pd[PD_BCE + blockIdx.x] = s;
}

// correction at scattered pixels: t can only be true where target>0 (v>0 required),
// i.e. exactly the listed pixels. Evaluate 5x5 max there; if t, swap the BCE term.
__global__ void k_bcecorr(const int* __restrict__ list, const float* __restrict__ target,
                          const float* __restrict__ pn, double* __restrict__ pd) {
  int idx = blockIdx.x*256 + threadIdx.x;
  double l = 0.0;
  if (idx < NLIST) {
    int p = list[idx];
    if (p >= 0) {
      int j = p / HWSZ, pix = p % HWSZ;
      int y = pix / WW, x = pix % WW;
      const float* tb = target + (size_t)j*HWSZ;
      float v = tb[pix];
      float mp = -INFINITY;
      for (int dy = -2; dy <= 2; dy++) {
        int yy = y + dy; if (yy < 0 || yy >= HH) continue;
        for (int dx = -2; dx <= 2; dx++) {
          int xx = x + dx; if (xx < 0 || xx >= WW) continue;
          mp = fmaxf(mp, tb[yy*WW+xx]);
        }
      }
      if (v > 0.f && v == mp) {
        float pv = pn[p];
        l = (double)(-fmaxf(logf(pv), -100.f)) + (double)fmaxf(logf(1.f - pv), -100.f);
      }
    }
  }
  double s = blockRedSum256(l);
  if (threadIdx.x == 0) pd[PD_CORR + blockIdx.x] = s;
}

__global__ void k_dn(const float* __restrict__ desc, float* __restrict__ dn) {
  int row = blockIdx.x;
  int d = threadIdx.x;
  float v = desc[(size_t)row*DDIM + d];
  __shared__ float sp[4];
  __shared__ float den_s;
  float s = v*v;
  #pragma unroll
  for (int o = 32; o > 0; o >>= 1) s += __shfl_down(s, o, 64);
  int lane = threadIdx.x & 63, wid = threadIdx.x >> 6;
  if (lane == 0) sp[wid] = s;
  __syncthreads();
  if (threadIdx.x == 0) den_s = fmaxf(sqrtf(sp[0]+sp[1]+sp[2]+sp[3]), 1e-8f);
  __syncthreads();
  dn[(size_t)row*DDIM + d] = v / den_s;
}

// fused match source compute + 8-way projection
__global__ void k_msrcdst(const float* __restrict__ points, const float* __restrict__ depths,
                          const float* __restrict__ poses, const float* __restrict__ Km,
                          float* __restrict__ psrc, float* __restrict__ pdst, int* __restrict__ minv) {
  int t = blockIdx.x*256 + threadIdx.x;
  if (t >= BB*NN) return;
  int a = t / NN, m = t % NN;
  float p0 = points[t*2], p1 = points[t*2+1];
  float px = (p0 + 1.0f)*0.5f*639.0f;
  float py = (p1 + 1.0f)*0.5f*479.0f;
  float Xw[3], d;
  src_compute(px, py, depths + (size_t)a*HWSZ, poses, Km, a, Xw, &d);
  psrc[t*2] = px; psrc[t*2+1] = py;
  for (int b = 0; b < BB; b++) {
    float nx, ny; bool inv;
    project_to(poses, Km, b, Xw, d, &nx, &ny, &inv);
    int o = (a*BB + b)*NN + m;
    pdst[o*2]   = (nx + 1.0f)*0.5f*639.0f;
    pdst[o*2+1] = (ny + 1.0f)*0.5f*479.0f;
    minv[o] = inv ? 1 : 0;
  }
}

// match: grid (BB*BB, MSPLIT); partial sums, no global atomics
__global__ void k_match(const float* __restrict__ psrc, const float* __restrict__ pdst,
                        const int* __restrict__ minv, const float* __restrict__ dn,
                        double* __restrict__ pd) {
  __shared__ float spd[2*NN], ssrc[2*NN];
  __shared__ int sinv[NN];
  int ab = blockIdx.x; int b = ab % BB; int a = ab / BB;
  int mm0 = blockIdx.y * MCH;
  int mmN = min(NN, mm0 + MCH);
  for (int e = threadIdx.x; e < NN; e += 256) {
    spd[e*2]   = pdst[(ab*NN+e)*2];
    spd[e*2+1] = pdst[(ab*NN+e)*2+1];
    sinv[e]    = minv[ab*NN+e];
    ssrc[e*2]   = psrc[(b*NN+e)*2];
    ssrc[e*2+1] = psrc[(b*NN+e)*2+1];
  }
  __syncthreads();
  double lsum = 0.0, lcnt = 0.0;
  int npairs = (mmN - mm0) * NN;
  for (int idx = threadIdx.x; idx < npairs; idx += 256) {
    int mm = mm0 + idx / NN;
    int nn = idx % NN;
    if (nn >= mm) continue;          // n < m
    if (sinv[nn]) continue;          // reference quirk: invis indexed by n
    float dx = ssrc[nn*2]   - spd[mm*2];
    float dy = ssrc[nn*2+1] - spd[mm*2+1];
    if (dx*dx + dy*dy <= 1.0f) {
      const float* da = dn + ((size_t)a*NN + mm)*DDIM;
      const float* db = dn + ((size_t)b*NN + nn)*DDIM;
      float dot = 0.f;
      for (int q = 0; q < DDIM; q++) dot += db[q]*da[q];
      lsum += (double)(1.0f - dot);
      lcnt += 1.0;
    }
  }
  int slot = blockIdx.y*64 + blockIdx.x;
  double s = blockRedSum256(lsum);
  if (threadIdx.x == 0) pd[PD_MS + slot] = s;
  double c2 = blockRedSum256(lcnt);
  if (threadIdx.x == 0) pd[PD_MC + slot] = c2;
}

// distinction: register-tiled 64x64 f32 GEMM tiles on dn * dn^T (symmetric:
// lower-triangle tiles x2). Partial sums, no global atomics.
__global__ __launch_bounds__(256) void k_dist(const float* __restrict__ dn, double* __restrict__ pd) {
  int slot = blockIdx.z*64 + blockIdx.y*8 + blockIdx.x;
  if (blockIdx.x > blockIdx.y) { if (threadIdx.x == 0) pd[PD_DIST + slot] = 0.0; return; }
  __shared__ float As[64][36];
  __shared__ float Bs[64][36];
  int b = blockIdx.z;
  int r0 = blockIdx.y*64, c0 = blockIdx.x*64;
  const float* base = dn + (size_t)b*NN*DDIM;
  float accf[4][4];
  #pragma unroll
  for (int i = 0; i < 4; i++)
    #pragma unroll
    for (int j = 0; j < 4; j++) accf[i][j] = 0.f;
  int tx = threadIdx.x & 15, ty = threadIdx.x >> 4;
  for (int kc = 0; kc < DDIM; kc += 32) {
    __syncthreads();
    #pragma unroll
    for (int l = 0; l < 2; l++) {
      int q = threadIdx.x + l*256;
      int row = q >> 3, kq = q & 7;
      int gr = r0 + row;
      float4 va = make_float4(0.f,0.f,0.f,0.f);
      if (gr < NN) va = *(const float4*)&base[(size_t)gr*DDIM + kc + kq*4];
      *(float4*)&As[row][kq*4] = va;
      int gc = c0 + row;
      float4 vb = make_float4(0.f,0.f,0.f,0.f);
      if (gc < NN) vb = *(const float4*)&base[(size_t)gc*DDIM + kc + kq*4];
      *(float4*)&Bs[row][kq*4] = vb;
    }
    __syncthreads();
    #pragma unroll
    for (int kk = 0; kk < 32; kk += 4) {
      float4 a4[4], b4[4];
      #pragma unroll
      for (int i = 0; i < 4; i++) a4[i] = *(const float4*)&As[ty*4+i][kk];
      #pragma unroll
      for (int j = 0; j < 4; j++) b4[j] = *(const float4*)&Bs[tx*4+j][kk];
      #pragma unroll
      for (int i = 0; i < 4; i++)
        #pragma unroll
        for (int j = 0; j < 4; j++)
          accf[i][j] += a4[i].x*b4[j].x + a4[i].y*b4[j].y + a4[i].z*b4[j].z + a4[i].w*b4[j].w;
    }
  }
  double wgt = (blockIdx.x == blockIdx.y) ? 1.0 : 2.0;
  double lsum = 0.0;
  #pragma unroll
  for (int i = 0; i < 4; i++)
    #pragma unroll
    for (int j = 0; j < 4; j++)
      lsum += (double)fmaxf(accf[i][j], 0.f);
  lsum *= wgt;
  double s = blockRedSum256(lsum);
  if (threadIdx.x == 0) pd[PD_DIST + slot] = s;
}

__global__ void k_final(const double* __restrict__ pd, float* __restrict__ out) {
  int tid = threadIdx.x;
  double l;
  l = 0.0; for (int i = tid; i < 512;  i += 256) l += pd[PD_DIST + i];
  double dist = blockRedSum256(l);
  l = 0.0; for (int i = tid; i < 512;  i += 256) l += pd[PD_MS + i];
  double ms = blockRedSum256(l);
  l = 0.0; for (int i = tid; i < 512;  i += 256) l += pd[PD_MC + i];
  double mc = blockRedSum256(l);
  l = 0.0; for (int i = tid; i < NBCE; i += 256) l += pd[PD_BCE + i];
  double bce = blockRedSum256(l);
  l = 0.0; for (int i = tid; i < NCORR; i += 256) l += pd[PD_CORR + i];
  double corr = blockRedSum256(l);
  if (tid == 0) {
    float distf = (float)(dist / (double)(BB*NN*NN));
    float cornf = (float)((bce + corr) / (double)BHW);
    float cntf  = fmaxf((float)mc, 1.0f);
    float matchf = (float)ms / cntf;
    out[0] = distf + cornf + matchf;
  }
}

// ---------------- host ----------------

extern "C" void kernel_launch(void* const* d_in, const int* in_sizes, int n_in,
                              void* d_out, int out_size, void* d_ws, size_t ws_size,
                              hipStream_t stream) {
  (void)in_sizes; (void)n_in; (void)out_size; (void)ws_size;
  const float* desc      = (const float*)d_in[0];
  const float* points    = (const float*)d_in[1];
  const float* pointness = (const float*)d_in[2];
  const float* depths    = (const float*)d_in[3];
  const float* poses     = (const float*)d_in[4];
  const float* Kmat      = (const float*)d_in[5];
  const float* imgs      = (const float*)d_in[6];
  float* out = (float*)d_out;

  double* pd = (double*)d_ws;                      // partial sums first (8B aligned)
  float* f = (float*)(pd + PD_TOTAL);
  float* bufA = f;                                 // resp
  float* bufC = bufA + (size_t)BHW;                // scatter target
  float* cv_main = bufC + (size_t)BHW;             // 8 x 4800
  int*   ci_main = (int*)(cv_main + BB*NBLK);
  float* cv_ovf  = (float*)(ci_main + BB*NBLK);    // 8 x 3392 (stale-safe: count-masked)
  int*   ci_ovf  = (int*)(cv_ovf + BB*NOVF);
  int*   ovf     = (int*)(ci_ovf + BB*NOVF);       // 8 x stride-64 counters (init in k_gfused)
  float* topv = (float*)(ovf + BB*64);
  int*   topi = (int*)(topv + BB*NN);
  float* psrc = (float*)(topi + BB*NN);
  float* pdst = psrc + BB*NN*2;
  int*   minv = (int*)(pdst + BB*BB*NN*2);
  float* dn   = (float*)(minv + BB*BB*NN);         // 8*500*256 floats
  int*   list = (int*)(dn + (size_t)BB*NN*DDIM);   // 32000 ints (init in k_gfused)

  dim3 tgrid(WW/32, HH/32, BB);                    // 20 x 15 x 8

  k_gfused <<<tgrid, 256, 0, stream>>>(imgs, bufA, ovf, list);
  k_nmscand<<<tgrid, 256, 0, stream>>>(bufA, cv_main, ci_main, cv_ovf, ci_ovf, ovf, bufC);
  k_topsel <<<BB, 1024, 0, stream>>>(cv_main, ci_main, cv_ovf, ci_ovf, ovf, topv, topi);
  k_scatfuse<<<(BB*NN + 255)/256, 256, 0, stream>>>(topv, topi, depths, poses, Kmat,
                                                    (unsigned int*)bufC, list);
  k_bce_stream<<<NBCE, 256, 0, stream>>>(pointness, pd);
  k_bcecorr<<<NCORR, 256, 0, stream>>>(list, bufC, pointness, pd);
  k_dn    <<<BB*NN, DDIM, 0, stream>>>(desc, dn);
  k_msrcdst<<<(BB*NN + 255)/256, 256, 0, stream>>>(points, depths, poses, Kmat, psrc, pdst, minv);
  k_match <<<dim3(BB*BB, MSPLIT), 256, 0, stream>>>(psrc, pdst, minv, dn, pd);
  k_dist  <<<dim3(8, 8, BB), 256, 0, stream>>>(dn, pd);
  k_final <<<1, 256, 0, stream>>>(pd, out);
}

// Round 8
// 141.175 us; speedup vs baseline: 7.2116x; 1.1235x over previous
//
#include <hip/hip_runtime.h>
#include <math.h>

#define BB 8
#define NN 500
#define DDIM 256
#define HH 480
#define WW 640
#define HWSZ (HH*WW)        // 307200
#define BHW (BB*HWSZ)       // 2457600
#define NBLK 4800           // 8x8 blocks per image
#define NOVF 3392           // overflow candidate slots per image
#define NLIST (BB*NN*BB)    // 32000 deterministic list slots
#define NBCE2 512           // bce streaming blocks (inside k_misc)
#define NCORR 125           // ceil(32000/256)

// partial-sum slot map (doubles at ws start)
#define PD_DIST  0          // 288 used
#define PD_MS    512        // 512
#define PD_MC    1024       // 512
#define PD_BCE   1536       // 512
#define PD_CORR  2560       // 125
#define PD_TOTAL 2688

// ---------------- helpers ----------------

static __device__ __forceinline__ float wredmaxf(float v) {
  #pragma unroll
  for (int o = 1; o < 64; o <<= 1) v = fmaxf(v, __shfl_xor(v, o, 64));
  return v;
}

static __device__ __forceinline__ double blockRedSum256(double v) {
  __shared__ double sp[4];
  __syncthreads();
  #pragma unroll
  for (int o = 32; o > 0; o >>= 1) v += __shfl_down(v, o, 64);
  int lane = threadIdx.x & 63, wid = threadIdx.x >> 6;
  if (lane == 0) sp[wid] = v;
  __syncthreads();
  double r = 0.0;
  if (threadIdx.x == 0) r = sp[0] + sp[1] + sp[2] + sp[3];
  return r;
}

static __device__ __forceinline__ float bilin(const float* __restrict__ img, float px, float py) {
  float x = fminf(fmaxf(px, 0.0f), 639.0f);
  float y = fminf(fmaxf(py, 0.0f), 479.0f);
  float x0 = floorf(x), y0 = floorf(y);
  float x1 = fminf(x0 + 1.0f, 639.0f);
  float y1 = fminf(y0 + 1.0f, 479.0f);
  float wx = x - x0, wy = y - y0;
  int x0i = (int)x0, x1i = (int)x1, y0i = (int)y0, y1i = (int)y1;
  float v00 = img[y0i*WW + x0i], v01 = img[y0i*WW + x1i];
  float v10 = img[y1i*WW + x0i], v11 = img[y1i*WW + x1i];
  return v00*(1.0f-wx)*(1.0f-wy) + v01*wx*(1.0f-wy) + v10*(1.0f-wx)*wy + v11*wx*wy;
}

// world point from pixel (px,py) in image bimg; replicates reference op order
static __device__ void src_compute(float px, float py, const float* __restrict__ dep,
                                   const float* __restrict__ poses, const float* __restrict__ Km,
                                   int bimg, float* Xw, float* dout) {
  float d = bilin(dep, px, py);
  const float* Kb = Km + bimg*9;
  double a00=Kb[0],a01=Kb[1],a02=Kb[2],a10=Kb[3],a11=Kb[4],a12=Kb[5],a20=Kb[6],a21=Kb[7],a22=Kb[8];
  double det = a00*(a11*a22-a12*a21) - a01*(a10*a22-a12*a20) + a02*(a10*a21-a11*a20);
  double id = 1.0/det;
  float i00=(float)((a11*a22-a12*a21)*id), i01=(float)((a02*a21-a01*a22)*id), i02=(float)((a01*a12-a02*a11)*id);
  float i10=(float)((a12*a20-a10*a22)*id), i11=(float)((a00*a22-a02*a20)*id), i12=(float)((a02*a10-a00*a12)*id);
  float i20=(float)((a10*a21-a11*a20)*id), i21=(float)((a01*a20-a00*a21)*id), i22=(float)((a00*a11-a01*a10)*id);
  float c0 = i00*px + i01*py + i02;
  float c1 = i10*px + i11*py + i12;
  float c2 = i20*px + i21*py + i22;
  float X0 = d*c0, X1 = d*c1, X2 = d*c2;
  const float* P = poses + bimg*16;
  Xw[0] = (P[0]*X0 + P[1]*X1 + P[2]*X2)  + P[3];
  Xw[1] = (P[4]*X0 + P[5]*X1 + P[6]*X2)  + P[7];
  Xw[2] = (P[8]*X0 + P[9]*X1 + P[10]*X2) + P[11];
  *dout = d;
}

static __device__ void project_to(const float* __restrict__ poses, const float* __restrict__ Km,
                                  int j, const float* Xw, float dsrc,
                                  float* pnx, float* pny, bool* invis) {
  const float* P = poses + j*16;
  float d0 = Xw[0]-P[3], d1 = Xw[1]-P[7], d2 = Xw[2]-P[11];
  float Xj0 = P[0]*d0 + P[4]*d1 + P[8]*d2;
  float Xj1 = P[1]*d0 + P[5]*d1 + P[9]*d2;
  float Xj2 = P[2]*d0 + P[6]*d1 + P[10]*d2;
  const float* Kb = Km + j*9;
  float u = Kb[0]*Xj0 + Kb[1]*Xj1 + Kb[2]*Xj2;
  float v = Kb[3]*Xj0 + Kb[4]*Xj1 + Kb[5]*Xj2;
  float z = Kb[6]*Xj0 + Kb[7]*Xj1 + Kb[8]*Xj2;
  float zs = (fabsf(z) < 1e-6f) ? 1e-6f : z;
  float pu = u/zs, pv = v/zs;
  float nx = 2.0f*pu/639.0f - 1.0f;
  float ny = 2.0f*pv/479.0f - 1.0f;
  *pnx = nx; *pny = ny;
  *invis = (z <= 1e-6f) || (fabsf(nx) > 1.0f) || (fabsf(ny) > 1.0f) || (dsrc <= 0.0f);
}

// ---------------- kernels ----------------

// fused gray -> sobel -> GFTT with SEPARABLE gaussian; also inits ovf + list.
__global__ __launch_bounds__(256) void k_gfused(const float* __restrict__ imgs, float* __restrict__ resp,
                                                int* __restrict__ ovf, int* __restrict__ list) {
  __shared__ float smem[6536];
  __shared__ float Gw[7];
  float* sgxy = smem;              // [38][38][2] interleaved gx,gy
  float* gray = smem + 2888;       // [40][41]  (dead after sobel)
  float* hxx  = smem + 2888;       // [38][32] aliases gray
  float* hyy  = hxx + 1216;
  float* hxy  = hyy + 1216;
  int bx = blockIdx.x*32, by = blockIdx.y*32, b = blockIdx.z;
  int tid = threadIdx.x;
  if (blockIdx.z == 0 && blockIdx.y == 0) {
    int g = blockIdx.x*256 + tid;                 // 0..5119
    for (int e = g; e < BB*64; e += 20*256) ovf[e] = 0;
    for (int e = g; e < NLIST; e += 20*256) list[e] = -1;
  }
  if (tid < 7) {
    double g[7]; double s = 0.0;
    for (int q = 0; q < 7; q++) { double r = (double)(q-3); g[q] = exp(-(r*r)/2.0); s += g[q]; }
    Gw[tid] = (float)(g[tid]/s);
  }
  const float* ib = imgs + (size_t)b*3*HWSZ;
  for (int e = tid; e < 40*40; e += 256) {
    int ly = e/40, lx = e%40;
    int X = bx - 4 + lx, Y = by - 4 + ly;
    float v = 0.f;
    if (X>=0 && X<WW && Y>=0 && Y<HH) {
      int p = Y*WW + X;
      v = 0.299f*ib[p] + 0.587f*ib[HWSZ+p] + 0.114f*ib[2*HWSZ+p];
    }
    gray[ly*41+lx] = v;
  }
  __syncthreads();
  const float kxw[3][3] = {{-0.125f,0.f,0.125f},{-0.25f,0.f,0.25f},{-0.125f,0.f,0.125f}};
  for (int e = tid; e < 38*38; e += 256) {
    int rr = e/38, c = e%38;
    int X = bx - 3 + c, Y = by - 3 + rr;
    float sx = 0.f, sy = 0.f;
    #pragma unroll
    for (int i = 0; i < 3; i++)
      #pragma unroll
      for (int j = 0; j < 3; j++) {
        float v = gray[(rr+i)*41 + (c+j)];
        sx += kxw[i][j]*v;
        sy += kxw[j][i]*v;
      }
    bool in = (X>=0 && X<WW && Y>=0 && Y<HH);
    sgxy[e*2]   = in ? sx : 0.f;    // conv zero-pad semantics
    sgxy[e*2+1] = in ? sy : 0.f;
  }
  __syncthreads();
  for (int e = tid; e < 38*32; e += 256) {
    int rr = e >> 5, co = e & 31;
    int base = (rr*38 + co)*2;
    float axx = 0.f, ayy = 0.f, axy = 0.f;
    #pragma unroll
    for (int j = 0; j < 7; j++) {
      float a = sgxy[base + j*2];
      float c = sgxy[base + j*2 + 1];
      float Gj = Gw[j];
      axx += Gj*(a*a); ayy += Gj*(c*c); axy += Gj*(a*c);
    }
    hxx[e] = axx; hyy[e] = ayy; hxy[e] = axy;
  }
  __syncthreads();
  int tx = tid & 31, ty = tid >> 5;
  int r0 = ty*4;
  float axx[4] = {0,0,0,0}, ayy[4] = {0,0,0,0}, axy[4] = {0,0,0,0};
  #pragma unroll
  for (int rr = 0; rr < 10; rr++) {
    int r = r0 + rr;
    float vxx = hxx[r*32+tx], vyy = hyy[r*32+tx], vxy = hxy[r*32+tx];
    #pragma unroll
    for (int o = 0; o < 4; o++) {
      int i = rr - o;
      if (i >= 0 && i <= 6) {
        float Gi = Gw[i];
        axx[o] += Gi*vxx; ayy[o] += Gi*vyy; axy[o] += Gi*vxy;
      }
    }
  }
  #pragma unroll
  for (int o = 0; o < 4; o++) {
    float tr = axx[o] + ayy[o];
    float det = axx[o]*ayy[o] - axy[o]*axy[o];
    float disc = fmaxf(tr*tr - 4.0f*det, 0.f);
    int y = by + r0 + o;
    resp[(size_t)b*HWSZ + y*WW + (bx+tx)] = 0.5f*(tr - sqrtf(disc));
  }
}

// fused SEPARABLE 5x5 NMS + per-8x8-block candidate extraction (+ zero scatter target)
__global__ __launch_bounds__(256) void k_nmscand(const float* __restrict__ resp, float* __restrict__ cv,
                          int* __restrict__ ci, float* __restrict__ cvo,
                          int* __restrict__ cio, int* __restrict__ ovf,
                          float* __restrict__ target) {
  __shared__ float s[36*37];
  __shared__ float hm[36*32];
  __shared__ float c32[32*32];
  int bx = blockIdx.x*32, by = blockIdx.y*32, b = blockIdx.z;
  int tid = threadIdx.x;
  const float* r = resp + (size_t)b*HWSZ;
  for (int e = tid; e < 36*36; e += 256) {
    int ly = e/36, lx = e%36;
    int X = bx - 2 + lx, Y = by - 2 + ly;
    s[ly*37+lx] = (X>=0 && X<WW && Y>=0 && Y<HH) ? r[Y*WW+X] : -INFINITY;
  }
  __syncthreads();
  for (int e = tid; e < 36*32; e += 256) {
    int rr = e >> 5, co = e & 31;
    int base = rr*37 + co;
    float m = s[base];
    m = fmaxf(m, s[base+1]); m = fmaxf(m, s[base+2]);
    m = fmaxf(m, s[base+3]); m = fmaxf(m, s[base+4]);
    hm[e] = m;
  }
  __syncthreads();
  for (int e = tid; e < 1024; e += 256) {
    int y = e >> 5, x = e & 31;
    float mp = hm[y*32+x];
    mp = fmaxf(mp, hm[(y+1)*32+x]); mp = fmaxf(mp, hm[(y+2)*32+x]);
    mp = fmaxf(mp, hm[(y+3)*32+x]); mp = fmaxf(mp, hm[(y+4)*32+x]);
    float v = s[(y+2)*37 + (x+2)];
    c32[e] = (v == mp) ? v : 0.f;
    target[(size_t)b*HWSZ + (by+y)*WW + (bx+x)] = 0.f;
  }
  __syncthreads();
  int wv = tid >> 6, lane = tid & 63;
  int ly8 = lane >> 3, lx8 = lane & 7;
  for (int q = 0; q < 4; q++) {
    int bb = wv*4 + q;
    int oy = (bb >> 2)*8, ox = (bb & 3)*8;
    float cval = c32[(oy+ly8)*32 + ox+lx8];
    float bm = wredmaxf(cval);
    bool win = (cval > 0.f) && (cval == bm);
    unsigned long long mask = __ballot(win);
    int BY = blockIdx.y*4 + (bb >> 2), BX = blockIdx.x*4 + (bb & 3);
    int rblk = BY*80 + BX;
    int gidx = (by+oy+ly8)*WW + (bx+ox+lx8);
    if (mask == 0ull) {
      if (lane == 0) { cv[b*NBLK+rblk] = 0.f; ci[b*NBLK+rblk] = 0; }
    } else if (win) {
      int rank = __popcll(mask & ((1ull << lane) - 1ull));
      if (rank == 0) { cv[b*NBLK+rblk] = cval; ci[b*NBLK+rblk] = gidx; }
      else {
        int pos = atomicAdd(&ovf[b*64], 1);
        if (pos < NOVF) { cvo[b*NOVF+pos] = cval; cio[b*NOVF+pos] = gidx; }
      }
    }
  }
}

// top-500 radix select (wave-synchronous scan, early exit) + fused projection
// scatter of the selected corners. Top-500 kept entirely in LDS.
// key = (float_bits << 32) | ~idx  -> top-k order == (value desc, idx asc).
__global__ __launch_bounds__(1024) void k_topscat(const float* __restrict__ cv, const int* __restrict__ ci,
                                                  const float* __restrict__ cvo, const int* __restrict__ cio,
                                                  const int* __restrict__ ovf,
                                                  const float* __restrict__ depths, const float* __restrict__ poses,
                                                  const float* __restrict__ Km,
                                                  unsigned int* __restrict__ target, int* __restrict__ list) {
  __shared__ unsigned int hist[256];
  __shared__ unsigned long long prefix_s;
  __shared__ int kk_s, fin_s, cgt_s, ceq_s;
  __shared__ float s_topv[NN];
  __shared__ int s_topi[NN];
  int b = blockIdx.x;
  int tid = threadIdx.x;
  int nval = min(ovf[b*64], NOVF);
  unsigned long long kreg[8];
  #pragma unroll
  for (int q = 0; q < 8; q++) {
    int e = tid + q*1024;
    float v = 0.f; unsigned int idx = 0u;
    if (e < NBLK) { v = cv[b*NBLK+e]; idx = (unsigned int)ci[b*NBLK+e]; }
    else if (e - NBLK < nval) { v = cvo[b*NOVF+e-NBLK]; idx = (unsigned int)cio[b*NOVF+e-NBLK]; }
    kreg[q] = ((unsigned long long)__float_as_uint(v) << 32) | (0xFFFFFFFFu - idx);
  }
  if (tid == 0) { prefix_s = 0ull; kk_s = NN; fin_s = -1; cgt_s = 0; ceq_s = 0; }
  if (tid < 256) hist[tid] = 0u;
  __syncthreads();
  for (int round = 0; round < 8; round++) {
    int shift = 56 - 8*round;
    unsigned long long prefix = prefix_s;
    int kk = kk_s;
    unsigned long long himask = (round == 0) ? 0ull : (~0ull << (shift + 8));
    #pragma unroll
    for (int q = 0; q < 8; q++)
      if ((kreg[q] & himask) == prefix)
        atomicAdd(&hist[(unsigned int)((kreg[q] >> shift) & 255ull)], 1u);
    __syncthreads();
    if (tid < 64) {
      int l = tid;
      unsigned s0 = hist[l], s1 = hist[64+l], s2 = hist[128+l], s3 = hist[192+l];
      #pragma unroll
      for (int off = 1; off < 64; off <<= 1) {
        unsigned t0 = __shfl_down(s0, off, 64), t1 = __shfl_down(s1, off, 64);
        unsigned t2 = __shfl_down(s2, off, 64), t3 = __shfl_down(s3, off, 64);
        if (l + off < 64) { s0 += t0; s1 += t1; s2 += t2; s3 += t3; }
      }
      unsigned S1 = __shfl(s1, 0, 64), S2 = __shfl(s2, 0, 64), S3 = __shfl(s3, 0, 64);
      unsigned suf0 = s0 + S1 + S2 + S3, suf1 = s1 + S2 + S3, suf2 = s2 + S3, suf3 = s3;
      int best = -1;
      if      (suf3 >= (unsigned)kk) best = 192 + l;
      else if (suf2 >= (unsigned)kk) best = 128 + l;
      else if (suf1 >= (unsigned)kk) best = 64 + l;
      else if (suf0 >= (unsigned)kk) best = l;
      #pragma unroll
      for (int off = 1; off < 64; off <<= 1) best = max(best, __shfl_xor(best, off, 64));
      if (l == (best & 63)) {
        int seg = best >> 6;
        unsigned sufb = (seg == 3) ? suf3 : ((seg == 2) ? suf2 : ((seg == 1) ? suf1 : suf0));
        unsigned c = hist[best];
        int Sn = (int)(sufb - c);
        int kkn = kk - Sn;
        prefix_s = prefix | ((unsigned long long)best << shift);
        kk_s = kkn;
        if (kkn == (int)c) fin_s = shift;
      }
      hist[l] = 0u; hist[64+l] = 0u; hist[128+l] = 0u; hist[192+l] = 0u;
    }
    __syncthreads();
    if (fin_s >= 0) break;
  }
  int sg = (fin_s > 0) ? fin_s : 0;
  unsigned long long prefix = prefix_s;
  int kk = kk_s;
  unsigned long long low = (sg > 0) ? ((1ull << sg) - 1ull) : 0ull;
  unsigned long long Tfull = prefix | low;
  unsigned long long mhi = ~low;
  #pragma unroll
  for (int q = 0; q < 8; q++) {
    unsigned long long key = kreg[q];
    int slot = -1;
    if (key > Tfull) slot = atomicAdd(&cgt_s, 1);
    else if ((key & mhi) == prefix) {
      int p = atomicAdd(&ceq_s, 1);
      if (p < kk) slot = (NN-1) - p;
    }
    if (slot >= 0) {
      s_topv[slot] = __uint_as_float((unsigned int)(key >> 32));
      s_topi[slot] = (int)(0xFFFFFFFFu - (unsigned int)(key & 0xFFFFFFFFull));
    }
  }
  __syncthreads();
  // ---- fused scatter: this block owns image b; 500 threads project its corners
  if (tid < NN) {
    float val = s_topv[tid];
    if (val > 0.f) {
      int idx = s_topi[tid];
      float xs = (float)(idx % WW), ys = (float)(idx / WW);
      float cx = 2.0f*xs/639.0f - 1.0f;
      float cy = 2.0f*ys/479.0f - 1.0f;
      float px = (cx + 1.0f)*0.5f*639.0f;
      float py = (cy + 1.0f)*0.5f*479.0f;
      float Xw[3], d;
      src_compute(px, py, depths + (size_t)b*HWSZ, poses, Km, b, Xw, &d);
      int tglob = b*NN + tid;
      for (int j = 0; j < BB; j++) {
        float nx, ny; bool inv;
        project_to(poses, Km, j, Xw, d, &nx, &ny, &inv);
        if (inv) { nx = -2.0f; ny = -2.0f; }
        float fx = rintf((nx + 1.0f)*0.5f*639.0f);
        float fy = rintf((ny + 1.0f)*0.5f*479.0f);
        int wq = (int)fx, hq = (int)fy;
        if (wq < 0) continue;
        int hc = min(max(hq, 0), HH-1), wc = min(max(wq, 0), WW-1);
        int p = j*HWSZ + hc*WW + wc;
        unsigned int old = atomicMax(&target[p], __float_as_uint(val));
        if (old == 0u) list[tglob*BB + j] = p;   // first writer, exactly once per pixel
      }
    }
  }
}

// fused independent mid-stage work, partitioned by block range:
// [0,4000): desc normalize; [4000,4016): match src+projections;
// [4016,4528): streaming BCE (t=false); [4528,4653): BCE correction at scattered px.
__global__ __launch_bounds__(256) void k_misc(const float* __restrict__ desc, float* __restrict__ dn,
                                              const float* __restrict__ points, const float* __restrict__ depths,
                                              const float* __restrict__ poses, const float* __restrict__ Km,
                                              float* __restrict__ psrc, float* __restrict__ pdst, int* __restrict__ minv,
                                              const float* __restrict__ pn, const int* __restrict__ list,
                                              const float* __restrict__ target, double* __restrict__ pd) {
  int bid = blockIdx.x, tid = threadIdx.x;
  if (bid < 4000) {
    int row = bid;
    float v = desc[(size_t)row*DDIM + tid];
    __shared__ float sp2[4];
    __shared__ float den_s;
    float s = v*v;
    #pragma unroll
    for (int o = 32; o > 0; o >>= 1) s += __shfl_down(s, o, 64);
    int lane = tid & 63, wid = tid >> 6;
    if (lane == 0) sp2[wid] = s;
    __syncthreads();
    if (tid == 0) den_s = fmaxf(sqrtf(sp2[0]+sp2[1]+sp2[2]+sp2[3]), 1e-8f);
    __syncthreads();
    dn[(size_t)row*DDIM + tid] = v / den_s;
  } else if (bid < 4016) {
    int t = (bid - 4000)*256 + tid;
    if (t < BB*NN) {
      int a = t / NN, m = t % NN;
      float p0 = points[t*2], p1 = points[t*2+1];
      float px = (p0 + 1.0f)*0.5f*639.0f;
      float py = (p1 + 1.0f)*0.5f*479.0f;
      float Xw[3], d;
      src_compute(px, py, depths + (size_t)a*HWSZ, poses, Km, a, Xw, &d);
      psrc[t*2] = px; psrc[t*2+1] = py;
      for (int b = 0; b < BB; b++) {
        float nx, ny; bool inv;
        project_to(poses, Km, b, Xw, d, &nx, &ny, &inv);
        int o = (a*BB + b)*NN + m;
        pdst[o*2]   = (nx + 1.0f)*0.5f*639.0f;   // raw projections (reference match path)
        pdst[o*2+1] = (ny + 1.0f)*0.5f*479.0f;
        minv[o] = inv ? 1 : 0;
      }
    }
  } else if (bid < 4016 + NBCE2) {
    int blk = bid - 4016;
    int g = blk*256 + tid;
    double l = 0.0;
    for (int q = g; q < BHW/4; q += NBCE2*256) {
      float4 v = ((const float4*)pn)[q];
      l -= (double)fmaxf(logf(1.f - v.x), -100.f);
      l -= (double)fmaxf(logf(1.f - v.y), -100.f);
      l -= (double)fmaxf(logf(1.f - v.z), -100.f);
      l -= (double)fmaxf(logf(1.f - v.w), -100.f);
    }
    double s = blockRedSum256(l);
    if (tid == 0) pd[PD_BCE + blk] = s;
  } else {
    int blk = bid - (4016 + NBCE2);
    int g = blk*256 + tid;
    double l = 0.0;
    if (g < NLIST) {
      int p = list[g];
      if (p >= 0) {
        int j = p / HWSZ, pix = p % HWSZ;
        int y = pix / WW, x = pix % WW;
        const float* tb = target + (size_t)j*HWSZ;
        float v = tb[pix];
        float mp = -INFINITY;
        for (int dy = -2; dy <= 2; dy++) {
          int yy = y + dy; if (yy < 0 || yy >= HH) continue;
          for (int dx = -2; dx <= 2; dx++) {
            int xx = x + dx; if (xx < 0 || xx >= WW) continue;
            mp = fmaxf(mp, tb[yy*WW+xx]);
          }
        }
        if (v > 0.f && v == mp) {
          float pv = pn[p];
          l = (double)(-fmaxf(logf(pv), -100.f)) + (double)fmaxf(logf(1.f - pv), -100.f);
        }
      }
    }
    double s = blockRedSum256(l);
    if (tid == 0) pd[PD_CORR + blk] = s;
  }
}

// fused tail: [0,512) match slices; [512,800) distinction GEMM tiles.
__global__ __launch_bounds__(256) void k_tail(const float* __restrict__ psrc, const float* __restrict__ pdst,
                                              const int* __restrict__ minv, const float* __restrict__ dn,
                                              double* __restrict__ pd) {
  __shared__ float sbuf[4608];
  int bid = blockIdx.x, tid = threadIdx.x;
  if (bid < 512) {
    float* spd = sbuf;                 // 1000
    float* ssrc = sbuf + 1000;         // 1000
    int* sinv = (int*)(sbuf + 2000);   // 500
    int ab = bid & 63; int b = ab % BB; int a = ab / BB;
    int mm0 = (bid >> 6) * 63;
    int mmN = min(NN, mm0 + 63);
    for (int e = tid; e < NN; e += 256) {
      spd[e*2]   = pdst[(ab*NN+e)*2];
      spd[e*2+1] = pdst[(ab*NN+e)*2+1];
      sinv[e]    = minv[ab*NN+e];
      ssrc[e*2]   = psrc[(b*NN+e)*2];
      ssrc[e*2+1] = psrc[(b*NN+e)*2+1];
    }
    __syncthreads();
    double lsum = 0.0, lcnt = 0.0;
    int npairs = (mmN - mm0) * NN;
    for (int idx = tid; idx < npairs; idx += 256) {
      int mm = mm0 + idx / NN;
      int nn = idx % NN;
      if (nn >= mm) continue;          // n < m
      if (sinv[nn]) continue;          // reference quirk: invis indexed by n
      float dx = ssrc[nn*2]   - spd[mm*2];
      float dy = ssrc[nn*2+1] - spd[mm*2+1];
      if (dx*dx + dy*dy <= 1.0f) {
        const float* da = dn + ((size_t)a*NN + mm)*DDIM;
        const float* db = dn + ((size_t)b*NN + nn)*DDIM;
        float dot = 0.f;
        for (int q = 0; q < DDIM; q++) dot += db[q]*da[q];
        lsum += (double)(1.0f - dot);
        lcnt += 1.0;
      }
    }
    double s = blockRedSum256(lsum);
    if (tid == 0) pd[PD_MS + bid] = s;
    double c2 = blockRedSum256(lcnt);
    if (tid == 0) pd[PD_MC + bid] = c2;
  } else {
    int t = bid - 512;                 // 0..287
    int b = t / 36, rem = t % 36;
    int yb = 0, xb = 0;
    for (int yy = 0; yy < 8; yy++) { if (rem < yy+1) { yb = yy; xb = rem; break; } rem -= yy+1; }
    float (*As)[36] = (float(*)[36])sbuf;
    float (*Bs)[36] = (float(*)[36])(sbuf + 2304);
    int r0 = yb*64, c0 = xb*64;
    const float* base = dn + (size_t)b*NN*DDIM;
    float accf[4][4];
    #pragma unroll
    for (int i = 0; i < 4; i++)
      #pragma unroll
      for (int j = 0; j < 4; j++) accf[i][j] = 0.f;
    int tx = tid & 15, ty = tid >> 4;
    for (int kc = 0; kc < DDIM; kc += 32) {
      __syncthreads();
      #pragma unroll
      for (int l = 0; l < 2; l++) {
        int q = tid + l*256;
        int row = q >> 3, kq = q & 7;
        int gr = r0 + row;
        float4 va = make_float4(0.f,0.f,0.f,0.f);
        if (gr < NN) va = *(const float4*)&base[(size_t)gr*DDIM + kc + kq*4];
        *(float4*)&As[row][kq*4] = va;
        int gc = c0 + row;
        float4 vb = make_float4(0.f,0.f,0.f,0.f);
        if (gc < NN) vb = *(const float4*)&base[(size_t)gc*DDIM + kc + kq*4];
        *(float4*)&Bs[row][kq*4] = vb;
      }
      __syncthreads();
      #pragma unroll
      for (int kk = 0; kk < 32; kk += 4) {
        float4 a4[4], b4[4];
        #pragma unroll
        for (int i = 0; i < 4; i++) a4[i] = *(const float4*)&As[ty*4+i][kk];
        #pragma unroll
        for (int j = 0; j < 4; j++) b4[j] = *(const float4*)&Bs[tx*4+j][kk];
        #pragma unroll
        for (int i = 0; i < 4; i++)
          #pragma unroll
          for (int j = 0; j < 4; j++)
            accf[i][j] += a4[i].x*b4[j].x + a4[i].y*b4[j].y + a4[i].z*b4[j].z + a4[i].w*b4[j].w;
      }
    }
    double wgt = (xb == yb) ? 1.0 : 2.0;
    double lsum = 0.0;
    #pragma unroll
    for (int i = 0; i < 4; i++)
      #pragma unroll
      for (int j = 0; j < 4; j++)
        lsum += (double)fmaxf(accf[i][j], 0.f);
    lsum *= wgt;
    double s = blockRedSum256(lsum);
    if (tid == 0) pd[PD_DIST + t] = s;
  }
}

__global__ void k_final(const double* __restrict__ pd, float* __restrict__ out) {
  int tid = threadIdx.x;
  double l;
  l = 0.0; for (int i = tid; i < 288;   i += 256) l += pd[PD_DIST + i];
  double dist = blockRedSum256(l);
  l = 0.0; for (int i = tid; i < 512;   i += 256) l += pd[PD_MS + i];
  double ms = blockRedSum256(l);
  l = 0.0; for (int i = tid; i < 512;   i += 256) l += pd[PD_MC + i];
  double mc = blockRedSum256(l);
  l = 0.0; for (int i = tid; i < NBCE2; i += 256) l += pd[PD_BCE + i];
  double bce = blockRedSum256(l);
  l = 0.0; for (int i = tid; i < NCORR; i += 256) l += pd[PD_CORR + i];
  double corr = blockRedSum256(l);
  if (tid == 0) {
    float distf = (float)(dist / (double)(BB*NN*NN));
    float cornf = (float)((bce + corr) / (double)BHW);
    float cntf  = fmaxf((float)mc, 1.0f);
    float matchf = (float)ms / cntf;
    out[0] = distf + cornf + matchf;
  }
}

// ---------------- host ----------------

extern "C" void kernel_launch(void* const* d_in, const int* in_sizes, int n_in,
                              void* d_out, int out_size, void* d_ws, size_t ws_size,
                              hipStream_t stream) {
  (void)in_sizes; (void)n_in; (void)out_size; (void)ws_size;
  const float* desc      = (const float*)d_in[0];
  const float* points    = (const float*)d_in[1];
  const float* pointness = (const float*)d_in[2];
  const float* depths    = (const float*)d_in[3];
  const float* poses     = (const float*)d_in[4];
  const float* Kmat      = (const float*)d_in[5];
  const float* imgs      = (const float*)d_in[6];
  float* out = (float*)d_out;

  double* pd = (double*)d_ws;                      // partial sums first (8B aligned)
  float* f = (float*)(pd + PD_TOTAL);
  float* bufA = f;                                 // resp
  float* bufC = bufA + (size_t)BHW;                // scatter target
  float* cv_main = bufC + (size_t)BHW;             // 8 x 4800
  int*   ci_main = (int*)(cv_main + BB*NBLK);
  float* cv_ovf  = (float*)(ci_main + BB*NBLK);    // 8 x 3392 (stale-safe: count-masked)
  int*   ci_ovf  = (int*)(cv_ovf + BB*NOVF);
  int*   ovf     = (int*)(ci_ovf + BB*NOVF);       // 8 x stride-64 counters (init in k_gfused)
  float* psrc = (float*)(ovf + BB*64);
  float* pdst = psrc + BB*NN*2;
  int*   minv = (int*)(pdst + BB*BB*NN*2);
  float* dn   = (float*)(minv + BB*BB*NN);         // 8*500*256 floats
  int*   list = (int*)(dn + (size_t)BB*NN*DDIM);   // 32000 ints (init in k_gfused)

  dim3 tgrid(WW/32, HH/32, BB);                    // 20 x 15 x 8

  k_gfused <<<tgrid, 256, 0, stream>>>(imgs, bufA, ovf, list);
  k_nmscand<<<tgrid, 256, 0, stream>>>(bufA, cv_main, ci_main, cv_ovf, ci_ovf, ovf, bufC);
  k_topscat<<<BB, 1024, 0, stream>>>(cv_main, ci_main, cv_ovf, ci_ovf, ovf,
                                     depths, poses, Kmat, (unsigned int*)bufC, list);
  k_misc   <<<4016 + NBCE2 + NCORR, 256, 0, stream>>>(desc, dn, points, depths, poses, Kmat,
                                                      psrc, pdst, minv, pointness, list, bufC, pd);
  k_tail   <<<512 + 288, 256, 0, stream>>>(psrc, pdst, minv, dn, pd);
  k_final  <<<1, 256, 0, stream>>>(pd, out);
}

// Round 9
// 137.458 us; speedup vs baseline: 7.4066x; 1.0270x over previous
//
#include <hip/hip_runtime.h>
#include <math.h>

#define BB 8
#define NN 500
#define DDIM 256
#define HH 480
#define WW 640
#define HWSZ (HH*WW)        // 307200
#define BHW (BB*HWSZ)       // 2457600
#define NBLK 4800           // 8x8 blocks per image
#define NOVF 3392           // overflow candidate slots per image
#define NLIST (BB*NN*BB)    // 32000 deterministic list slots
#define NBCE2 512           // bce streaming blocks (inside k_misc)
#define NCORR 125           // ceil(32000/256)
#define NDIST 288           // 8 images x 36 lower-tri 64x64 tiles

// partial-sum slot map (doubles at ws start)
#define PD_DIST  0          // 288 used
#define PD_MS    512        // 512
#define PD_MC    1024       // 512
#define PD_BCE   1536       // 512
#define PD_CORR  2560       // 125
#define PD_TOTAL 2688

// ---------------- helpers ----------------

static __device__ __forceinline__ float wredmaxf(float v) {
  #pragma unroll
  for (int o = 1; o < 64; o <<= 1) v = fmaxf(v, __shfl_xor(v, o, 64));
  return v;
}

static __device__ __forceinline__ double blockRedSum256(double v) {
  __shared__ double sp[4];
  __syncthreads();
  #pragma unroll
  for (int o = 32; o > 0; o >>= 1) v += __shfl_down(v, o, 64);
  int lane = threadIdx.x & 63, wid = threadIdx.x >> 6;
  if (lane == 0) sp[wid] = v;
  __syncthreads();
  double r = 0.0;
  if (threadIdx.x == 0) r = sp[0] + sp[1] + sp[2] + sp[3];
  return r;
}

static __device__ __forceinline__ float bilin(const float* __restrict__ img, float px, float py) {
  float x = fminf(fmaxf(px, 0.0f), 639.0f);
  float y = fminf(fmaxf(py, 0.0f), 479.0f);
  float x0 = floorf(x), y0 = floorf(y);
  float x1 = fminf(x0 + 1.0f, 639.0f);
  float y1 = fminf(y0 + 1.0f, 479.0f);
  float wx = x - x0, wy = y - y0;
  int x0i = (int)x0, x1i = (int)x1, y0i = (int)y0, y1i = (int)y1;
  float v00 = img[y0i*WW + x0i], v01 = img[y0i*WW + x1i];
  float v10 = img[y1i*WW + x0i], v11 = img[y1i*WW + x1i];
  return v00*(1.0f-wx)*(1.0f-wy) + v01*wx*(1.0f-wy) + v10*(1.0f-wx)*wy + v11*wx*wy;
}

// world point from pixel (px,py) in image bimg; replicates reference op order
static __device__ void src_compute(float px, float py, const float* __restrict__ dep,
                                   const float* __restrict__ poses, const float* __restrict__ Km,
                                   int bimg, float* Xw, float* dout) {
  float d = bilin(dep, px, py);
  const float* Kb = Km + bimg*9;
  double a00=Kb[0],a01=Kb[1],a02=Kb[2],a10=Kb[3],a11=Kb[4],a12=Kb[5],a20=Kb[6],a21=Kb[7],a22=Kb[8];
  double det = a00*(a11*a22-a12*a21) - a01*(a10*a22-a12*a20) + a02*(a10*a21-a11*a20);
  double id = 1.0/det;
  float i00=(float)((a11*a22-a12*a21)*id), i01=(float)((a02*a21-a01*a22)*id), i02=(float)((a01*a12-a02*a11)*id);
  float i10=(float)((a12*a20-a10*a22)*id), i11=(float)((a00*a22-a02*a20)*id), i12=(float)((a02*a10-a00*a12)*id);
  float i20=(float)((a10*a21-a11*a20)*id), i21=(float)((a01*a20-a00*a21)*id), i22=(float)((a00*a11-a01*a10)*id);
  float c0 = i00*px + i01*py + i02;
  float c1 = i10*px + i11*py + i12;
  float c2 = i20*px + i21*py + i22;
  float X0 = d*c0, X1 = d*c1, X2 = d*c2;
  const float* P = poses + bimg*16;
  Xw[0] = (P[0]*X0 + P[1]*X1 + P[2]*X2)  + P[3];
  Xw[1] = (P[4]*X0 + P[5]*X1 + P[6]*X2)  + P[7];
  Xw[2] = (P[8]*X0 + P[9]*X1 + P[10]*X2) + P[11];
  *dout = d;
}

static __device__ void project_to(const float* __restrict__ poses, const float* __restrict__ Km,
                                  int j, const float* Xw, float dsrc,
                                  float* pnx, float* pny, bool* invis) {
  const float* P = poses + j*16;
  float d0 = Xw[0]-P[3], d1 = Xw[1]-P[7], d2 = Xw[2]-P[11];
  float Xj0 = P[0]*d0 + P[4]*d1 + P[8]*d2;
  float Xj1 = P[1]*d0 + P[5]*d1 + P[9]*d2;
  float Xj2 = P[2]*d0 + P[6]*d1 + P[10]*d2;
  const float* Kb = Km + j*9;
  float u = Kb[0]*Xj0 + Kb[1]*Xj1 + Kb[2]*Xj2;
  float v = Kb[3]*Xj0 + Kb[4]*Xj1 + Kb[5]*Xj2;
  float z = Kb[6]*Xj0 + Kb[7]*Xj1 + Kb[8]*Xj2;
  float zs = (fabsf(z) < 1e-6f) ? 1e-6f : z;
  float pu = u/zs, pv = v/zs;
  float nx = 2.0f*pu/639.0f - 1.0f;
  float ny = 2.0f*pv/479.0f - 1.0f;
  *pnx = nx; *pny = ny;
  *invis = (z <= 1e-6f) || (fabsf(nx) > 1.0f) || (fabsf(ny) > 1.0f) || (dsrc <= 0.0f);
}

// ---------------- kernels ----------------

// fused gray -> sobel -> GFTT with SEPARABLE gaussian; also inits ovf + list.
__global__ __launch_bounds__(256) void k_gfused(const float* __restrict__ imgs, float* __restrict__ resp,
                                                int* __restrict__ ovf, int* __restrict__ list) {
  __shared__ float smem[6536];
  __shared__ float Gw[7];
  float* sgxy = smem;              // [38][38][2] interleaved gx,gy
  float* gray = smem + 2888;       // [40][41]  (dead after sobel)
  float* hxx  = smem + 2888;       // [38][32] aliases gray
  float* hyy  = hxx + 1216;
  float* hxy  = hyy + 1216;
  int bx = blockIdx.x*32, by = blockIdx.y*32, b = blockIdx.z;
  int tid = threadIdx.x;
  if (blockIdx.z == 0 && blockIdx.y == 0) {
    int g = blockIdx.x*256 + tid;                 // 0..5119
    for (int e = g; e < BB*64; e += 20*256) ovf[e] = 0;
    for (int e = g; e < NLIST; e += 20*256) list[e] = -1;
  }
  if (tid < 7) {
    double g[7]; double s = 0.0;
    for (int q = 0; q < 7; q++) { double r = (double)(q-3); g[q] = exp(-(r*r)/2.0); s += g[q]; }
    Gw[tid] = (float)(g[tid]/s);
  }
  const float* ib = imgs + (size_t)b*3*HWSZ;
  for (int e = tid; e < 40*40; e += 256) {
    int ly = e/40, lx = e%40;
    int X = bx - 4 + lx, Y = by - 4 + ly;
    float v = 0.f;
    if (X>=0 && X<WW && Y>=0 && Y<HH) {
      int p = Y*WW + X;
      v = 0.299f*ib[p] + 0.587f*ib[HWSZ+p] + 0.114f*ib[2*HWSZ+p];
    }
    gray[ly*41+lx] = v;
  }
  __syncthreads();
  const float kxw[3][3] = {{-0.125f,0.f,0.125f},{-0.25f,0.f,0.25f},{-0.125f,0.f,0.125f}};
  for (int e = tid; e < 38*38; e += 256) {
    int rr = e/38, c = e%38;
    int X = bx - 3 + c, Y = by - 3 + rr;
    float sx = 0.f, sy = 0.f;
    #pragma unroll
    for (int i = 0; i < 3; i++)
      #pragma unroll
      for (int j = 0; j < 3; j++) {
        float v = gray[(rr+i)*41 + (c+j)];
        sx += kxw[i][j]*v;
        sy += kxw[j][i]*v;
      }
    bool in = (X>=0 && X<WW && Y>=0 && Y<HH);
    sgxy[e*2]   = in ? sx : 0.f;    // conv zero-pad semantics
    sgxy[e*2+1] = in ? sy : 0.f;
  }
  __syncthreads();
  for (int e = tid; e < 38*32; e += 256) {
    int rr = e >> 5, co = e & 31;
    int base = (rr*38 + co)*2;
    float axx = 0.f, ayy = 0.f, axy = 0.f;
    #pragma unroll
    for (int j = 0; j < 7; j++) {
      float a = sgxy[base + j*2];
      float c = sgxy[base + j*2 + 1];
      float Gj = Gw[j];
      axx += Gj*(a*a); ayy += Gj*(c*c); axy += Gj*(a*c);
    }
    hxx[e] = axx; hyy[e] = ayy; hxy[e] = axy;
  }
  __syncthreads();
  int tx = tid & 31, ty = tid >> 5;
  int r0 = ty*4;
  float axx[4] = {0,0,0,0}, ayy[4] = {0,0,0,0}, axy[4] = {0,0,0,0};
  #pragma unroll
  for (int rr = 0; rr < 10; rr++) {
    int r = r0 + rr;
    float vxx = hxx[r*32+tx], vyy = hyy[r*32+tx], vxy = hxy[r*32+tx];
    #pragma unroll
    for (int o = 0; o < 4; o++) {
      int i = rr - o;
      if (i >= 0 && i <= 6) {
        float Gi = Gw[i];
        axx[o] += Gi*vxx; ayy[o] += Gi*vyy; axy[o] += Gi*vxy;
      }
    }
  }
  #pragma unroll
  for (int o = 0; o < 4; o++) {
    float tr = axx[o] + ayy[o];
    float det = axx[o]*ayy[o] - axy[o]*axy[o];
    float disc = fmaxf(tr*tr - 4.0f*det, 0.f);
    int y = by + r0 + o;
    resp[(size_t)b*HWSZ + y*WW + (bx+tx)] = 0.5f*(tr - sqrtf(disc));
  }
}

// fused SEPARABLE 5x5 NMS + per-8x8-block candidate extraction (+ zero scatter target)
__global__ __launch_bounds__(256) void k_nmscand(const float* __restrict__ resp, float* __restrict__ cv,
                          int* __restrict__ ci, float* __restrict__ cvo,
                          int* __restrict__ cio, int* __restrict__ ovf,
                          float* __restrict__ target) {
  __shared__ float s[36*37];
  __shared__ float hm[36*32];
  __shared__ float c32[32*32];
  int bx = blockIdx.x*32, by = blockIdx.y*32, b = blockIdx.z;
  int tid = threadIdx.x;
  const float* r = resp + (size_t)b*HWSZ;
  for (int e = tid; e < 36*36; e += 256) {
    int ly = e/36, lx = e%36;
    int X = bx - 2 + lx, Y = by - 2 + ly;
    s[ly*37+lx] = (X>=0 && X<WW && Y>=0 && Y<HH) ? r[Y*WW+X] : -INFINITY;
  }
  __syncthreads();
  for (int e = tid; e < 36*32; e += 256) {
    int rr = e >> 5, co = e & 31;
    int base = rr*37 + co;
    float m = s[base];
    m = fmaxf(m, s[base+1]); m = fmaxf(m, s[base+2]);
    m = fmaxf(m, s[base+3]); m = fmaxf(m, s[base+4]);
    hm[e] = m;
  }
  __syncthreads();
  for (int e = tid; e < 1024; e += 256) {
    int y = e >> 5, x = e & 31;
    float mp = hm[y*32+x];
    mp = fmaxf(mp, hm[(y+1)*32+x]); mp = fmaxf(mp, hm[(y+2)*32+x]);
    mp = fmaxf(mp, hm[(y+3)*32+x]); mp = fmaxf(mp, hm[(y+4)*32+x]);
    float v = s[(y+2)*37 + (x+2)];
    c32[e] = (v == mp) ? v : 0.f;
    target[(size_t)b*HWSZ + (by+y)*WW + (bx+x)] = 0.f;
  }
  __syncthreads();
  int wv = tid >> 6, lane = tid & 63;
  int ly8 = lane >> 3, lx8 = lane & 7;
  for (int q = 0; q < 4; q++) {
    int bb = wv*4 + q;
    int oy = (bb >> 2)*8, ox = (bb & 3)*8;
    float cval = c32[(oy+ly8)*32 + ox+lx8];
    float bm = wredmaxf(cval);
    bool win = (cval > 0.f) && (cval == bm);
    unsigned long long mask = __ballot(win);
    int BY = blockIdx.y*4 + (bb >> 2), BX = blockIdx.x*4 + (bb & 3);
    int rblk = BY*80 + BX;
    int gidx = (by+oy+ly8)*WW + (bx+ox+lx8);
    if (mask == 0ull) {
      if (lane == 0) { cv[b*NBLK+rblk] = 0.f; ci[b*NBLK+rblk] = 0; }
    } else if (win) {
      int rank = __popcll(mask & ((1ull << lane) - 1ull));
      if (rank == 0) { cv[b*NBLK+rblk] = cval; ci[b*NBLK+rblk] = gidx; }
      else {
        int pos = atomicAdd(&ovf[b*64], 1);
        if (pos < NOVF) { cvo[b*NOVF+pos] = cval; cio[b*NOVF+pos] = gidx; }
      }
    }
  }
}

// top-500 radix select (wave-synchronous scan, early exit) + fused projection
// scatter of the selected corners. Top-500 kept entirely in LDS.
__global__ __launch_bounds__(1024) void k_topscat(const float* __restrict__ cv, const int* __restrict__ ci,
                                                  const float* __restrict__ cvo, const int* __restrict__ cio,
                                                  const int* __restrict__ ovf,
                                                  const float* __restrict__ depths, const float* __restrict__ poses,
                                                  const float* __restrict__ Km,
                                                  unsigned int* __restrict__ target, int* __restrict__ list) {
  __shared__ unsigned int hist[256];
  __shared__ unsigned long long prefix_s;
  __shared__ int kk_s, fin_s, cgt_s, ceq_s;
  __shared__ float s_topv[NN];
  __shared__ int s_topi[NN];
  int b = blockIdx.x;
  int tid = threadIdx.x;
  int nval = min(ovf[b*64], NOVF);
  unsigned long long kreg[8];
  #pragma unroll
  for (int q = 0; q < 8; q++) {
    int e = tid + q*1024;
    float v = 0.f; unsigned int idx = 0u;
    if (e < NBLK) { v = cv[b*NBLK+e]; idx = (unsigned int)ci[b*NBLK+e]; }
    else if (e - NBLK < nval) { v = cvo[b*NOVF+e-NBLK]; idx = (unsigned int)cio[b*NOVF+e-NBLK]; }
    kreg[q] = ((unsigned long long)__float_as_uint(v) << 32) | (0xFFFFFFFFu - idx);
  }
  if (tid == 0) { prefix_s = 0ull; kk_s = NN; fin_s = -1; cgt_s = 0; ceq_s = 0; }
  if (tid < 256) hist[tid] = 0u;
  __syncthreads();
  for (int round = 0; round < 8; round++) {
    int shift = 56 - 8*round;
    unsigned long long prefix = prefix_s;
    int kk = kk_s;
    unsigned long long himask = (round == 0) ? 0ull : (~0ull << (shift + 8));
    #pragma unroll
    for (int q = 0; q < 8; q++)
      if ((kreg[q] & himask) == prefix)
        atomicAdd(&hist[(unsigned int)((kreg[q] >> shift) & 255ull)], 1u);
    __syncthreads();
    if (tid < 64) {
      int l = tid;
      unsigned s0 = hist[l], s1 = hist[64+l], s2 = hist[128+l], s3 = hist[192+l];
      #pragma unroll
      for (int off = 1; off < 64; off <<= 1) {
        unsigned t0 = __shfl_down(s0, off, 64), t1 = __shfl_down(s1, off, 64);
        unsigned t2 = __shfl_down(s2, off, 64), t3 = __shfl_down(s3, off, 64);
        if (l + off < 64) { s0 += t0; s1 += t1; s2 += t2; s3 += t3; }
      }
      unsigned S1 = __shfl(s1, 0, 64), S2 = __shfl(s2, 0, 64), S3 = __shfl(s3, 0, 64);
      unsigned suf0 = s0 + S1 + S2 + S3, suf1 = s1 + S2 + S3, suf2 = s2 + S3, suf3 = s3;
      int best = -1;
      if      (suf3 >= (unsigned)kk) best = 192 + l;
      else if (suf2 >= (unsigned)kk) best = 128 + l;
      else if (suf1 >= (unsigned)kk) best = 64 + l;
      else if (suf0 >= (unsigned)kk) best = l;
      #pragma unroll
      for (int off = 1; off < 64; off <<= 1) best = max(best, __shfl_xor(best, off, 64));
      if (l == (best & 63)) {
        int seg = best >> 6;
        unsigned sufb = (seg == 3) ? suf3 : ((seg == 2) ? suf2 : ((seg == 1) ? suf1 : suf0));
        unsigned c = hist[best];
        int Sn = (int)(sufb - c);
        int kkn = kk - Sn;
        prefix_s = prefix | ((unsigned long long)best << shift);
        kk_s = kkn;
        if (kkn == (int)c) fin_s = shift;
      }
      hist[l] = 0u; hist[64+l] = 0u; hist[128+l] = 0u; hist[192+l] = 0u;
    }
    __syncthreads();
    if (fin_s >= 0) break;
  }
  int sg = (fin_s > 0) ? fin_s : 0;
  unsigned long long prefix = prefix_s;
  int kk = kk_s;
  unsigned long long low = (sg > 0) ? ((1ull << sg) - 1ull) : 0ull;
  unsigned long long Tfull = prefix | low;
  unsigned long long mhi = ~low;
  #pragma unroll
  for (int q = 0; q < 8; q++) {
    unsigned long long key = kreg[q];
    int slot = -1;
    if (key > Tfull) slot = atomicAdd(&cgt_s, 1);
    else if ((key & mhi) == prefix) {
      int p = atomicAdd(&ceq_s, 1);
      if (p < kk) slot = (NN-1) - p;
    }
    if (slot >= 0) {
      s_topv[slot] = __uint_as_float((unsigned int)(key >> 32));
      s_topi[slot] = (int)(0xFFFFFFFFu - (unsigned int)(key & 0xFFFFFFFFull));
    }
  }
  __syncthreads();
  // ---- fused scatter: this block owns image b; 500 threads project its corners
  if (tid < NN) {
    float val = s_topv[tid];
    if (val > 0.f) {
      int idx = s_topi[tid];
      float xs = (float)(idx % WW), ys = (float)(idx / WW);
      float cx = 2.0f*xs/639.0f - 1.0f;
      float cy = 2.0f*ys/479.0f - 1.0f;
      float px = (cx + 1.0f)*0.5f*639.0f;
      float py = (cy + 1.0f)*0.5f*479.0f;
      float Xw[3], d;
      src_compute(px, py, depths + (size_t)b*HWSZ, poses, Km, b, Xw, &d);
      int tglob = b*NN + tid;
      for (int j = 0; j < BB; j++) {
        float nx, ny; bool inv;
        project_to(poses, Km, j, Xw, d, &nx, &ny, &inv);
        if (inv) { nx = -2.0f; ny = -2.0f; }
        float fx = rintf((nx + 1.0f)*0.5f*639.0f);
        float fy = rintf((ny + 1.0f)*0.5f*479.0f);
        int wq = (int)fx, hq = (int)fy;
        if (wq < 0) continue;
        int hc = min(max(hq, 0), HH-1), wc = min(max(wq, 0), WW-1);
        int p = j*HWSZ + hc*WW + wc;
        unsigned int old = atomicMax(&target[p], __float_as_uint(val));
        if (old == 0u) list[tglob*BB + j] = p;   // first writer, exactly once per pixel
      }
    }
  }
}

// fused independent mid-stage work, partitioned by block range.
__global__ __launch_bounds__(256) void k_misc(const float* __restrict__ desc, float* __restrict__ dn,
                                              const float* __restrict__ points, const float* __restrict__ depths,
                                              const float* __restrict__ poses, const float* __restrict__ Km,
                                              float* __restrict__ psrc, float* __restrict__ pdst, int* __restrict__ minv,
                                              const float* __restrict__ pn, const int* __restrict__ list,
                                              const float* __restrict__ target, double* __restrict__ pd) {
  int bid = blockIdx.x, tid = threadIdx.x;
  if (bid < 4000) {
    int row = bid;
    float v = desc[(size_t)row*DDIM + tid];
    __shared__ float sp2[4];
    __shared__ float den_s;
    float s = v*v;
    #pragma unroll
    for (int o = 32; o > 0; o >>= 1) s += __shfl_down(s, o, 64);
    int lane = tid & 63, wid = tid >> 6;
    if (lane == 0) sp2[wid] = s;
    __syncthreads();
    if (tid == 0) den_s = fmaxf(sqrtf(sp2[0]+sp2[1]+sp2[2]+sp2[3]), 1e-8f);
    __syncthreads();
    dn[(size_t)row*DDIM + tid] = v / den_s;
  } else if (bid < 4016) {
    int t = (bid - 4000)*256 + tid;
    if (t < BB*NN) {
      int a = t / NN, m = t % NN;
      float p0 = points[t*2], p1 = points[t*2+1];
      float px = (p0 + 1.0f)*0.5f*639.0f;
      float py = (p1 + 1.0f)*0.5f*479.0f;
      float Xw[3], d;
      src_compute(px, py, depths + (size_t)a*HWSZ, poses, Km, a, Xw, &d);
      psrc[t*2] = px; psrc[t*2+1] = py;
      for (int b = 0; b < BB; b++) {
        float nx, ny; bool inv;
        project_to(poses, Km, b, Xw, d, &nx, &ny, &inv);
        int o = (a*BB + b)*NN + m;
        pdst[o*2]   = (nx + 1.0f)*0.5f*639.0f;   // raw projections (reference match path)
        pdst[o*2+1] = (ny + 1.0f)*0.5f*479.0f;
        minv[o] = inv ? 1 : 0;
      }
    }
  } else if (bid < 4016 + NBCE2) {
    int blk = bid - 4016;
    int g = blk*256 + tid;
    double l = 0.0;
    for (int q = g; q < BHW/4; q += NBCE2*256) {
      float4 v = ((const float4*)pn)[q];
      l -= (double)fmaxf(logf(1.f - v.x), -100.f);
      l -= (double)fmaxf(logf(1.f - v.y), -100.f);
      l -= (double)fmaxf(logf(1.f - v.z), -100.f);
      l -= (double)fmaxf(logf(1.f - v.w), -100.f);
    }
    double s = blockRedSum256(l);
    if (tid == 0) pd[PD_BCE + blk] = s;
  } else {
    int blk = bid - (4016 + NBCE2);
    int g = blk*256 + tid;
    double l = 0.0;
    if (g < NLIST) {
      int p = list[g];
      if (p >= 0) {
        int j = p / HWSZ, pix = p % HWSZ;
        int y = pix / WW, x = pix % WW;
        const float* tb = target + (size_t)j*HWSZ;
        float v = tb[pix];
        float mp = -INFINITY;
        for (int dy = -2; dy <= 2; dy++) {
          int yy = y + dy; if (yy < 0 || yy >= HH) continue;
          for (int dx = -2; dx <= 2; dx++) {
            int xx = x + dx; if (xx < 0 || xx >= WW) continue;
            mp = fmaxf(mp, tb[yy*WW+xx]);
          }
        }
        if (v > 0.f && v == mp) {
          float pv = pn[p];
          l = (double)(-fmaxf(logf(pv), -100.f)) + (double)fmaxf(logf(1.f - pv), -100.f);
        }
      }
    }
    double s = blockRedSum256(l);
    if (tid == 0) pd[PD_CORR + blk] = s;
  }
}

// fused tail: [0,288) distinction GEMM tiles (long blocks first); [288,800) match slices.
__global__ __launch_bounds__(256) void k_tail(const float* __restrict__ psrc, const float* __restrict__ pdst,
                                              const int* __restrict__ minv, const float* __restrict__ dn,
                                              double* __restrict__ pd) {
  __shared__ float sbuf[4608];
  int bid = blockIdx.x, tid = threadIdx.x;
  if (bid < NDIST) {
    // ---- distinction 64x64 tile: conflict-free micro-tile mapping
    int t = bid;
    int b = t / 36, rem = t % 36;
    int yb = 0, xb = 0;
    for (int yy = 0; yy < 8; yy++) { if (rem < yy+1) { yb = yy; xb = rem; break; } rem -= yy+1; }
    float (*As)[36] = (float(*)[36])sbuf;
    float (*Bs)[36] = (float(*)[36])(sbuf + 2304);
    int r0 = yb*64, c0 = xb*64;
    const float* base = dn + (size_t)b*NN*DDIM;
    float accf[4][4];
    #pragma unroll
    for (int i = 0; i < 4; i++)
      #pragma unroll
      for (int j = 0; j < 4; j++) accf[i][j] = 0.f;
    int tx = tid & 15, ty = tid >> 4;
    for (int kc = 0; kc < DDIM; kc += 32) {
      __syncthreads();
      #pragma unroll
      for (int l = 0; l < 2; l++) {
        int q = tid + l*256;
        int row = q >> 3, kq = q & 7;
        int gr = r0 + row;
        float4 va = make_float4(0.f,0.f,0.f,0.f);
        if (gr < NN) va = *(const float4*)&base[(size_t)gr*DDIM + kc + kq*4];
        *(float4*)&As[row][kq*4] = va;
        int gc = c0 + row;
        float4 vb = make_float4(0.f,0.f,0.f,0.f);
        if (gc < NN) vb = *(const float4*)&base[(size_t)gc*DDIM + kc + kq*4];
        *(float4*)&Bs[row][kq*4] = vb;
      }
      __syncthreads();
      #pragma unroll
      for (int kk = 0; kk < 32; kk += 4) {
        float4 a4[4], b4[4];
        // A rows ty*4+i (broadcast across 16 tx-lanes; 2-way bank alias = free)
        #pragma unroll
        for (int i = 0; i < 4; i++) a4[i] = *(const float4*)&As[ty*4+i][kk];
        // B rows tx+16*j: lanes' banks = 4*tx mod 32 -> 8 distinct, 2-way = free
        #pragma unroll
        for (int j = 0; j < 4; j++) b4[j] = *(const float4*)&Bs[tx + 16*j][kk];
        #pragma unroll
        for (int i = 0; i < 4; i++)
          #pragma unroll
          for (int j = 0; j < 4; j++)
            accf[i][j] += a4[i].x*b4[j].x + a4[i].y*b4[j].y + a4[i].z*b4[j].z + a4[i].w*b4[j].w;
      }
    }
    double wgt = (xb == yb) ? 1.0 : 2.0;
    double lsum = 0.0;
    #pragma unroll
    for (int i = 0; i < 4; i++)
      #pragma unroll
      for (int j = 0; j < 4; j++)
        lsum += (double)fmaxf(accf[i][j], 0.f);
    lsum *= wgt;
    double s = blockRedSum256(lsum);
    if (tid == 0) pd[PD_DIST + t] = s;
  } else {
    // ---- match slice: mm strided by 8 (balanced), nn-inner coalesced, no int div
    int mbid = bid - NDIST;            // 0..511
    float* spd = sbuf;                 // 1000
    float* ssrc = sbuf + 1000;         // 1000
    int* sinv = (int*)(sbuf + 2000);   // 500
    int ab = mbid & 63; int b = ab % BB; int a = ab / BB;
    int ys = mbid >> 6;                // 0..7 stripe
    for (int e = tid; e < NN; e += 256) {
      spd[e*2]   = pdst[(ab*NN+e)*2];
      spd[e*2+1] = pdst[(ab*NN+e)*2+1];
      sinv[e]    = minv[ab*NN+e];
      ssrc[e*2]   = psrc[(b*NN+e)*2];
      ssrc[e*2+1] = psrc[(b*NN+e)*2+1];
    }
    __syncthreads();
    double lsum = 0.0, lcnt = 0.0;
    for (int mm = ys; mm < NN; mm += 8) {
      float px = spd[mm*2], py = spd[mm*2+1];
      for (int nn = tid; nn < mm; nn += 256) {
        if (sinv[nn]) continue;        // reference quirk: invis indexed by n
        float dx = ssrc[nn*2]   - px;
        float dy = ssrc[nn*2+1] - py;
        if (dx*dx + dy*dy <= 1.0f) {
          const float* da = dn + ((size_t)a*NN + mm)*DDIM;
          const float* db = dn + ((size_t)b*NN + nn)*DDIM;
          float dot = 0.f;
          for (int q = 0; q < DDIM; q++) dot += db[q]*da[q];
          lsum += (double)(1.0f - dot);
          lcnt += 1.0;
        }
      }
    }
    double s = blockRedSum256(lsum);
    if (tid == 0) pd[PD_MS + mbid] = s;
    double c2 = blockRedSum256(lcnt);
    if (tid == 0) pd[PD_MC + mbid] = c2;
  }
}

__global__ void k_final(const double* __restrict__ pd, float* __restrict__ out) {
  int tid = threadIdx.x;
  double l;
  l = 0.0; for (int i = tid; i < NDIST; i += 256) l += pd[PD_DIST + i];
  double dist = blockRedSum256(l);
  l = 0.0; for (int i = tid; i < 512;   i += 256) l += pd[PD_MS + i];
  double ms = blockRedSum256(l);
  l = 0.0; for (int i = tid; i < 512;   i += 256) l += pd[PD_MC + i];
  double mc = blockRedSum256(l);
  l = 0.0; for (int i = tid; i < NBCE2; i += 256) l += pd[PD_BCE + i];
  double bce = blockRedSum256(l);
  l = 0.0; for (int i = tid; i < NCORR; i += 256) l += pd[PD_CORR + i];
  double corr = blockRedSum256(l);
  if (tid == 0) {
    float distf = (float)(dist / (double)(BB*NN*NN));
    float cornf = (float)((bce + corr) / (double)BHW);
    float cntf  = fmaxf((float)mc, 1.0f);
    float matchf = (float)ms / cntf;
    out[0] = distf + cornf + matchf;
  }
}

// ---------------- host ----------------

extern "C" void kernel_launch(void* const* d_in, const int* in_sizes, int n_in,
                              void* d_out, int out_size, void* d_ws, size_t ws_size,
                              hipStream_t stream) {
  (void)in_sizes; (void)n_in; (void)out_size; (void)ws_size;
  const float* desc      = (const float*)d_in[0];
  const float* points    = (const float*)d_in[1];
  const float* pointness = (const float*)d_in[2];
  const float* depths    = (const float*)d_in[3];
  const float* poses     = (const float*)d_in[4];
  const float* Kmat      = (const float*)d_in[5];
  const float* imgs      = (const float*)d_in[6];
  float* out = (float*)d_out;

  double* pd = (double*)d_ws;                      // partial sums first (8B aligned)
  float* f = (float*)(pd + PD_TOTAL);
  float* bufA = f;                                 // resp
  float* bufC = bufA + (size_t)BHW;                // scatter target
  float* cv_main = bufC + (size_t)BHW;             // 8 x 4800
  int*   ci_main = (int*)(cv_main + BB*NBLK);
  float* cv_ovf  = (float*)(ci_main + BB*NBLK);    // 8 x 3392 (stale-safe: count-masked)
  int*   ci_ovf  = (int*)(cv_ovf + BB*NOVF);
  int*   ovf     = (int*)(ci_ovf + BB*NOVF);       // 8 x stride-64 counters (init in k_gfused)
  float* psrc = (float*)(ovf + BB*64);
  float* pdst = psrc + BB*NN*2;
  int*   minv = (int*)(pdst + BB*BB*NN*2);
  float* dn   = (float*)(minv + BB*BB*NN);         // 8*500*256 floats
  int*   list = (int*)(dn + (size_t)BB*NN*DDIM);   // 32000 ints (init in k_gfused)

  dim3 tgrid(WW/32, HH/32, BB);                    // 20 x 15 x 8

  k_gfused <<<tgrid, 256, 0, stream>>>(imgs, bufA, ovf, list);
  k_nmscand<<<tgrid, 256, 0, stream>>>(bufA, cv_main, ci_main, cv_ovf, ci_ovf, ovf, bufC);
  k_topscat<<<BB, 1024, 0, stream>>>(cv_main, ci_main, cv_ovf, ci_ovf, ovf,
                                     depths, poses, Kmat, (unsigned int*)bufC, list);
  k_misc   <<<4016 + NBCE2 + NCORR, 256, 0, stream>>>(desc, dn, points, depths, poses, Kmat,
                                                      psrc, pdst, minv, pointness, list, bufC, pd);
  k_tail   <<<NDIST + 512, 256, 0, stream>>>(psrc, pdst, minv, dn, pd);
  k_final  <<<1, 256, 0, stream>>>(pd, out);
}

// Round 10
// 124.712 us; speedup vs baseline: 8.1636x; 1.1022x over previous
//
#include <hip/hip_runtime.h>
#include <math.h>

#define BB 8
#define NN 500
#define DDIM 256
#define HH 480
#define WW 640
#define HWSZ (HH*WW)        // 307200
#define BHW (BB*HWSZ)       // 2457600
#define NBLK 4800           // 8x8 blocks per image
#define NOVF 3392           // overflow candidate slots per image
#define NLIST (BB*NN*BB)    // 32000 deterministic list slots
#define NBCE2 512           // bce streaming blocks (inside k_misc)
#define NCORR 125           // ceil(32000/256)
#define NDM 66              // dist-mfma blocks: 66*4 waves * 16 jobs = 4224 = 8*528 tiles

// partial-sum slot map (doubles at ws start)
#define PD_DIST  0          // 66 used
#define PD_MS    512        // 512
#define PD_MC    1024       // 512
#define PD_BCE   1536       // 512
#define PD_CORR  2560       // 125
#define PD_TOTAL 2688

typedef __attribute__((ext_vector_type(8))) short short8;
typedef __attribute__((ext_vector_type(4))) float f32x4;

// ---------------- helpers ----------------

static __device__ __forceinline__ float wredmaxf(float v) {
  #pragma unroll
  for (int o = 1; o < 64; o <<= 1) v = fmaxf(v, __shfl_xor(v, o, 64));
  return v;
}

static __device__ __forceinline__ double blockRedSum256(double v) {
  __shared__ double sp[4];
  __syncthreads();
  #pragma unroll
  for (int o = 32; o > 0; o >>= 1) v += __shfl_down(v, o, 64);
  int lane = threadIdx.x & 63, wid = threadIdx.x >> 6;
  if (lane == 0) sp[wid] = v;
  __syncthreads();
  double r = 0.0;
  if (threadIdx.x == 0) r = sp[0] + sp[1] + sp[2] + sp[3];
  return r;
}

static __device__ __forceinline__ unsigned short f2bf(float f) {
  unsigned u = __float_as_uint(f);
  return (unsigned short)((u + 0x7FFFu + ((u >> 16) & 1u)) >> 16);   // RNE
}

static __device__ __forceinline__ float bilin(const float* __restrict__ img, float px, float py) {
  float x = fminf(fmaxf(px, 0.0f), 639.0f);
  float y = fminf(fmaxf(py, 0.0f), 479.0f);
  float x0 = floorf(x), y0 = floorf(y);
  float x1 = fminf(x0 + 1.0f, 639.0f);
  float y1 = fminf(y0 + 1.0f, 479.0f);
  float wx = x - x0, wy = y - y0;
  int x0i = (int)x0, x1i = (int)x1, y0i = (int)y0, y1i = (int)y1;
  float v00 = img[y0i*WW + x0i], v01 = img[y0i*WW + x1i];
  float v10 = img[y1i*WW + x0i], v11 = img[y1i*WW + x1i];
  return v00*(1.0f-wx)*(1.0f-wy) + v01*wx*(1.0f-wy) + v10*(1.0f-wx)*wy + v11*wx*wy;
}

// world point from pixel (px,py) in image bimg; replicates reference op order
static __device__ void src_compute(float px, float py, const float* __restrict__ dep,
                                   const float* __restrict__ poses, const float* __restrict__ Km,
                                   int bimg, float* Xw, float* dout) {
  float d = bilin(dep, px, py);
  const float* Kb = Km + bimg*9;
  double a00=Kb[0],a01=Kb[1],a02=Kb[2],a10=Kb[3],a11=Kb[4],a12=Kb[5],a20=Kb[6],a21=Kb[7],a22=Kb[8];
  double det = a00*(a11*a22-a12*a21) - a01*(a10*a22-a12*a20) + a02*(a10*a21-a11*a20);
  double id = 1.0/det;
  float i00=(float)((a11*a22-a12*a21)*id), i01=(float)((a02*a21-a01*a22)*id), i02=(float)((a01*a12-a02*a11)*id);
  float i10=(float)((a12*a20-a10*a22)*id), i11=(float)((a00*a22-a02*a20)*id), i12=(float)((a02*a10-a00*a12)*id);
  float i20=(float)((a10*a21-a11*a20)*id), i21=(float)((a01*a20-a00*a21)*id), i22=(float)((a00*a11-a01*a10)*id);
  float c0 = i00*px + i01*py + i02;
  float c1 = i10*px + i11*py + i12;
  float c2 = i20*px + i21*py + i22;
  float X0 = d*c0, X1 = d*c1, X2 = d*c2;
  const float* P = poses + bimg*16;
  Xw[0] = (P[0]*X0 + P[1]*X1 + P[2]*X2)  + P[3];
  Xw[1] = (P[4]*X0 + P[5]*X1 + P[6]*X2)  + P[7];
  Xw[2] = (P[8]*X0 + P[9]*X1 + P[10]*X2) + P[11];
  *dout = d;
}

static __device__ void project_to(const float* __restrict__ poses, const float* __restrict__ Km,
                                  int j, const float* Xw, float dsrc,
                                  float* pnx, float* pny, bool* invis) {
  const float* P = poses + j*16;
  float d0 = Xw[0]-P[3], d1 = Xw[1]-P[7], d2 = Xw[2]-P[11];
  float Xj0 = P[0]*d0 + P[4]*d1 + P[8]*d2;
  float Xj1 = P[1]*d0 + P[5]*d1 + P[9]*d2;
  float Xj2 = P[2]*d0 + P[6]*d1 + P[10]*d2;
  const float* Kb = Km + j*9;
  float u = Kb[0]*Xj0 + Kb[1]*Xj1 + Kb[2]*Xj2;
  float v = Kb[3]*Xj0 + Kb[4]*Xj1 + Kb[5]*Xj2;
  float z = Kb[6]*Xj0 + Kb[7]*Xj1 + Kb[8]*Xj2;
  float zs = (fabsf(z) < 1e-6f) ? 1e-6f : z;
  float pu = u/zs, pv = v/zs;
  float nx = 2.0f*pu/639.0f - 1.0f;
  float ny = 2.0f*pv/479.0f - 1.0f;
  *pnx = nx; *pny = ny;
  *invis = (z <= 1e-6f) || (fabsf(nx) > 1.0f) || (fabsf(ny) > 1.0f) || (dsrc <= 0.0f);
}

// ---------------- kernels ----------------

// fused gray -> sobel -> GFTT with SEPARABLE gaussian; also inits ovf + list + dnb pad rows.
__global__ __launch_bounds__(256) void k_gfused(const float* __restrict__ imgs, float* __restrict__ resp,
                                                int* __restrict__ ovf, int* __restrict__ list,
                                                unsigned int* __restrict__ dnb_u) {
  __shared__ float smem[6536];
  __shared__ float Gw[7];
  float* sgxy = smem;              // [38][38][2] interleaved gx,gy
  float* gray = smem + 2888;       // [40][41]  (dead after sobel)
  float* hxx  = smem + 2888;       // [38][32] aliases gray
  float* hyy  = hxx + 1216;
  float* hxy  = hyy + 1216;
  int bx = blockIdx.x*32, by = blockIdx.y*32, b = blockIdx.z;
  int tid = threadIdx.x;
  if (blockIdx.z == 0 && blockIdx.y == 0) {
    int g = blockIdx.x*256 + tid;                 // 0..5119
    for (int e = g; e < BB*64; e += 20*256) ovf[e] = 0;
    for (int e = g; e < NLIST; e += 20*256) list[e] = -1;
    for (int e = g; e < 12288; e += 20*256) {     // zero bf16 pad rows 500..511 per image
      int bi = e / 1536, r = e % 1536;
      dnb_u[(bi*512 + 500)*128 + r] = 0u;
    }
  }
  if (tid < 7) {
    double g[7]; double s = 0.0;
    for (int q = 0; q < 7; q++) { double r = (double)(q-3); g[q] = exp(-(r*r)/2.0); s += g[q]; }
    Gw[tid] = (float)(g[tid]/s);
  }
  const float* ib = imgs + (size_t)b*3*HWSZ;
  for (int e = tid; e < 40*40; e += 256) {
    int ly = e/40, lx = e%40;
    int X = bx - 4 + lx, Y = by - 4 + ly;
    float v = 0.f;
    if (X>=0 && X<WW && Y>=0 && Y<HH) {
      int p = Y*WW + X;
      v = 0.299f*ib[p] + 0.587f*ib[HWSZ+p] + 0.114f*ib[2*HWSZ+p];
    }
    gray[ly*41+lx] = v;
  }
  __syncthreads();
  const float kxw[3][3] = {{-0.125f,0.f,0.125f},{-0.25f,0.f,0.25f},{-0.125f,0.f,0.125f}};
  for (int e = tid; e < 38*38; e += 256) {
    int rr = e/38, c = e%38;
    int X = bx - 3 + c, Y = by - 3 + rr;
    float sx = 0.f, sy = 0.f;
    #pragma unroll
    for (int i = 0; i < 3; i++)
      #pragma unroll
      for (int j = 0; j < 3; j++) {
        float v = gray[(rr+i)*41 + (c+j)];
        sx += kxw[i][j]*v;
        sy += kxw[j][i]*v;
      }
    bool in = (X>=0 && X<WW && Y>=0 && Y<HH);
    sgxy[e*2]   = in ? sx : 0.f;    // conv zero-pad semantics
    sgxy[e*2+1] = in ? sy : 0.f;
  }
  __syncthreads();
  for (int e = tid; e < 38*32; e += 256) {
    int rr = e >> 5, co = e & 31;
    int base = (rr*38 + co)*2;
    float axx = 0.f, ayy = 0.f, axy = 0.f;
    #pragma unroll
    for (int j = 0; j < 7; j++) {
      float a = sgxy[base + j*2];
      float c = sgxy[base + j*2 + 1];
      float Gj = Gw[j];
      axx += Gj*(a*a); ayy += Gj*(c*c); axy += Gj*(a*c);
    }
    hxx[e] = axx; hyy[e] = ayy; hxy[e] = axy;
  }
  __syncthreads();
  int tx = tid & 31, ty = tid >> 5;
  int r0 = ty*4;
  float axx[4] = {0,0,0,0}, ayy[4] = {0,0,0,0}, axy[4] = {0,0,0,0};
  #pragma unroll
  for (int rr = 0; rr < 10; rr++) {
    int r = r0 + rr;
    float vxx = hxx[r*32+tx], vyy = hyy[r*32+tx], vxy = hxy[r*32+tx];
    #pragma unroll
    for (int o = 0; o < 4; o++) {
      int i = rr - o;
      if (i >= 0 && i <= 6) {
        float Gi = Gw[i];
        axx[o] += Gi*vxx; ayy[o] += Gi*vyy; axy[o] += Gi*vxy;
      }
    }
  }
  #pragma unroll
  for (int o = 0; o < 4; o++) {
    float tr = axx[o] + ayy[o];
    float det = axx[o]*ayy[o] - axy[o]*axy[o];
    float disc = fmaxf(tr*tr - 4.0f*det, 0.f);
    int y = by + r0 + o;
    resp[(size_t)b*HWSZ + y*WW + (bx+tx)] = 0.5f*(tr - sqrtf(disc));
  }
}

// fused SEPARABLE 5x5 NMS + per-8x8-block candidate extraction (+ zero scatter target)
__global__ __launch_bounds__(256) void k_nmscand(const float* __restrict__ resp, float* __restrict__ cv,
                          int* __restrict__ ci, float* __restrict__ cvo,
                          int* __restrict__ cio, int* __restrict__ ovf,
                          float* __restrict__ target) {
  __shared__ float s[36*37];
  __shared__ float hm[36*32];
  __shared__ float c32[32*32];
  int bx = blockIdx.x*32, by = blockIdx.y*32, b = blockIdx.z;
  int tid = threadIdx.x;
  const float* r = resp + (size_t)b*HWSZ;
  for (int e = tid; e < 36*36; e += 256) {
    int ly = e/36, lx = e%36;
    int X = bx - 2 + lx, Y = by - 2 + ly;
    s[ly*37+lx] = (X>=0 && X<WW && Y>=0 && Y<HH) ? r[Y*WW+X] : -INFINITY;
  }
  __syncthreads();
  for (int e = tid; e < 36*32; e += 256) {
    int rr = e >> 5, co = e & 31;
    int base = rr*37 + co;
    float m = s[base];
    m = fmaxf(m, s[base+1]); m = fmaxf(m, s[base+2]);
    m = fmaxf(m, s[base+3]); m = fmaxf(m, s[base+4]);
    hm[e] = m;
  }
  __syncthreads();
  for (int e = tid; e < 1024; e += 256) {
    int y = e >> 5, x = e & 31;
    float mp = hm[y*32+x];
    mp = fmaxf(mp, hm[(y+1)*32+x]); mp = fmaxf(mp, hm[(y+2)*32+x]);
    mp = fmaxf(mp, hm[(y+3)*32+x]); mp = fmaxf(mp, hm[(y+4)*32+x]);
    float v = s[(y+2)*37 + (x+2)];
    c32[e] = (v == mp) ? v : 0.f;
    target[(size_t)b*HWSZ + (by+y)*WW + (bx+x)] = 0.f;
  }
  __syncthreads();
  int wv = tid >> 6, lane = tid & 63;
  int ly8 = lane >> 3, lx8 = lane & 7;
  for (int q = 0; q < 4; q++) {
    int bb = wv*4 + q;
    int oy = (bb >> 2)*8, ox = (bb & 3)*8;
    float cval = c32[(oy+ly8)*32 + ox+lx8];
    float bm = wredmaxf(cval);
    bool win = (cval > 0.f) && (cval == bm);
    unsigned long long mask = __ballot(win);
    int BY = blockIdx.y*4 + (bb >> 2), BX = blockIdx.x*4 + (bb & 3);
    int rblk = BY*80 + BX;
    int gidx = (by+oy+ly8)*WW + (bx+ox+lx8);
    if (mask == 0ull) {
      if (lane == 0) { cv[b*NBLK+rblk] = 0.f; ci[b*NBLK+rblk] = 0; }
    } else if (win) {
      int rank = __popcll(mask & ((1ull << lane) - 1ull));
      if (rank == 0) { cv[b*NBLK+rblk] = cval; ci[b*NBLK+rblk] = gidx; }
      else {
        int pos = atomicAdd(&ovf[b*64], 1);
        if (pos < NOVF) { cvo[b*NOVF+pos] = cval; cio[b*NOVF+pos] = gidx; }
      }
    }
  }
}

// top-500 radix select (wave-synchronous scan, early exit) + fused projection
// scatter of the selected corners. Top-500 kept entirely in LDS.
__global__ __launch_bounds__(1024) void k_topscat(const float* __restrict__ cv, const int* __restrict__ ci,
                                                  const float* __restrict__ cvo, const int* __restrict__ cio,
                                                  const int* __restrict__ ovf,
                                                  const float* __restrict__ depths, const float* __restrict__ poses,
                                                  const float* __restrict__ Km,
                                                  unsigned int* __restrict__ target, int* __restrict__ list) {
  __shared__ unsigned int hist[256];
  __shared__ unsigned long long prefix_s;
  __shared__ int kk_s, fin_s, cgt_s, ceq_s;
  __shared__ float s_topv[NN];
  __shared__ int s_topi[NN];
  int b = blockIdx.x;
  int tid = threadIdx.x;
  int nval = min(ovf[b*64], NOVF);
  unsigned long long kreg[8];
  #pragma unroll
  for (int q = 0; q < 8; q++) {
    int e = tid + q*1024;
    float v = 0.f; unsigned int idx = 0u;
    if (e < NBLK) { v = cv[b*NBLK+e]; idx = (unsigned int)ci[b*NBLK+e]; }
    else if (e - NBLK < nval) { v = cvo[b*NOVF+e-NBLK]; idx = (unsigned int)cio[b*NOVF+e-NBLK]; }
    kreg[q] = ((unsigned long long)__float_as_uint(v) << 32) | (0xFFFFFFFFu - idx);
  }
  if (tid == 0) { prefix_s = 0ull; kk_s = NN; fin_s = -1; cgt_s = 0; ceq_s = 0; }
  if (tid < 256) hist[tid] = 0u;
  __syncthreads();
  for (int round = 0; round < 8; round++) {
    int shift = 56 - 8*round;
    unsigned long long prefix = prefix_s;
    int kk = kk_s;
    unsigned long long himask = (round == 0) ? 0ull : (~0ull << (shift + 8));
    #pragma unroll
    for (int q = 0; q < 8; q++)
      if ((kreg[q] & himask) == prefix)
        atomicAdd(&hist[(unsigned int)((kreg[q] >> shift) & 255ull)], 1u);
    __syncthreads();
    if (tid < 64) {
      int l = tid;
      unsigned s0 = hist[l], s1 = hist[64+l], s2 = hist[128+l], s3 = hist[192+l];
      #pragma unroll
      for (int off = 1; off < 64; off <<= 1) {
        unsigned t0 = __shfl_down(s0, off, 64), t1 = __shfl_down(s1, off, 64);
        unsigned t2 = __shfl_down(s2, off, 64), t3 = __shfl_down(s3, off, 64);
        if (l + off < 64) { s0 += t0; s1 += t1; s2 += t2; s3 += t3; }
      }
      unsigned S1 = __shfl(s1, 0, 64), S2 = __shfl(s2, 0, 64), S3 = __shfl(s3, 0, 64);
      unsigned suf0 = s0 + S1 + S2 + S3, suf1 = s1 + S2 + S3, suf2 = s2 + S3, suf3 = s3;
      int best = -1;
      if      (suf3 >= (unsigned)kk) best = 192 + l;
      else if (suf2 >= (unsigned)kk) best = 128 + l;
      else if (suf1 >= (unsigned)kk) best = 64 + l;
      else if (suf0 >= (unsigned)kk) best = l;
      #pragma unroll
      for (int off = 1; off < 64; off <<= 1) best = max(best, __shfl_xor(best, off, 64));
      if (l == (best & 63)) {
        int seg = best >> 6;
        unsigned sufb = (seg == 3) ? suf3 : ((seg == 2) ? suf2 : ((seg == 1) ? suf1 : suf0));
        unsigned c = hist[best];
        int Sn = (int)(sufb - c);
        int kkn = kk - Sn;
        prefix_s = prefix | ((unsigned long long)best << shift);
        kk_s = kkn;
        if (kkn == (int)c) fin_s = shift;
      }
      hist[l] = 0u; hist[64+l] = 0u; hist[128+l] = 0u; hist[192+l] = 0u;
    }
    __syncthreads();
    if (fin_s >= 0) break;
  }
  int sg = (fin_s > 0) ? fin_s : 0;
  unsigned long long prefix = prefix_s;
  int kk = kk_s;
  unsigned long long low = (sg > 0) ? ((1ull << sg) - 1ull) : 0ull;
  unsigned long long Tfull = prefix | low;
  unsigned long long mhi = ~low;
  #pragma unroll
  for (int q = 0; q < 8; q++) {
    unsigned long long key = kreg[q];
    int slot = -1;
    if (key > Tfull) slot = atomicAdd(&cgt_s, 1);
    else if ((key & mhi) == prefix) {
      int p = atomicAdd(&ceq_s, 1);
      if (p < kk) slot = (NN-1) - p;
    }
    if (slot >= 0) {
      s_topv[slot] = __uint_as_float((unsigned int)(key >> 32));
      s_topi[slot] = (int)(0xFFFFFFFFu - (unsigned int)(key & 0xFFFFFFFFull));
    }
  }
  __syncthreads();
  // ---- fused scatter: this block owns image b; 500 threads project its corners
  if (tid < NN) {
    float val = s_topv[tid];
    if (val > 0.f) {
      int idx = s_topi[tid];
      float xs = (float)(idx % WW), ys = (float)(idx / WW);
      float cx = 2.0f*xs/639.0f - 1.0f;
      float cy = 2.0f*ys/479.0f - 1.0f;
      float px = (cx + 1.0f)*0.5f*639.0f;
      float py = (cy + 1.0f)*0.5f*479.0f;
      float Xw[3], d;
      src_compute(px, py, depths + (size_t)b*HWSZ, poses, Km, b, Xw, &d);
      int tglob = b*NN + tid;
      for (int j = 0; j < BB; j++) {
        float nx, ny; bool inv;
        project_to(poses, Km, j, Xw, d, &nx, &ny, &inv);
        if (inv) { nx = -2.0f; ny = -2.0f; }
        float fx = rintf((nx + 1.0f)*0.5f*639.0f);
        float fy = rintf((ny + 1.0f)*0.5f*479.0f);
        int wq = (int)fx, hq = (int)fy;
        if (wq < 0) continue;
        int hc = min(max(hq, 0), HH-1), wc = min(max(wq, 0), WW-1);
        int p = j*HWSZ + hc*WW + wc;
        unsigned int old = atomicMax(&target[p], __float_as_uint(val));
        if (old == 0u) list[tglob*BB + j] = p;   // first writer, exactly once per pixel
      }
    }
  }
}

// fused independent mid-stage work, partitioned by block range.
__global__ __launch_bounds__(256) void k_misc(const float* __restrict__ desc, float* __restrict__ dn,
                                              unsigned short* __restrict__ dnb,
                                              const float* __restrict__ points, const float* __restrict__ depths,
                                              const float* __restrict__ poses, const float* __restrict__ Km,
                                              float* __restrict__ psrc, float* __restrict__ pdst, int* __restrict__ minv,
                                              const float* __restrict__ pn, const int* __restrict__ list,
                                              const float* __restrict__ target, double* __restrict__ pd) {
  int bid = blockIdx.x, tid = threadIdx.x;
  if (bid < 4000) {
    int row = bid;
    float v = desc[(size_t)row*DDIM + tid];
    __shared__ float sp2[4];
    __shared__ float den_s;
    float s = v*v;
    #pragma unroll
    for (int o = 32; o > 0; o >>= 1) s += __shfl_down(s, o, 64);
    int lane = tid & 63, wid = tid >> 6;
    if (lane == 0) sp2[wid] = s;
    __syncthreads();
    if (tid == 0) den_s = fmaxf(sqrtf(sp2[0]+sp2[1]+sp2[2]+sp2[3]), 1e-8f);
    __syncthreads();
    float o = v / den_s;
    dn[(size_t)row*DDIM + tid] = o;
    int pr = (row/500)*512 + (row%500);             // padded bf16 row
    dnb[(size_t)pr*DDIM + tid] = f2bf(o);
  } else if (bid < 4016) {
    int t = (bid - 4000)*256 + tid;
    if (t < BB*NN) {
      int a = t / NN, m = t % NN;
      float p0 = points[t*2], p1 = points[t*2+1];
      float px = (p0 + 1.0f)*0.5f*639.0f;
      float py = (p1 + 1.0f)*0.5f*479.0f;
      float Xw[3], d;
      src_compute(px, py, depths + (size_t)a*HWSZ, poses, Km, a, Xw, &d);
      psrc[t*2] = px; psrc[t*2+1] = py;
      for (int b = 0; b < BB; b++) {
        float nx, ny; bool inv;
        project_to(poses, Km, b, Xw, d, &nx, &ny, &inv);
        int o = (a*BB + b)*NN + m;
        pdst[o*2]   = (nx + 1.0f)*0.5f*639.0f;   // raw projections (reference match path)
        pdst[o*2+1] = (ny + 1.0f)*0.5f*479.0f;
        minv[o] = inv ? 1 : 0;
      }
    }
  } else if (bid < 4016 + NBCE2) {
    int blk = bid - 4016;
    int g = blk*256 + tid;
    double l = 0.0;
    for (int q = g; q < BHW/4; q += NBCE2*256) {
      float4 v = ((const float4*)pn)[q];
      l -= (double)fmaxf(logf(1.f - v.x), -100.f);
      l -= (double)fmaxf(logf(1.f - v.y), -100.f);
      l -= (double)fmaxf(logf(1.f - v.z), -100.f);
      l -= (double)fmaxf(logf(1.f - v.w), -100.f);
    }
    double s = blockRedSum256(l);
    if (tid == 0) pd[PD_BCE + blk] = s;
  } else {
    int blk = bid - (4016 + NBCE2);
    int g = blk*256 + tid;
    double l = 0.0;
    if (g < NLIST) {
      int p = list[g];
      if (p >= 0) {
        int j = p / HWSZ, pix = p % HWSZ;
        int y = pix / WW, x = pix % WW;
        const float* tb = target + (size_t)j*HWSZ;
        float v = tb[pix];
        float mp = -INFINITY;
        for (int dy = -2; dy <= 2; dy++) {
          int yy = y + dy; if (yy < 0 || yy >= HH) continue;
          for (int dx = -2; dx <= 2; dx++) {
            int xx = x + dx; if (xx < 0 || xx >= WW) continue;
            mp = fmaxf(mp, tb[yy*WW+xx]);
          }
        }
        if (v > 0.f && v == mp) {
          float pv = pn[p];
          l = (double)(-fmaxf(logf(pv), -100.f)) + (double)fmaxf(logf(1.f - pv), -100.f);
        }
      }
    }
    double s = blockRedSum256(l);
    if (tid == 0) pd[PD_CORR + blk] = s;
  }
}

// fused tail: [0,NDM) distinction via bf16 MFMA (no LDS); [NDM,NDM+512) match slices.
__global__ __launch_bounds__(256) void k_tail(const float* __restrict__ psrc, const float* __restrict__ pdst,
                                              const int* __restrict__ minv, const float* __restrict__ dn,
                                              const short* __restrict__ dnb, double* __restrict__ pd) {
  __shared__ float sbuf[2500];
  int bid = blockIdx.x, tid = threadIdx.x;
  if (bid < NDM) {
    // ---- distinction: 16x16 lower-tri tiles via v_mfma_f32_16x16x32_bf16.
    // A-frag: lane l -> row r0+(l&15), k = (l>>4)*8 + e  (8 contiguous bf16)
    // B-frag: lane l -> col c0+(l&15), same k layout (row of dnb = col of B)
    int w = tid >> 6, lane = tid & 63;
    int gw = bid*4 + w;                          // 0..263
    int r16 = lane & 15, koff = (lane >> 4)*8;
    double dsum = 0.0;
    for (int j = 0; j < 16; j++) {
      int jb = gw*16 + j;                        // 0..4223
      int b = jb / 528, t = jb % 528;
      int I = (int)((sqrtf(8.f*(float)t + 1.f) - 1.f)*0.5f);
      while ((I+1)*(I+2)/2 <= t) I++;
      while (I*(I+1)/2 > t) I--;
      int J = t - I*(I+1)/2;
      const short* bp = dnb + (size_t)b*512*DDIM;
      const short* ap = bp + (I*16 + r16)*DDIM + koff;
      const short* cp = bp + (J*16 + r16)*DDIM + koff;
      f32x4 acc = {0.f, 0.f, 0.f, 0.f};
      #pragma unroll
      for (int kk = 0; kk < 8; kk++) {
        short8 af = *(const short8*)(ap + kk*32);
        short8 bf = *(const short8*)(cp + kk*32);
        acc = __builtin_amdgcn_mfma_f32_16x16x32_bf16(af, bf, acc, 0, 0, 0);
      }
      float ls = fmaxf(acc[0],0.f) + fmaxf(acc[1],0.f) + fmaxf(acc[2],0.f) + fmaxf(acc[3],0.f);
      dsum += (double)ls * ((I == J) ? 1.0 : 2.0);
    }
    double s = blockRedSum256(dsum);
    if (tid == 0) pd[PD_DIST + bid] = s;
  } else {
    // ---- match slice: mm strided by 8 (balanced), nn-inner coalesced, no int div
    int mbid = bid - NDM;              // 0..511
    float* spd = sbuf;                 // 1000
    float* ssrc = sbuf + 1000;         // 1000
    int* sinv = (int*)(sbuf + 2000);   // 500
    int ab = mbid & 63; int b = ab % BB; int a = ab / BB;
    int ys = mbid >> 6;                // 0..7 stripe
    for (int e = tid; e < NN; e += 256) {
      spd[e*2]   = pdst[(ab*NN+e)*2];
      spd[e*2+1] = pdst[(ab*NN+e)*2+1];
      sinv[e]    = minv[ab*NN+e];
      ssrc[e*2]   = psrc[(b*NN+e)*2];
      ssrc[e*2+1] = psrc[(b*NN+e)*2+1];
    }
    __syncthreads();
    double lsum = 0.0, lcnt = 0.0;
    for (int mm = ys; mm < NN; mm += 8) {
      float px = spd[mm*2], py = spd[mm*2+1];
      for (int nn = tid; nn < mm; nn += 256) {
        if (sinv[nn]) continue;        // reference quirk: invis indexed by n
        float dx = ssrc[nn*2]   - px;
        float dy = ssrc[nn*2+1] - py;
        if (dx*dx + dy*dy <= 1.0f) {
          const float* da = dn + ((size_t)a*NN + mm)*DDIM;
          const float* db = dn + ((size_t)b*NN + nn)*DDIM;
          float dot = 0.f;
          for (int q = 0; q < DDIM; q++) dot += db[q]*da[q];
          lsum += (double)(1.0f - dot);
          lcnt += 1.0;
        }
      }
    }
    double s = blockRedSum256(lsum);
    if (tid == 0) pd[PD_MS + mbid] = s;
    double c2 = blockRedSum256(lcnt);
    if (tid == 0) pd[PD_MC + mbid] = c2;
  }
}

__global__ void k_final(const double* __restrict__ pd, float* __restrict__ out) {
  int tid = threadIdx.x;
  double l;
  l = 0.0; for (int i = tid; i < NDM;   i += 256) l += pd[PD_DIST + i];
  double dist = blockRedSum256(l);
  l = 0.0; for (int i = tid; i < 512;   i += 256) l += pd[PD_MS + i];
  double ms = blockRedSum256(l);
  l = 0.0; for (int i = tid; i < 512;   i += 256) l += pd[PD_MC + i];
  double mc = blockRedSum256(l);
  l = 0.0; for (int i = tid; i < NBCE2; i += 256) l += pd[PD_BCE + i];
  double bce = blockRedSum256(l);
  l = 0.0; for (int i = tid; i < NCORR; i += 256) l += pd[PD_CORR + i];
  double corr = blockRedSum256(l);
  if (tid == 0) {
    float distf = (float)(dist / (double)(BB*NN*NN));
    float cornf = (float)((bce + corr) / (double)BHW);
    float cntf  = fmaxf((float)mc, 1.0f);
    float matchf = (float)ms / cntf;
    out[0] = distf + cornf + matchf;
  }
}

// ---------------- host ----------------

extern "C" void kernel_launch(void* const* d_in, const int* in_sizes, int n_in,
                              void* d_out, int out_size, void* d_ws, size_t ws_size,
                              hipStream_t stream) {
  (void)in_sizes; (void)n_in; (void)out_size; (void)ws_size;
  const float* desc      = (const float*)d_in[0];
  const float* points    = (const float*)d_in[1];
  const float* pointness = (const float*)d_in[2];
  const float* depths    = (const float*)d_in[3];
  const float* poses     = (const float*)d_in[4];
  const float* Kmat      = (const float*)d_in[5];
  const float* imgs      = (const float*)d_in[6];
  float* out = (float*)d_out;

  double* pd = (double*)d_ws;                      // partial sums first (8B aligned)
  float* f = (float*)(pd + PD_TOTAL);
  float* bufA = f;                                 // resp
  float* bufC = bufA + (size_t)BHW;                // scatter target
  float* cv_main = bufC + (size_t)BHW;             // 8 x 4800
  int*   ci_main = (int*)(cv_main + BB*NBLK);
  float* cv_ovf  = (float*)(ci_main + BB*NBLK);    // 8 x 3392 (stale-safe: count-masked)
  int*   ci_ovf  = (int*)(cv_ovf + BB*NOVF);
  int*   ovf     = (int*)(ci_ovf + BB*NOVF);       // 8 x stride-64 counters (init in k_gfused)
  float* psrc = (float*)(ovf + BB*64);
  float* pdst = psrc + BB*NN*2;
  int*   minv = (int*)(pdst + BB*BB*NN*2);
  float* dn   = (float*)(minv + BB*BB*NN);         // 8*500*256 floats
  int*   list = (int*)(dn + (size_t)BB*NN*DDIM);   // 32000 ints (init in k_gfused)
  unsigned short* dnb = (unsigned short*)(list + NLIST);  // 8*512*256 bf16 (pad init in k_gfused)

  dim3 tgrid(WW/32, HH/32, BB);                    // 20 x 15 x 8

  k_gfused <<<tgrid, 256, 0, stream>>>(imgs, bufA, ovf, list, (unsigned int*)dnb);
  k_nmscand<<<tgrid, 256, 0, stream>>>(bufA, cv_main, ci_main, cv_ovf, ci_ovf, ovf, bufC);
  k_topscat<<<BB, 1024, 0, stream>>>(cv_main, ci_main, cv_ovf, ci_ovf, ovf,
                                     depths, poses, Kmat, (unsigned int*)bufC, list);
  k_misc   <<<4016 + NBCE2 + NCORR, 256, 0, stream>>>(desc, dn, dnb, points, depths, poses, Kmat,
                                                      psrc, pdst, minv, pointness, list, bufC, pd);
  k_tail   <<<NDM + 512, 256, 0, stream>>>(psrc, pdst, minv, dn, (const short*)dnb, pd);
  k_final  <<<1, 256, 0, stream>>>(pd, out);
}

// Round 11
// 110.414 us; speedup vs baseline: 9.2208x; 1.1295x over previous
//
#include <hip/hip_runtime.h>
#include <math.h>

#define BB 8
#define NN 500
#define DDIM 256
#define HH 480
#define WW 640
#define HWSZ (HH*WW)        // 307200
#define BHW (BB*HWSZ)       // 2457600
#define NBLK 4800           // 8x8 blocks per image
#define NOVF 3392           // overflow candidate slots per image
#define NLIST (BB*NN*BB)    // 32000 deterministic list slots
#define NBCE2 512           // bce streaming blocks (inside k_front)
#define NCORR 125           // ceil(32000/256)
#define NDM 66              // dist-mfma blocks: 66*4 waves * 16 jobs = 4224 = 8*528 tiles

// partial-sum slot map (doubles at ws start)
#define PD_DIST  0          // 66 used
#define PD_MS    512        // 512
#define PD_MC    1024       // 512
#define PD_BCE   1536       // 512
#define PD_CORR  2560       // 125
#define PD_TOTAL 2688

typedef __attribute__((ext_vector_type(8))) short short8;
typedef __attribute__((ext_vector_type(4))) float f32x4;

// ---------------- helpers ----------------

static __device__ __forceinline__ float wredmaxf(float v) {
  #pragma unroll
  for (int o = 1; o < 64; o <<= 1) v = fmaxf(v, __shfl_xor(v, o, 64));
  return v;
}

static __device__ __forceinline__ double blockRedSum256(double v) {
  __shared__ double sp[4];
  __syncthreads();
  #pragma unroll
  for (int o = 32; o > 0; o >>= 1) v += __shfl_down(v, o, 64);
  int lane = threadIdx.x & 63, wid = threadIdx.x >> 6;
  if (lane == 0) sp[wid] = v;
  __syncthreads();
  double r = 0.0;
  if (threadIdx.x == 0) r = sp[0] + sp[1] + sp[2] + sp[3];
  return r;
}

static __device__ __forceinline__ unsigned short f2bf(float f) {
  unsigned u = __float_as_uint(f);
  return (unsigned short)((u + 0x7FFFu + ((u >> 16) & 1u)) >> 16);   // RNE
}

static __device__ __forceinline__ float bilin(const float* __restrict__ img, float px, float py) {
  float x = fminf(fmaxf(px, 0.0f), 639.0f);
  float y = fminf(fmaxf(py, 0.0f), 479.0f);
  float x0 = floorf(x), y0 = floorf(y);
  float x1 = fminf(x0 + 1.0f, 639.0f);
  float y1 = fminf(y0 + 1.0f, 479.0f);
  float wx = x - x0, wy = y - y0;
  int x0i = (int)x0, x1i = (int)x1, y0i = (int)y0, y1i = (int)y1;
  float v00 = img[y0i*WW + x0i], v01 = img[y0i*WW + x1i];
  float v10 = img[y1i*WW + x0i], v11 = img[y1i*WW + x1i];
  return v00*(1.0f-wx)*(1.0f-wy) + v01*wx*(1.0f-wy) + v10*(1.0f-wx)*wy + v11*wx*wy;
}

// world point from pixel (px,py) in image bimg; replicates reference op order
static __device__ void src_compute(float px, float py, const float* __restrict__ dep,
                                   const float* __restrict__ poses, const float* __restrict__ Km,
                                   int bimg, float* Xw, float* dout) {
  float d = bilin(dep, px, py);
  const float* Kb = Km + bimg*9;
  double a00=Kb[0],a01=Kb[1],a02=Kb[2],a10=Kb[3],a11=Kb[4],a12=Kb[5],a20=Kb[6],a21=Kb[7],a22=Kb[8];
  double det = a00*(a11*a22-a12*a21) - a01*(a10*a22-a12*a20) + a02*(a10*a21-a11*a20);
  double id = 1.0/det;
  float i00=(float)((a11*a22-a12*a21)*id), i01=(float)((a02*a21-a01*a22)*id), i02=(float)((a01*a12-a02*a11)*id);
  float i10=(float)((a12*a20-a10*a22)*id), i11=(float)((a00*a22-a02*a20)*id), i12=(float)((a02*a10-a00*a12)*id);
  float i20=(float)((a10*a21-a11*a20)*id), i21=(float)((a01*a20-a00*a21)*id), i22=(float)((a00*a11-a01*a10)*id);
  float c0 = i00*px + i01*py + i02;
  float c1 = i10*px + i11*py + i12;
  float c2 = i20*px + i21*py + i22;
  float X0 = d*c0, X1 = d*c1, X2 = d*c2;
  const float* P = poses + bimg*16;
  Xw[0] = (P[0]*X0 + P[1]*X1 + P[2]*X2)  + P[3];
  Xw[1] = (P[4]*X0 + P[5]*X1 + P[6]*X2)  + P[7];
  Xw[2] = (P[8]*X0 + P[9]*X1 + P[10]*X2) + P[11];
  *dout = d;
}

static __device__ void project_to(const float* __restrict__ poses, const float* __restrict__ Km,
                                  int j, const float* Xw, float dsrc,
                                  float* pnx, float* pny, bool* invis) {
  const float* P = poses + j*16;
  float d0 = Xw[0]-P[3], d1 = Xw[1]-P[7], d2 = Xw[2]-P[11];
  float Xj0 = P[0]*d0 + P[4]*d1 + P[8]*d2;
  float Xj1 = P[1]*d0 + P[5]*d1 + P[9]*d2;
  float Xj2 = P[2]*d0 + P[6]*d1 + P[10]*d2;
  const float* Kb = Km + j*9;
  float u = Kb[0]*Xj0 + Kb[1]*Xj1 + Kb[2]*Xj2;
  float v = Kb[3]*Xj0 + Kb[4]*Xj1 + Kb[5]*Xj2;
  float z = Kb[6]*Xj0 + Kb[7]*Xj1 + Kb[8]*Xj2;
  float zs = (fabsf(z) < 1e-6f) ? 1e-6f : z;
  float pu = u/zs, pv = v/zs;
  float nx = 2.0f*pu/639.0f - 1.0f;
  float ny = 2.0f*pv/479.0f - 1.0f;
  *pnx = nx; *pny = ny;
  *invis = (z <= 1e-6f) || (fabsf(nx) > 1.0f) || (fabsf(ny) > 1.0f) || (dsrc <= 0.0f);
}

// ---------------- kernels ----------------

// k_front: [0,2400) fused gray->sobel->separable-GFTT tiles (+ ws inits on bid<20);
// [2400,6400) desc normalize + bf16; [6400,6416) match src+projections;
// [6416,6928) streaming BCE (t=false assumption).
__global__ __launch_bounds__(256) void k_front(const float* __restrict__ imgs, float* __restrict__ resp,
                                               int* __restrict__ ovf, int* __restrict__ list,
                                               unsigned int* __restrict__ dnb_u,
                                               const float* __restrict__ desc, float* __restrict__ dn,
                                               unsigned short* __restrict__ dnb,
                                               const float* __restrict__ points, const float* __restrict__ depths,
                                               const float* __restrict__ poses, const float* __restrict__ Km,
                                               float* __restrict__ psrc, float* __restrict__ pdst,
                                               int* __restrict__ minv,
                                               const float* __restrict__ pn, double* __restrict__ pd) {
  __shared__ float smem[6536];
  __shared__ float Gw[7];
  int bid = blockIdx.x, tid = threadIdx.x;
  if (bid < 2400) {
    float* sgxy = smem;              // [38][38][2] interleaved gx,gy
    float* gray = smem + 2888;       // [40][41]  (dead after sobel)
    float* hxx  = smem + 2888;       // [38][32] aliases gray
    float* hyy  = hxx + 1216;
    float* hxy  = hyy + 1216;
    int b = bid / 300, r = bid % 300;
    int byi = r / 20, bxi = r % 20;
    int bx = bxi*32, by = byi*32;
    if (bid < 20) {
      int g = bid*256 + tid;                 // 0..5119
      for (int e = g; e < BB*64; e += 20*256) ovf[e] = 0;
      for (int e = g; e < NLIST; e += 20*256) list[e] = -1;
      for (int e = g; e < 12288; e += 20*256) {     // zero bf16 pad rows 500..511 per image
        int bi = e / 1536, rr2 = e % 1536;
        dnb_u[(bi*512 + 500)*128 + rr2] = 0u;
      }
    }
    if (tid < 7) {
      double g[7]; double s = 0.0;
      for (int q = 0; q < 7; q++) { double rr2 = (double)(q-3); g[q] = exp(-(rr2*rr2)/2.0); s += g[q]; }
      Gw[tid] = (float)(g[tid]/s);
    }
    const float* ib = imgs + (size_t)b*3*HWSZ;
    for (int e = tid; e < 40*40; e += 256) {
      int ly = e/40, lx = e%40;
      int X = bx - 4 + lx, Y = by - 4 + ly;
      float v = 0.f;
      if (X>=0 && X<WW && Y>=0 && Y<HH) {
        int p = Y*WW + X;
        v = 0.299f*ib[p] + 0.587f*ib[HWSZ+p] + 0.114f*ib[2*HWSZ+p];
      }
      gray[ly*41+lx] = v;
    }
    __syncthreads();
    const float kxw[3][3] = {{-0.125f,0.f,0.125f},{-0.25f,0.f,0.25f},{-0.125f,0.f,0.125f}};
    for (int e = tid; e < 38*38; e += 256) {
      int rr2 = e/38, c = e%38;
      int X = bx - 3 + c, Y = by - 3 + rr2;
      float sx = 0.f, sy = 0.f;
      #pragma unroll
      for (int i = 0; i < 3; i++)
        #pragma unroll
        for (int j = 0; j < 3; j++) {
          float v = gray[(rr2+i)*41 + (c+j)];
          sx += kxw[i][j]*v;
          sy += kxw[j][i]*v;
        }
      bool in = (X>=0 && X<WW && Y>=0 && Y<HH);
      sgxy[e*2]   = in ? sx : 0.f;    // conv zero-pad semantics
      sgxy[e*2+1] = in ? sy : 0.f;
    }
    __syncthreads();
    for (int e = tid; e < 38*32; e += 256) {
      int rr2 = e >> 5, co = e & 31;
      int base = (rr2*38 + co)*2;
      float axx = 0.f, ayy = 0.f, axy = 0.f;
      #pragma unroll
      for (int j = 0; j < 7; j++) {
        float a = sgxy[base + j*2];
        float c = sgxy[base + j*2 + 1];
        float Gj = Gw[j];
        axx += Gj*(a*a); ayy += Gj*(c*c); axy += Gj*(a*c);
      }
      hxx[e] = axx; hyy[e] = ayy; hxy[e] = axy;
    }
    __syncthreads();
    int tx = tid & 31, ty = tid >> 5;
    int r0 = ty*4;
    float axx[4] = {0,0,0,0}, ayy[4] = {0,0,0,0}, axy[4] = {0,0,0,0};
    #pragma unroll
    for (int rr2 = 0; rr2 < 10; rr2++) {
      int rr3 = r0 + rr2;
      float vxx = hxx[rr3*32+tx], vyy = hyy[rr3*32+tx], vxy = hxy[rr3*32+tx];
      #pragma unroll
      for (int o = 0; o < 4; o++) {
        int i = rr2 - o;
        if (i >= 0 && i <= 6) {
          float Gi = Gw[i];
          axx[o] += Gi*vxx; ayy[o] += Gi*vyy; axy[o] += Gi*vxy;
        }
      }
    }
    #pragma unroll
    for (int o = 0; o < 4; o++) {
      float tr = axx[o] + ayy[o];
      float det = axx[o]*ayy[o] - axy[o]*axy[o];
      float disc = fmaxf(tr*tr - 4.0f*det, 0.f);
      int y = by + r0 + o;
      resp[(size_t)b*HWSZ + y*WW + (bx+tx)] = 0.5f*(tr - sqrtf(disc));
    }
  } else if (bid < 6400) {
    int row = bid - 2400;
    float v = desc[(size_t)row*DDIM + tid];
    float* sp2 = smem;
    float s = v*v;
    #pragma unroll
    for (int o = 32; o > 0; o >>= 1) s += __shfl_down(s, o, 64);
    int lane = tid & 63, wid = tid >> 6;
    if (lane == 0) sp2[wid] = s;
    __syncthreads();
    if (tid == 0) sp2[4] = fmaxf(sqrtf(sp2[0]+sp2[1]+sp2[2]+sp2[3]), 1e-8f);
    __syncthreads();
    float o = v / sp2[4];
    dn[(size_t)row*DDIM + tid] = o;
    int pr = (row/500)*512 + (row%500);             // padded bf16 row
    dnb[(size_t)pr*DDIM + tid] = f2bf(o);
  } else if (bid < 6416) {
    int t = (bid - 6400)*256 + tid;
    if (t < BB*NN) {
      int a = t / NN, m = t % NN;
      float p0 = points[t*2], p1 = points[t*2+1];
      float px = (p0 + 1.0f)*0.5f*639.0f;
      float py = (p1 + 1.0f)*0.5f*479.0f;
      float Xw[3], d;
      src_compute(px, py, depths + (size_t)a*HWSZ, poses, Km, a, Xw, &d);
      psrc[t*2] = px; psrc[t*2+1] = py;
      for (int b = 0; b < BB; b++) {
        float nx, ny; bool inv;
        project_to(poses, Km, b, Xw, d, &nx, &ny, &inv);
        int o = (a*BB + b)*NN + m;
        pdst[o*2]   = (nx + 1.0f)*0.5f*639.0f;   // raw projections (reference match path)
        pdst[o*2+1] = (ny + 1.0f)*0.5f*479.0f;
        minv[o] = inv ? 1 : 0;
      }
    }
  } else {
    int blk = bid - 6416;
    int g = blk*256 + tid;
    double l = 0.0;
    for (int q = g; q < BHW/4; q += NBCE2*256) {
      float4 v = ((const float4*)pn)[q];
      l -= (double)fmaxf(logf(1.f - v.x), -100.f);
      l -= (double)fmaxf(logf(1.f - v.y), -100.f);
      l -= (double)fmaxf(logf(1.f - v.z), -100.f);
      l -= (double)fmaxf(logf(1.f - v.w), -100.f);
    }
    double s = blockRedSum256(l);
    if (tid == 0) pd[PD_BCE + blk] = s;
  }
}

// fused SEPARABLE 5x5 NMS + per-8x8-block candidate extraction (+ zero scatter target)
__global__ __launch_bounds__(256) void k_nmscand(const float* __restrict__ resp, float* __restrict__ cv,
                          int* __restrict__ ci, float* __restrict__ cvo,
                          int* __restrict__ cio, int* __restrict__ ovf,
                          float* __restrict__ target) {
  __shared__ float s[36*37];
  __shared__ float hm[36*32];
  __shared__ float c32[32*32];
  int bx = blockIdx.x*32, by = blockIdx.y*32, b = blockIdx.z;
  int tid = threadIdx.x;
  const float* r = resp + (size_t)b*HWSZ;
  for (int e = tid; e < 36*36; e += 256) {
    int ly = e/36, lx = e%36;
    int X = bx - 2 + lx, Y = by - 2 + ly;
    s[ly*37+lx] = (X>=0 && X<WW && Y>=0 && Y<HH) ? r[Y*WW+X] : -INFINITY;
  }
  __syncthreads();
  for (int e = tid; e < 36*32; e += 256) {
    int rr = e >> 5, co = e & 31;
    int base = rr*37 + co;
    float m = s[base];
    m = fmaxf(m, s[base+1]); m = fmaxf(m, s[base+2]);
    m = fmaxf(m, s[base+3]); m = fmaxf(m, s[base+4]);
    hm[e] = m;
  }
  __syncthreads();
  for (int e = tid; e < 1024; e += 256) {
    int y = e >> 5, x = e & 31;
    float mp = hm[y*32+x];
    mp = fmaxf(mp, hm[(y+1)*32+x]); mp = fmaxf(mp, hm[(y+2)*32+x]);
    mp = fmaxf(mp, hm[(y+3)*32+x]); mp = fmaxf(mp, hm[(y+4)*32+x]);
    float v = s[(y+2)*37 + (x+2)];
    c32[e] = (v == mp) ? v : 0.f;
    target[(size_t)b*HWSZ + (by+y)*WW + (bx+x)] = 0.f;
  }
  __syncthreads();
  int wv = tid >> 6, lane = tid & 63;
  int ly8 = lane >> 3, lx8 = lane & 7;
  for (int q = 0; q < 4; q++) {
    int bb = wv*4 + q;
    int oy = (bb >> 2)*8, ox = (bb & 3)*8;
    float cval = c32[(oy+ly8)*32 + ox+lx8];
    float bm = wredmaxf(cval);
    bool win = (cval > 0.f) && (cval == bm);
    unsigned long long mask = __ballot(win);
    int BY = blockIdx.y*4 + (bb >> 2), BX = blockIdx.x*4 + (bb & 3);
    int rblk = BY*80 + BX;
    int gidx = (by+oy+ly8)*WW + (bx+ox+lx8);
    if (mask == 0ull) {
      if (lane == 0) { cv[b*NBLK+rblk] = 0.f; ci[b*NBLK+rblk] = 0; }
    } else if (win) {
      int rank = __popcll(mask & ((1ull << lane) - 1ull));
      if (rank == 0) { cv[b*NBLK+rblk] = cval; ci[b*NBLK+rblk] = gidx; }
      else {
        int pos = atomicAdd(&ovf[b*64], 1);
        if (pos < NOVF) { cvo[b*NOVF+pos] = cval; cio[b*NOVF+pos] = gidx; }
      }
    }
  }
}

// top-500 radix select + fused projection scatter.
// Per-wave privatized histograms (stride 257: copies on distinct banks) kill the
// same-address LDS-atomic serialization; extraction uses ballot-aggregated atomics
// (slot sets are order-free).
__global__ __launch_bounds__(1024) void k_topscat(const float* __restrict__ cv, const int* __restrict__ ci,
                                                  const float* __restrict__ cvo, const int* __restrict__ cio,
                                                  const int* __restrict__ ovf,
                                                  const float* __restrict__ depths, const float* __restrict__ poses,
                                                  const float* __restrict__ Km,
                                                  unsigned int* __restrict__ target, int* __restrict__ list) {
  __shared__ unsigned int hist[16*257];
  __shared__ unsigned int histsum[256];
  __shared__ unsigned long long prefix_s;
  __shared__ int kk_s, fin_s, cgt_s, ceq_s;
  __shared__ float s_topv[NN];
  __shared__ int s_topi[NN];
  int b = blockIdx.x;
  int tid = threadIdx.x;
  int w257 = (tid >> 6)*257;
  int nval = min(ovf[b*64], NOVF);
  unsigned long long kreg[8];
  #pragma unroll
  for (int q = 0; q < 8; q++) {
    int e = tid + q*1024;
    float v = 0.f; unsigned int idx = 0u;
    if (e < NBLK) { v = cv[b*NBLK+e]; idx = (unsigned int)ci[b*NBLK+e]; }
    else if (e - NBLK < nval) { v = cvo[b*NOVF+e-NBLK]; idx = (unsigned int)cio[b*NOVF+e-NBLK]; }
    kreg[q] = ((unsigned long long)__float_as_uint(v) << 32) | (0xFFFFFFFFu - idx);
  }
  if (tid == 0) { prefix_s = 0ull; kk_s = NN; fin_s = -1; cgt_s = 0; ceq_s = 0; }
  for (int e = tid; e < 16*257; e += 1024) hist[e] = 0u;
  __syncthreads();
  for (int round = 0; round < 8; round++) {
    int shift = 56 - 8*round;
    unsigned long long prefix = prefix_s;
    int kk = kk_s;
    unsigned long long himask = (round == 0) ? 0ull : (~0ull << (shift + 8));
    #pragma unroll
    for (int q = 0; q < 8; q++)
      if ((kreg[q] & himask) == prefix)
        atomicAdd(&hist[w257 + (unsigned int)((kreg[q] >> shift) & 255ull)], 1u);
    __syncthreads();
    if (tid < 256) {
      unsigned s = 0u;
      #pragma unroll
      for (int ww = 0; ww < 16; ww++) s += hist[ww*257 + tid];
      histsum[tid] = s;
    }
    __syncthreads();
    // clear privatized hists for next round (parallel with wave-0 scan below)
    for (int e = tid; e < 16*257; e += 1024) hist[e] = 0u;
    if (tid < 64) {
      int l = tid;
      unsigned s0 = histsum[l], s1 = histsum[64+l], s2 = histsum[128+l], s3 = histsum[192+l];
      #pragma unroll
      for (int off = 1; off < 64; off <<= 1) {
        unsigned t0 = __shfl_down(s0, off, 64), t1 = __shfl_down(s1, off, 64);
        unsigned t2 = __shfl_down(s2, off, 64), t3 = __shfl_down(s3, off, 64);
        if (l + off < 64) { s0 += t0; s1 += t1; s2 += t2; s3 += t3; }
      }
      unsigned S1 = __shfl(s1, 0, 64), S2 = __shfl(s2, 0, 64), S3 = __shfl(s3, 0, 64);
      unsigned suf0 = s0 + S1 + S2 + S3, suf1 = s1 + S2 + S3, suf2 = s2 + S3, suf3 = s3;
      int best = -1;
      if      (suf3 >= (unsigned)kk) best = 192 + l;
      else if (suf2 >= (unsigned)kk) best = 128 + l;
      else if (suf1 >= (unsigned)kk) best = 64 + l;
      else if (suf0 >= (unsigned)kk) best = l;
      #pragma unroll
      for (int off = 1; off < 64; off <<= 1) best = max(best, __shfl_xor(best, off, 64));
      if (l == (best & 63)) {
        int seg = best >> 6;
        unsigned sufb = (seg == 3) ? suf3 : ((seg == 2) ? suf2 : ((seg == 1) ? suf1 : suf0));
        unsigned c = histsum[best];
        int Sn = (int)(sufb - c);
        int kkn = kk - Sn;
        prefix_s = prefix | ((unsigned long long)best << shift);
        kk_s = kkn;
        if (kkn == (int)c) fin_s = shift;
      }
    }
    __syncthreads();
    if (fin_s >= 0) break;
  }
  int sg = (fin_s > 0) ? fin_s : 0;
  unsigned long long prefix = prefix_s;
  int kk = kk_s;
  unsigned long long low = (sg > 0) ? ((1ull << sg) - 1ull) : 0ull;
  unsigned long long Tfull = prefix | low;
  unsigned long long mhi = ~low;
  int lane = tid & 63;
  unsigned long long lmask = (1ull << lane) - 1ull;
  #pragma unroll
  for (int q = 0; q < 8; q++) {
    unsigned long long key = kreg[q];
    bool gt = key > Tfull;
    bool eq = !gt && ((key & mhi) == prefix);
    unsigned long long mg = __ballot(gt);
    unsigned long long me = __ballot(eq);
    int slot = -1;
    if (mg != 0ull) {
      int ldr = __ffsll((long long)mg) - 1;
      int baseg = 0;
      if (lane == ldr) baseg = atomicAdd(&cgt_s, (int)__popcll(mg));
      baseg = __shfl(baseg, ldr, 64);
      if (gt) slot = baseg + (int)__popcll(mg & lmask);
    }
    if (me != 0ull) {
      int ldr = __ffsll((long long)me) - 1;
      int basee = 0;
      if (lane == ldr) basee = atomicAdd(&ceq_s, (int)__popcll(me));
      basee = __shfl(basee, ldr, 64);
      if (eq) {
        int p = basee + (int)__popcll(me & lmask);
        if (p < kk) slot = (NN-1) - p;
      }
    }
    if (slot >= 0) {
      s_topv[slot] = __uint_as_float((unsigned int)(key >> 32));
      s_topi[slot] = (int)(0xFFFFFFFFu - (unsigned int)(key & 0xFFFFFFFFull));
    }
  }
  __syncthreads();
  // ---- fused scatter: this block owns image b; 500 threads project its corners
  if (tid < NN) {
    float val = s_topv[tid];
    if (val > 0.f) {
      int idx = s_topi[tid];
      float xs = (float)(idx % WW), ys = (float)(idx / WW);
      float cx = 2.0f*xs/639.0f - 1.0f;
      float cy = 2.0f*ys/479.0f - 1.0f;
      float px = (cx + 1.0f)*0.5f*639.0f;
      float py = (cy + 1.0f)*0.5f*479.0f;
      float Xw[3], d;
      src_compute(px, py, depths + (size_t)b*HWSZ, poses, Km, b, Xw, &d);
      int tglob = b*NN + tid;
      for (int j = 0; j < BB; j++) {
        float nx, ny; bool inv;
        project_to(poses, Km, j, Xw, d, &nx, &ny, &inv);
        if (inv) { nx = -2.0f; ny = -2.0f; }
        float fx = rintf((nx + 1.0f)*0.5f*639.0f);
        float fy = rintf((ny + 1.0f)*0.5f*479.0f);
        int wq = (int)fx, hq = (int)fy;
        if (wq < 0) continue;
        int hc = min(max(hq, 0), HH-1), wc = min(max(wq, 0), WW-1);
        int p = j*HWSZ + hc*WW + wc;
        unsigned int old = atomicMax(&target[p], __float_as_uint(val));
        if (old == 0u) list[tglob*BB + j] = p;   // first writer, exactly once per pixel
      }
    }
  }
}

// fused tail: [0,NDM) distinction via bf16 MFMA; [NDM,NDM+512) match slices;
// [NDM+512, NDM+512+NCORR) BCE correction at scattered pixels.
__global__ __launch_bounds__(256) void k_tail(const float* __restrict__ psrc, const float* __restrict__ pdst,
                                              const int* __restrict__ minv, const float* __restrict__ dn,
                                              const short* __restrict__ dnb,
                                              const int* __restrict__ list, const float* __restrict__ target,
                                              const float* __restrict__ pn, double* __restrict__ pd) {
  __shared__ float sbuf[2500];
  int bid = blockIdx.x, tid = threadIdx.x;
  if (bid < NDM) {
    // ---- distinction: 16x16 lower-tri tiles via v_mfma_f32_16x16x32_bf16 (no LDS)
    int w = tid >> 6, lane = tid & 63;
    int gw = bid*4 + w;                          // 0..263
    int r16 = lane & 15, koff = (lane >> 4)*8;
    double dsum = 0.0;
    for (int j = 0; j < 16; j++) {
      int jb = gw*16 + j;                        // 0..4223
      int b = jb / 528, t = jb % 528;
      int I = (int)((sqrtf(8.f*(float)t + 1.f) - 1.f)*0.5f);
      while ((I+1)*(I+2)/2 <= t) I++;
      while (I*(I+1)/2 > t) I--;
      int J = t - I*(I+1)/2;
      const short* bp = dnb + (size_t)b*512*DDIM;
      const short* ap = bp + (I*16 + r16)*DDIM + koff;
      const short* cp = bp + (J*16 + r16)*DDIM + koff;
      f32x4 acc = {0.f, 0.f, 0.f, 0.f};
      #pragma unroll
      for (int kk = 0; kk < 8; kk++) {
        short8 af = *(const short8*)(ap + kk*32);
        short8 bf = *(const short8*)(cp + kk*32);
        acc = __builtin_amdgcn_mfma_f32_16x16x32_bf16(af, bf, acc, 0, 0, 0);
      }
      float ls = fmaxf(acc[0],0.f) + fmaxf(acc[1],0.f) + fmaxf(acc[2],0.f) + fmaxf(acc[3],0.f);
      dsum += (double)ls * ((I == J) ? 1.0 : 2.0);
    }
    double s = blockRedSum256(dsum);
    if (tid == 0) pd[PD_DIST + bid] = s;
  } else if (bid < NDM + 512) {
    // ---- match slice: mm strided by 8 (balanced), nn-inner coalesced, no int div
    int mbid = bid - NDM;              // 0..511
    float* spd = sbuf;                 // 1000
    float* ssrc = sbuf + 1000;         // 1000
    int* sinv = (int*)(sbuf + 2000);   // 500
    int ab = mbid & 63; int b = ab % BB; int a = ab / BB;
    int ys = mbid >> 6;                // 0..7 stripe
    for (int e = tid; e < NN; e += 256) {
      spd[e*2]   = pdst[(ab*NN+e)*2];
      spd[e*2+1] = pdst[(ab*NN+e)*2+1];
      sinv[e]    = minv[ab*NN+e];
      ssrc[e*2]   = psrc[(b*NN+e)*2];
      ssrc[e*2+1] = psrc[(b*NN+e)*2+1];
    }
    __syncthreads();
    double lsum = 0.0, lcnt = 0.0;
    for (int mm = ys; mm < NN; mm += 8) {
      float px = spd[mm*2], py = spd[mm*2+1];
      for (int nn = tid; nn < mm; nn += 256) {
        if (sinv[nn]) continue;        // reference quirk: invis indexed by n
        float dx = ssrc[nn*2]   - px;
        float dy = ssrc[nn*2+1] - py;
        if (dx*dx + dy*dy <= 1.0f) {
          const float* da = dn + ((size_t)a*NN + mm)*DDIM;
          const float* db = dn + ((size_t)b*NN + nn)*DDIM;
          float dot = 0.f;
          for (int q = 0; q < DDIM; q++) dot += db[q]*da[q];
          lsum += (double)(1.0f - dot);
          lcnt += 1.0;
        }
      }
    }
    double s = blockRedSum256(lsum);
    if (tid == 0) pd[PD_MS + mbid] = s;
    double c2 = blockRedSum256(lcnt);
    if (tid == 0) pd[PD_MC + mbid] = c2;
  } else {
    // ---- BCE correction at scattered pixels
    int blk = bid - (NDM + 512);
    int g = blk*256 + tid;
    double l = 0.0;
    if (g < NLIST) {
      int p = list[g];
      if (p >= 0) {
        int j = p / HWSZ, pix = p % HWSZ;
        int y = pix / WW, x = pix % WW;
        const float* tb = target + (size_t)j*HWSZ;
        float v = tb[pix];
        float mp = -INFINITY;
        for (int dy = -2; dy <= 2; dy++) {
          int yy = y + dy; if (yy < 0 || yy >= HH) continue;
          for (int dx = -2; dx <= 2; dx++) {
            int xx = x + dx; if (xx < 0 || xx >= WW) continue;
            mp = fmaxf(mp, tb[yy*WW+xx]);
          }
        }
        if (v > 0.f && v == mp) {
          float pv = pn[p];
          l = (double)(-fmaxf(logf(pv), -100.f)) + (double)fmaxf(logf(1.f - pv), -100.f);
        }
      }
    }
    double s = blockRedSum256(l);
    if (tid == 0) pd[PD_CORR + blk] = s;
  }
}

__global__ void k_final(const double* __restrict__ pd, float* __restrict__ out) {
  int tid = threadIdx.x;
  double l;
  l = 0.0; for (int i = tid; i < NDM;   i += 256) l += pd[PD_DIST + i];
  double dist = blockRedSum256(l);
  l = 0.0; for (int i = tid; i < 512;   i += 256) l += pd[PD_MS + i];
  double ms = blockRedSum256(l);
  l = 0.0; for (int i = tid; i < 512;   i += 256) l += pd[PD_MC + i];
  double mc = blockRedSum256(l);
  l = 0.0; for (int i = tid; i < NBCE2; i += 256) l += pd[PD_BCE + i];
  double bce = blockRedSum256(l);
  l = 0.0; for (int i = tid; i < NCORR; i += 256) l += pd[PD_CORR + i];
  double corr = blockRedSum256(l);
  if (tid == 0) {
    float distf = (float)(dist / (double)(BB*NN*NN));
    float cornf = (float)((bce + corr) / (double)BHW);
    float cntf  = fmaxf((float)mc, 1.0f);
    float matchf = (float)ms / cntf;
    out[0] = distf + cornf + matchf;
  }
}

// ---------------- host ----------------

extern "C" void kernel_launch(void* const* d_in, const int* in_sizes, int n_in,
                              void* d_out, int out_size, void* d_ws, size_t ws_size,
                              hipStream_t stream) {
  (void)in_sizes; (void)n_in; (void)out_size; (void)ws_size;
  const float* desc      = (const float*)d_in[0];
  const float* points    = (const float*)d_in[1];
  const float* pointness = (const float*)d_in[2];
  const float* depths    = (const float*)d_in[3];
  const float* poses     = (const float*)d_in[4];
  const float* Kmat      = (const float*)d_in[5];
  const float* imgs      = (const float*)d_in[6];
  float* out = (float*)d_out;

  double* pd = (double*)d_ws;                      // partial sums first (8B aligned)
  float* f = (float*)(pd + PD_TOTAL);
  float* bufA = f;                                 // resp
  float* bufC = bufA + (size_t)BHW;                // scatter target
  float* cv_main = bufC + (size_t)BHW;             // 8 x 4800
  int*   ci_main = (int*)(cv_main + BB*NBLK);
  float* cv_ovf  = (float*)(ci_main + BB*NBLK);    // 8 x 3392 (stale-safe: count-masked)
  int*   ci_ovf  = (int*)(cv_ovf + BB*NOVF);
  int*   ovf     = (int*)(ci_ovf + BB*NOVF);       // 8 x stride-64 counters (init in k_front)
  float* psrc = (float*)(ovf + BB*64);
  float* pdst = psrc + BB*NN*2;
  int*   minv = (int*)(pdst + BB*BB*NN*2);
  float* dn   = (float*)(minv + BB*BB*NN);         // 8*500*256 floats
  int*   list = (int*)(dn + (size_t)BB*NN*DDIM);   // 32000 ints (init in k_front)
  unsigned short* dnb = (unsigned short*)(list + NLIST);  // 8*512*256 bf16 (pad init in k_front)

  dim3 tgrid(WW/32, HH/32, BB);                    // 20 x 15 x 8

  k_front  <<<6928, 256, 0, stream>>>(imgs, bufA, ovf, list, (unsigned int*)dnb,
                                      desc, dn, dnb, points, depths, poses, Kmat,
                                      psrc, pdst, minv, pointness, pd);
  k_nmscand<<<tgrid, 256, 0, stream>>>(bufA, cv_main, ci_main, cv_ovf, ci_ovf, ovf, bufC);
  k_topscat<<<BB, 1024, 0, stream>>>(cv_main, ci_main, cv_ovf, ci_ovf, ovf,
                                     depths, poses, Kmat, (unsigned int*)bufC, list);
  k_tail   <<<NDM + 512 + NCORR, 256, 0, stream>>>(psrc, pdst, minv, dn, (const short*)dnb,
                                                   list, bufC, pointness, pd);
  k_final  <<<1, 256, 0, stream>>>(pd, out);
}